// Round 6
// baseline (378.332 us; speedup 1.0000x reference)
//
#include <hip/hip_runtime.h>
#include <hip/hip_bf16.h>

#define NNODE 50000
#define NEDGE 640000
#define NREL  3
#define HIDD  128
#define GNUM  512
#define K1    112   // layer-1 GEMM K (99 used + 13 zero pad)
#define K2    512   // layer-2 GEMM K (3*128 relations + 128 root)
#define NB    196   // scan blocks = ceil(NNODE/256)

typedef float  f32x4   __attribute__((ext_vector_type(4)));
typedef short  vshort8 __attribute__((ext_vector_type(8)));
typedef short  vshort4 __attribute__((ext_vector_type(4)));
typedef unsigned short vus4 __attribute__((ext_vector_type(4)));

// ---------------- builders ----------------
__global__ void build_tabs_kernel(const float* __restrict__ shape_w,
                                  const float* __restrict__ color_w,
                                  const float* __restrict__ W1,
                                  const float* __restrict__ root1,
                                  float* __restrict__ B1eff,
                                  float* __restrict__ rootTab) {
    int idx = blockIdx.x * blockDim.x + threadIdx.x;
    if (idx >= 4 * 33 * 128) return;
    int h  = idx & 127;
    int j  = (idx >> 7) % 33;
    int rr = idx / (33 * 128);
    const float* Wsrc = (rr < 3) ? (W1 + (size_t)rr * 129 * 128) : root1; // [129][128]
    float v = 0.f;
    if (j < 16) {
        for (int e = 0; e < 64; ++e) v += shape_w[j * 64 + e] * Wsrc[e * 128 + h];
    } else if (j < 32) {
        int c = j - 16;
        for (int e = 0; e < 64; ++e) v += color_w[c * 64 + e] * Wsrc[(64 + e) * 128 + h];
    } else {
        v = Wsrc[128 * 128 + h];
    }
    if (rr < 3) B1eff[(rr * 33 + j) * 128 + h] = v;
    else        rootTab[j * 128 + h] = v;
}

__device__ __forceinline__ void split_bf16(float f, short& hi, short& lo) {
    unsigned u  = __float_as_uint(f);
    unsigned uh = (u + 0x7FFFu + ((u >> 16) & 1u)) >> 16;
    hi = (short)uh;
    float fl = f - __uint_as_float(uh << 16);
    unsigned ul  = __float_as_uint(fl);
    unsigned ulh = (ul + 0x7FFFu + ((ul >> 16) & 1u)) >> 16;
    lo = (short)ulh;
}

__device__ __forceinline__ short bf16_rne(float f) {
    unsigned u = __float_as_uint(f);
    return (short)((u + 0x7FFFu + ((u >> 16) & 1u)) >> 16);
}

// B2 transposed + split: Bt[n][k], k<384 -> W2, else root2
__global__ void build_B2t_kernel(const float* __restrict__ W2,
                                 const float* __restrict__ root2,
                                 short* __restrict__ Bt_hi,
                                 short* __restrict__ Bt_lo) {
    int idx = blockIdx.x * blockDim.x + threadIdx.x; // 512*128
    if (idx >= K2 * 128) return;
    int k = idx >> 7, n = idx & 127;
    float v = (k < 384) ? W2[idx] : root2[idx - 384 * 128];
    short h, l;
    split_bf16(v, h, l);
    Bt_hi[(size_t)n * K2 + k] = h;
    Bt_lo[(size_t)n * K2 + k] = l;
}

// ---------------- edge counting (1 int atomic/edge) + node-feature pack ----------------
__global__ void count_nf_kernel(const int* __restrict__ ei, const int* __restrict__ et,
                                const int* __restrict__ shape_id, const int* __restrict__ color_id,
                                const float* __restrict__ pos,
                                int* __restrict__ cnt, int2* __restrict__ nf) {
    int e = blockIdx.x * blockDim.x + threadIdx.x;
    if (e < NNODE) nf[e] = make_int2(shape_id[e] | (color_id[e] << 8), __float_as_int(pos[e]));
    if (e >= NEDGE) return;
    int d = ei[NEDGE + e], r = et[e];
    atomicAdd(&cnt[d * 3 + r], 1);
}

// ---------------- prefix scan over per-node degree (3-phase) ----------------
__global__ void scan_partial_kernel(const int* __restrict__ cnt, int* __restrict__ partial) {
    __shared__ int sh[256];
    int t = threadIdx.x, i = blockIdx.x * 256 + t;
    int v = (i < NNODE) ? cnt[3 * i] + cnt[3 * i + 1] + cnt[3 * i + 2] : 0;
    sh[t] = v; __syncthreads();
    for (int o = 128; o > 0; o >>= 1) { if (t < o) sh[t] += sh[t + o]; __syncthreads(); }
    if (t == 0) partial[blockIdx.x] = sh[0];
}

__global__ void scan_mid_kernel(const int* __restrict__ partial, int* __restrict__ partial_pre,
                                int* __restrict__ offs) {
    __shared__ int sh[256];
    int t = threadIdx.x;
    int v = (t < NB) ? partial[t] : 0;
    sh[t] = v; __syncthreads();
    for (int o = 1; o < 256; o <<= 1) {
        int x = (t >= o) ? sh[t - o] : 0; __syncthreads();
        sh[t] += x; __syncthreads();
    }
    if (t < NB) partial_pre[t] = sh[t] - v;
    if (t == 0) offs[NNODE] = NEDGE;
}

__global__ void scan_final_kernel(const int* __restrict__ cnt, const int* __restrict__ partial_pre,
                                  int* __restrict__ offs, int* __restrict__ cursor,
                                  float* __restrict__ rcnt) {
    __shared__ int sh[256];
    int t = threadIdx.x, i = blockIdx.x * 256 + t;
    int c0 = 0, c1 = 0, c2 = 0;
    if (i < NNODE) { c0 = cnt[3 * i]; c1 = cnt[3 * i + 1]; c2 = cnt[3 * i + 2]; }
    int v = c0 + c1 + c2;
    sh[t] = v; __syncthreads();
    for (int o = 1; o < 256; o <<= 1) {
        int x = (t >= o) ? sh[t - o] : 0; __syncthreads();
        sh[t] += x; __syncthreads();
    }
    int exc = sh[t] - v + partial_pre[blockIdx.x];
    if (i < NNODE) {
        offs[i] = exc; cursor[i] = exc;
        float4 rc = make_float4(1.f / fmaxf((float)c0, 1.f), 1.f / fmaxf((float)c1, 1.f),
                                1.f / fmaxf((float)c2, 1.f), 1.f);
        *(float4*)&rcnt[i * 4] = rc;
    }
}

// ---------------- fill: dst-sorted edge list, src|rel packed ----------------
__global__ void fill_kernel(const int* __restrict__ ei, const int* __restrict__ et,
                            int* __restrict__ cursor, int* __restrict__ sorted) {
    int e = blockIdx.x * blockDim.x + threadIdx.x;
    if (e >= NEDGE) return;
    int s = ei[e], d = ei[NEDGE + e], r = et[e];
    int p = atomicAdd(&cursor[d], 1);
    sorted[p] = s | (r << 16);   // NNODE < 65536, r < 4
}

// ---------------- layer-1 histogram: edge-parallel, per-wave LDS hist ----------------
__global__ __launch_bounds__(256) void hist1_kernel(const int* __restrict__ offs,
                                                    const int* __restrict__ sorted,
                                                    const int2* __restrict__ nf,
                                                    float* __restrict__ A1) {
    __shared__ float hist[4][3 * 34];
    int lane = threadIdx.x & 63;
    int wv   = threadIdx.x >> 6;
    int d    = (blockIdx.x << 2) + wv;
    float* hf = hist[wv];
    if (lane < 51) { hf[lane] = 0.f; hf[lane + 51] = 0.f; }
    if (d < NNODE) {
        int beg = offs[d], end = offs[d + 1];
        for (int i = beg + lane; i < end; i += 64) {
            int w = sorted[i];
            int s = w & 0xFFFF, r = (w >> 16) & 3;
            int2 f = nf[s];
            atomicAdd(&hf[r * 34 + (f.x & 0xFF)], 1.f);
            atomicAdd(&hf[r * 34 + 16 + (f.x >> 8)], 1.f);
            atomicAdd(&hf[r * 34 + 32], __int_as_float(f.y));
        }
        float* row = &A1[(size_t)d * K1];
        row[lane] = hf[(lane / 33) * 34 + lane % 33];           // lanes 0..63 < 99
        int j = lane + 64;                                      // 64..127
        if (j < K1)                                             // BOUND GUARD (r5 bug fix)
            row[j] = (j < 99) ? hf[(j / 33) * 34 + j % 33] : 0.f;
    }
}

// ---------------- layer-2 aggregation: wave-per-node, 2 edges/half-wave + unroll ----------------
__device__ __forceinline__ f32x4 shfl_xor32_add(f32x4 a) {
    f32x4 r;
    r.x = a.x + __shfl_xor(a.x, 32, 64);
    r.y = a.y + __shfl_xor(a.y, 32, 64);
    r.z = a.z + __shfl_xor(a.z, 32, 64);
    r.w = a.w + __shfl_xor(a.w, 32, 64);
    return r;
}

__global__ __launch_bounds__(256) void aggregate_kernel(const int* __restrict__ offs,
                                                        const int* __restrict__ sorted,
                                                        const float* __restrict__ rcnt,
                                                        const unsigned short* __restrict__ x1b,
                                                        float* __restrict__ A2) {
    int lane = threadIdx.x & 63;
    int d = (blockIdx.x << 2) + (threadIdx.x >> 6);
    if (d >= NNODE) return;
    const int half = lane >> 5;     // which edge of a pair this lane serves
    const int sub  = lane & 31;     // column group: cols 4*sub..4*sub+3
    int beg = offs[d], end = offs[d + 1];
    f32x4 a0 = {0.f, 0.f, 0.f, 0.f}, a1 = a0, a2v = a0;
    auto proc = [&](int i) {
        int w = sorted[i];
        int s = w & 0xFFFF, r = (w >> 16) & 3;
        vus4 x = *(const vus4*)(x1b + ((size_t)s << 7) + (sub << 2));
        f32x4 v;
        v.x = __uint_as_float((unsigned)x.x << 16);
        v.y = __uint_as_float((unsigned)x.y << 16);
        v.z = __uint_as_float((unsigned)x.z << 16);
        v.w = __uint_as_float((unsigned)x.w << 16);
        if (r == 0) a0 += v; else if (r == 1) a1 += v; else a2v += v;
    };
    int i = beg;
    for (; i + 4 <= end; i += 4) { proc(i + half); proc(i + 2 + half); }  // 4 gathers in flight/wave
    if (i + 2 <= end) { proc(i + half); i += 2; }
    if (i + half < end) proc(i + half);
    // combine the two half-waves (same columns, different edges)
    a0  = shfl_xor32_add(a0);
    a1  = shfl_xor32_add(a1);
    a2v = shfl_xor32_add(a2v);
    if (half == 0) {
        float rc0 = rcnt[d * 4 + 0], rc1 = rcnt[d * 4 + 1], rc2 = rcnt[d * 4 + 2];
        float* o = &A2[(size_t)d * 512 + (sub << 2)];
        *(f32x4*)(o)       = a0 * rc0;
        *(f32x4*)(o + 128) = a1 * rc1;
        *(f32x4*)(o + 256) = a2v * rc2;
    }
}

// ---------------- layer-1 fused GEMM (fp32, 64x128 tile, 4x8 microtile) ----------------
__global__ __launch_bounds__(256) void gemm1_kernel(
    const float* __restrict__ A, const float* __restrict__ B,
    const float* __restrict__ rcnt,
    const int* __restrict__ shape_id, const int* __restrict__ color_id,
    const float* __restrict__ pos, const float* __restrict__ rootTab,
    const float* __restrict__ bias,
    float* __restrict__ Cout, unsigned short* __restrict__ x1b) {
    constexpr int K = K1, BM = 64, BK = 16;
    __shared__ float As[BK][BM + 4];
    __shared__ float Bs[BK][HIDD];
    const int t  = threadIdx.x;
    const int m0 = blockIdx.x * BM;
    const int tx = t & 15, ty = t >> 4;
    const int arow = t >> 2, ac4 = (t & 3) * 4;
    const int brow = t >> 4, bc = (t & 15) * 8;
    float acc[4][8] = {};
    for (int kt = 0; kt < K; kt += BK) {
        {
            int gr = m0 + arow;
            float4 v = make_float4(0.f, 0.f, 0.f, 0.f);
            if (gr < NNODE) {
                v = *(const float4*)&A[(size_t)gr * K + kt + ac4];
                float* vp = &v.x;
#pragma unroll
                for (int i = 0; i < 4; ++i) {
                    int kk = kt + ac4 + i;
                    int r = min(kk / 33, 3);
                    vp[i] *= rcnt[gr * 4 + r];
                }
            }
            As[ac4 + 0][arow] = v.x;
            As[ac4 + 1][arow] = v.y;
            As[ac4 + 2][arow] = v.z;
            As[ac4 + 3][arow] = v.w;
        }
        {
            const float4* src = (const float4*)&B[(size_t)(kt + brow) * HIDD + bc];
            *(float4*)&Bs[brow][bc]     = src[0];
            *(float4*)&Bs[brow][bc + 4] = src[1];
        }
        __syncthreads();
#pragma unroll
        for (int k = 0; k < BK; ++k) {
            float a[4], b[8];
            *(float4*)a      = *(const float4*)&As[k][ty * 4];
            *(float4*)&b[0]  = *(const float4*)&Bs[k][tx * 8];
            *(float4*)&b[4]  = *(const float4*)&Bs[k][tx * 8 + 4];
#pragma unroll
            for (int i = 0; i < 4; ++i)
#pragma unroll
                for (int j = 0; j < 8; ++j)
                    acc[i][j] = fmaf(a[i], b[j], acc[i][j]);
        }
        __syncthreads();
    }
#pragma unroll
    for (int i = 0; i < 4; ++i) {
        int gr = m0 + ty * 4 + i;
        if (gr >= NNODE) continue;
        int sid = shape_id[gr], cid = color_id[gr];
        float p = pos[gr];
        vshort8 p8;
#pragma unroll
        for (int j = 0; j < 8; ++j) {
            int h = tx * 8 + j;
            float v = acc[i][j] + rootTab[sid * 128 + h] + rootTab[(16 + cid) * 128 + h]
                    + p * rootTab[32 * 128 + h] + bias[h];
            float rv = fmaxf(v, 0.f);
            Cout[(size_t)gr * 512 + 384 + h] = rv;
            p8[j] = bf16_rne(rv);
        }
        *(vshort8*)&x1b[(size_t)gr * 128 + tx * 8] = p8;
    }
}

// ---------------- layer-2 GEMM: MFMA bf16x3 split (fp32-accurate) ----------------
__global__ __launch_bounds__(256) void gemm2_mfma_kernel(
    const float* __restrict__ A,
    const short* __restrict__ Bt_hi, const short* __restrict__ Bt_lo,
    const float* __restrict__ bias,
    float* __restrict__ x2) {
    __shared__ short Ah[4][128][8];
    __shared__ short Al[4][128][8];
    __shared__ short Bh[4][128][8];
    __shared__ short Bl[4][128][8];
    const int t    = threadIdx.x;
    const int lane = t & 63;
    const int w    = t >> 6;
    const int wm   = w >> 1, wn = w & 1;
    const int bm0  = blockIdx.x * 128;
    const int lr   = lane & 15, lk = lane >> 4;
    f32x4 acc[4][4] = {};
    for (int kt = 0; kt < K2; kt += 32) {
        __syncthreads();
#pragma unroll
        for (int p = 0; p < 4; ++p) {
            int idx = p * 256 + t;
            int row = idx >> 3;
            int kq  = (idx & 7) * 4;
            int gr  = bm0 + row;
            float4 v = make_float4(0.f, 0.f, 0.f, 0.f);
            if (gr < NNODE) v = *(const float4*)&A[(size_t)gr * K2 + kt + kq];
            vshort4 h4, l4;
            float* vp = &v.x;
#pragma unroll
            for (int i = 0; i < 4; ++i) { short hh, ll; split_bf16(vp[i], hh, ll); h4[i] = hh; l4[i] = ll; }
            int kb = kq >> 3, j0 = kq & 7;
            *(vshort4*)&Ah[kb][row][j0] = h4;
            *(vshort4*)&Al[kb][row][j0] = l4;
        }
#pragma unroll
        for (int p = 0; p < 2; ++p) {
            int idx = p * 256 + t;
            int n = idx >> 2, kb = idx & 3;
            *(vshort8*)&Bh[kb][n][0] = *(const vshort8*)&Bt_hi[(size_t)n * K2 + kt + kb * 8];
            *(vshort8*)&Bl[kb][n][0] = *(const vshort8*)&Bt_lo[(size_t)n * K2 + kt + kb * 8];
        }
        __syncthreads();
        vshort8 af_h[4], af_l[4], bf_h[4], bf_l[4];
#pragma unroll
        for (int f = 0; f < 4; ++f) {
            af_h[f] = *(const vshort8*)&Ah[lk][wm * 64 + f * 16 + lr][0];
            af_l[f] = *(const vshort8*)&Al[lk][wm * 64 + f * 16 + lr][0];
            bf_h[f] = *(const vshort8*)&Bh[lk][wn * 64 + f * 16 + lr][0];
            bf_l[f] = *(const vshort8*)&Bl[lk][wn * 64 + f * 16 + lr][0];
        }
#pragma unroll
        for (int mf = 0; mf < 4; ++mf)
#pragma unroll
            for (int nf = 0; nf < 4; ++nf) {
                acc[mf][nf] = __builtin_amdgcn_mfma_f32_16x16x32_bf16(af_h[mf], bf_h[nf], acc[mf][nf], 0, 0, 0);
                acc[mf][nf] = __builtin_amdgcn_mfma_f32_16x16x32_bf16(af_l[mf], bf_h[nf], acc[mf][nf], 0, 0, 0);
                acc[mf][nf] = __builtin_amdgcn_mfma_f32_16x16x32_bf16(af_h[mf], bf_l[nf], acc[mf][nf], 0, 0, 0);
            }
    }
#pragma unroll
    for (int mf = 0; mf < 4; ++mf) {
        int mb = bm0 + wm * 64 + mf * 16 + (lane >> 4) * 4;
#pragma unroll
        for (int nf = 0; nf < 4; ++nf) {
            int n = wn * 64 + nf * 16 + lr;
            float bn = bias[n];
#pragma unroll
            for (int r = 0; r < 4; ++r) {
                int gm = mb + r;
                if (gm < NNODE)
                    x2[(size_t)gm * HIDD + n] = fmaxf(acc[mf][nf][r] + bn, 0.f);
            }
        }
    }
}

// ---------------- pooling (batch sorted -> run-length reduce), 64 nodes/block ----------------
__global__ void pool_kernel(const float* __restrict__ x2, const int* __restrict__ batch,
                            float* __restrict__ pooled, float* __restrict__ cntg) {
    const int CH = 64;
    int h  = threadIdx.x; // 128
    int n0 = blockIdx.x * CH;
    if (n0 >= NNODE) return;
    int n1 = min(n0 + CH, NNODE);
    int cur = batch[n0];
    float acc = 0.f;
    int run = 0;
    for (int n = n0; n < n1; ++n) {
        int g = batch[n];
        if (g != cur) {
            atomicAdd(&pooled[cur * 128 + h], acc);
            if (h == 0) atomicAdd(&cntg[cur], (float)run);
            acc = 0.f; run = 0; cur = g;
        }
        acc += x2[(size_t)n * 128 + h];
        ++run;
    }
    atomicAdd(&pooled[cur * 128 + h], acc);
    if (h == 0) atomicAdd(&cntg[cur], (float)run);
}

__global__ void final_kernel(const float* __restrict__ pooled, const float* __restrict__ cntg,
                             const float* __restrict__ lin_w, const float* __restrict__ lin_b,
                             float* __restrict__ out) {
    int idx = blockIdx.x * blockDim.x + threadIdx.x;
    if (idx >= GNUM * 4) return;
    int g = idx >> 2, c = idx & 3;
    float dot = 0.f;
    for (int k = 0; k < 128; ++k) dot += pooled[g * 128 + k] * lin_w[k * 4 + c];
    out[idx] = dot / fmaxf(cntg[g], 1.f) + lin_b[c];
}

// ---------------- launch ----------------
extern "C" void kernel_launch(void* const* d_in, const int* in_sizes, int n_in,
                              void* d_out, int out_size, void* d_ws, size_t ws_size,
                              hipStream_t stream) {
    const float* pos      = (const float*)d_in[0];
    const int*   shape_id = (const int*)d_in[1];
    const int*   color_id = (const int*)d_in[2];
    const int*   ei       = (const int*)d_in[3];
    const int*   et       = (const int*)d_in[4];
    const int*   batch    = (const int*)d_in[5];
    const float* shape_w  = (const float*)d_in[6];
    const float* color_w  = (const float*)d_in[7];
    const float* W1       = (const float*)d_in[8];
    const float* root1    = (const float*)d_in[9];
    const float* b1       = (const float*)d_in[10];
    const float* W2       = (const float*)d_in[11];
    const float* root2    = (const float*)d_in[12];
    const float* b2       = (const float*)d_in[13];
    const float* lin_w    = (const float*)d_in[14];
    const float* lin_b    = (const float*)d_in[15];
    float* out = (float*)d_out;

    char* p = (char*)d_ws;
    auto alloc = [&](size_t bytes) { char* r = p; p += (bytes + 255) & ~(size_t)255; return r; };
    int*   cnt     = (int*)alloc((size_t)NNODE * 3 * 4);
    float* A1      = (float*)alloc((size_t)NNODE * K1 * 4);
    float* rcntBuf = (float*)alloc((size_t)NNODE * 4 * 4);
    float* A2      = (float*)alloc((size_t)NNODE * 512 * 4);
    float* x2      = (float*)alloc((size_t)NNODE * 128 * 4);
    unsigned short* x1b = (unsigned short*)alloc((size_t)NNODE * 128 * 2);
    float* B1eff   = (float*)alloc((size_t)K1 * 128 * 4);
    float* rootTab = (float*)alloc((size_t)33 * 128 * 4);
    short* Bt_hi   = (short*)alloc((size_t)128 * K2 * 2);
    short* Bt_lo   = (short*)alloc((size_t)128 * K2 * 2);
    float* pooled  = (float*)alloc((size_t)GNUM * 128 * 4);
    float* cntg    = (float*)alloc((size_t)GNUM * 4);
    int2*  nfTab   = (int2*)alloc((size_t)NNODE * 8);
    // CSR temporaries alias into x2 (all consumed before gemm2 writes x2)
    char* xb = (char*)x2;
    int* sorted     = (int*)(xb);                       // E ints = 2.56 MB
    int* offs       = (int*)(xb + 2600960);             // NNODE+1 ints
    int* cursor     = (int*)(xb + 2900992);             // NNODE ints
    int* partial    = (int*)(xb + 3200000);             // NB ints
    int* partialPre = (int*)(xb + 3210240);             // NB ints

    hipMemsetAsync(cnt,    0, (size_t)NNODE * 3 * 4, stream);
    hipMemsetAsync(B1eff,  0, (size_t)K1 * 128 * 4, stream);
    hipMemsetAsync(pooled, 0, (size_t)GNUM * 128 * 4, stream);
    hipMemsetAsync(cntg,   0, (size_t)GNUM * 4, stream);

    build_tabs_kernel<<<(4 * 33 * 128 + 255) / 256, 256, 0, stream>>>(
        shape_w, color_w, W1, root1, B1eff, rootTab);
    build_B2t_kernel<<<(K2 * 128 + 255) / 256, 256, 0, stream>>>(W2, root2, Bt_hi, Bt_lo);

    count_nf_kernel<<<(NEDGE + 255) / 256, 256, 0, stream>>>(
        ei, et, shape_id, color_id, pos, cnt, nfTab);
    scan_partial_kernel<<<NB, 256, 0, stream>>>(cnt, partial);
    scan_mid_kernel<<<1, 256, 0, stream>>>(partial, partialPre, offs);
    scan_final_kernel<<<NB, 256, 0, stream>>>(cnt, partialPre, offs, cursor, rcntBuf);
    fill_kernel<<<(NEDGE + 255) / 256, 256, 0, stream>>>(ei, et, cursor, sorted);

    hist1_kernel<<<(NNODE + 3) / 4, 256, 0, stream>>>(offs, sorted, nfTab, A1);

    gemm1_kernel<<<(NNODE + 63) / 64, 256, 0, stream>>>(
        A1, B1eff, rcntBuf, shape_id, color_id, pos, rootTab, b1, A2, x1b);

    aggregate_kernel<<<(NNODE + 3) / 4, 256, 0, stream>>>(offs, sorted, rcntBuf, x1b, A2);

    gemm2_mfma_kernel<<<(NNODE + 127) / 128, 256, 0, stream>>>(
        A2, Bt_hi, Bt_lo, b2, x2);

    pool_kernel<<<(NNODE + 63) / 64, 128, 0, stream>>>(x2, batch, pooled, cntg);

    final_kernel<<<(GNUM * 4 + 255) / 256, 256, 0, stream>>>(
        pooled, cntg, lin_w, lin_b, out);
}

// Round 7
// 262.619 us; speedup vs baseline: 1.4406x; 1.4406x over previous
//
#include <hip/hip_runtime.h>
#include <hip/hip_bf16.h>

#define NNODE 50000
#define NEDGE 640000
#define NREL  3
#define HIDD  128
#define GNUM  512
#define K1    112   // layer-1 GEMM K (99 used + 13 zero pad)
#define K2    512   // layer-2 GEMM K (3*128 relations + 128 root)
#define NB    196   // scan blocks = ceil(NNODE/256)

typedef float  f32x4   __attribute__((ext_vector_type(4)));
typedef short  vshort8 __attribute__((ext_vector_type(8)));
typedef short  vshort4 __attribute__((ext_vector_type(4)));

// ---------------- builders ----------------
__global__ void build_tabs_kernel(const float* __restrict__ shape_w,
                                  const float* __restrict__ color_w,
                                  const float* __restrict__ W1,
                                  const float* __restrict__ root1,
                                  float* __restrict__ B1eff,
                                  float* __restrict__ rootTab) {
    int idx = blockIdx.x * blockDim.x + threadIdx.x;
    if (idx >= 4 * 33 * 128) return;
    int h  = idx & 127;
    int j  = (idx >> 7) % 33;
    int rr = idx / (33 * 128);
    const float* Wsrc = (rr < 3) ? (W1 + (size_t)rr * 129 * 128) : root1; // [129][128]
    float v = 0.f;
    if (j < 16) {
        for (int e = 0; e < 64; ++e) v += shape_w[j * 64 + e] * Wsrc[e * 128 + h];
    } else if (j < 32) {
        int c = j - 16;
        for (int e = 0; e < 64; ++e) v += color_w[c * 64 + e] * Wsrc[(64 + e) * 128 + h];
    } else {
        v = Wsrc[128 * 128 + h];
    }
    if (rr < 3) B1eff[(rr * 33 + j) * 128 + h] = v;
    else        rootTab[j * 128 + h] = v;
}

__device__ __forceinline__ void split_bf16(float f, short& hi, short& lo) {
    unsigned u  = __float_as_uint(f);
    unsigned uh = (u + 0x7FFFu + ((u >> 16) & 1u)) >> 16;
    hi = (short)uh;
    float fl = f - __uint_as_float(uh << 16);
    unsigned ul  = __float_as_uint(fl);
    unsigned ulh = (ul + 0x7FFFu + ((ul >> 16) & 1u)) >> 16;
    lo = (short)ulh;
}

__device__ __forceinline__ short bf16_rne(float f) {
    unsigned u = __float_as_uint(f);
    return (short)((u + 0x7FFFu + ((u >> 16) & 1u)) >> 16);
}

// B2 transposed + split: Bt[n][k], k<384 -> W2, else root2
__global__ void build_B2t_kernel(const float* __restrict__ W2,
                                 const float* __restrict__ root2,
                                 short* __restrict__ Bt_hi,
                                 short* __restrict__ Bt_lo) {
    int idx = blockIdx.x * blockDim.x + threadIdx.x; // 512*128
    if (idx >= K2 * 128) return;
    int k = idx >> 7, n = idx & 127;
    float v = (k < 384) ? W2[idx] : root2[idx - 384 * 128];
    short h, l;
    split_bf16(v, h, l);
    Bt_hi[(size_t)n * K2 + k] = h;
    Bt_lo[(size_t)n * K2 + k] = l;
}

// ---------------- edge counting (1 int atomic/edge) + node-feature pack ----------------
__global__ void count_nf_kernel(const int* __restrict__ ei, const int* __restrict__ et,
                                const int* __restrict__ shape_id, const int* __restrict__ color_id,
                                const float* __restrict__ pos,
                                int* __restrict__ cnt, int2* __restrict__ nf) {
    int e = blockIdx.x * blockDim.x + threadIdx.x;
    if (e < NNODE) nf[e] = make_int2(shape_id[e] | (color_id[e] << 8), __float_as_int(pos[e]));
    if (e >= NEDGE) return;
    int d = ei[NEDGE + e], r = et[e];
    atomicAdd(&cnt[d * 3 + r], 1);
}

// ---------------- prefix scan over per-node degree (3-phase) ----------------
__global__ void scan_partial_kernel(const int* __restrict__ cnt, int* __restrict__ partial) {
    __shared__ int sh[256];
    int t = threadIdx.x, i = blockIdx.x * 256 + t;
    int v = (i < NNODE) ? cnt[3 * i] + cnt[3 * i + 1] + cnt[3 * i + 2] : 0;
    sh[t] = v; __syncthreads();
    for (int o = 128; o > 0; o >>= 1) { if (t < o) sh[t] += sh[t + o]; __syncthreads(); }
    if (t == 0) partial[blockIdx.x] = sh[0];
}

__global__ void scan_mid_kernel(const int* __restrict__ partial, int* __restrict__ partial_pre,
                                int* __restrict__ offs) {
    __shared__ int sh[256];
    int t = threadIdx.x;
    int v = (t < NB) ? partial[t] : 0;
    sh[t] = v; __syncthreads();
    for (int o = 1; o < 256; o <<= 1) {
        int x = (t >= o) ? sh[t - o] : 0; __syncthreads();
        sh[t] += x; __syncthreads();
    }
    if (t < NB) partial_pre[t] = sh[t] - v;
    if (t == 0) offs[NNODE] = NEDGE;
}

__global__ void scan_final_kernel(const int* __restrict__ cnt, const int* __restrict__ partial_pre,
                                  int* __restrict__ offs, int* __restrict__ cursor,
                                  float* __restrict__ rcnt) {
    __shared__ int sh[256];
    int t = threadIdx.x, i = blockIdx.x * 256 + t;
    int c0 = 0, c1 = 0, c2 = 0;
    if (i < NNODE) { c0 = cnt[3 * i]; c1 = cnt[3 * i + 1]; c2 = cnt[3 * i + 2]; }
    int v = c0 + c1 + c2;
    sh[t] = v; __syncthreads();
    for (int o = 1; o < 256; o <<= 1) {
        int x = (t >= o) ? sh[t - o] : 0; __syncthreads();
        sh[t] += x; __syncthreads();
    }
    int exc = sh[t] - v + partial_pre[blockIdx.x];
    if (i < NNODE) {
        offs[i] = exc; cursor[i] = exc;
        float4 rc = make_float4(1.f / fmaxf((float)c0, 1.f), 1.f / fmaxf((float)c1, 1.f),
                                1.f / fmaxf((float)c2, 1.f), 1.f);
        *(float4*)&rcnt[i * 4] = rc;
    }
}

// ---------------- fill: dst-sorted edge list, src|rel packed ----------------
__global__ void fill_kernel(const int* __restrict__ ei, const int* __restrict__ et,
                            int* __restrict__ cursor, int* __restrict__ sorted) {
    int e = blockIdx.x * blockDim.x + threadIdx.x;
    if (e >= NEDGE) return;
    int s = ei[e], d = ei[NEDGE + e], r = et[e];
    int p = atomicAdd(&cursor[d], 1);
    sorted[p] = s | (r << 16);   // NNODE < 65536, r < 4
}

// ---------------- layer-1 histogram: edge-parallel, per-wave LDS hist ----------------
__global__ __launch_bounds__(256) void hist1_kernel(const int* __restrict__ offs,
                                                    const int* __restrict__ sorted,
                                                    const int2* __restrict__ nf,
                                                    float* __restrict__ A1) {
    __shared__ float hist[4][3 * 34];
    int lane = threadIdx.x & 63;
    int wv   = threadIdx.x >> 6;
    int d    = (blockIdx.x << 2) + wv;
    float* hf = hist[wv];
    if (lane < 51) { hf[lane] = 0.f; hf[lane + 51] = 0.f; }
    if (d < NNODE) {
        int beg = offs[d], end = offs[d + 1];
        for (int i = beg + lane; i < end; i += 64) {
            int w = sorted[i];
            int s = w & 0xFFFF, r = (w >> 16) & 3;
            int2 f = nf[s];
            atomicAdd(&hf[r * 34 + (f.x & 0xFF)], 1.f);
            atomicAdd(&hf[r * 34 + 16 + (f.x >> 8)], 1.f);
            atomicAdd(&hf[r * 34 + 32], __int_as_float(f.y));
        }
        float* row = &A1[(size_t)d * K1];
        row[lane] = hf[(lane / 33) * 34 + lane % 33];           // lanes 0..63 < 99
        int j = lane + 64;                                      // 64..127
        if (j < K1)                                             // bound guard
            row[j] = (j < 99) ? hf[(j / 33) * 34 + j % 33] : 0.f;
    }
}

// ---------------- layer-2 aggregation: wave-per-node, scalar regs, 4-deep ILP ----------------
__global__ __launch_bounds__(256) void aggregate_kernel(const int* __restrict__ offs,
                                                        const int* __restrict__ sorted,
                                                        const float* __restrict__ rcnt,
                                                        const unsigned short* __restrict__ x1b,
                                                        float* __restrict__ A2) {
    int lane = threadIdx.x & 63;
    int d = (blockIdx.x << 2) + (threadIdx.x >> 6);
    if (d >= NNODE) return;
    int beg = __builtin_amdgcn_readfirstlane(offs[d]);
    int end = __builtin_amdgcn_readfirstlane(offs[d + 1]);
    const unsigned* xp = (const unsigned*)x1b;   // row = 64 unsigneds (2 bf16 each)
    // scalar accumulators only -- NO vector arrays, NO lambdas (r6 spill lesson)
    float a00 = 0.f, a01 = 0.f, a10 = 0.f, a11 = 0.f, a20 = 0.f, a21 = 0.f;
#define AGG_ACC(w, x) {                                             \
        int r_ = ((w) >> 16) & 3;                                   \
        float lo_ = __uint_as_float((x) << 16);                     \
        float hi_ = __uint_as_float((x) & 0xFFFF0000u);             \
        if (r_ == 0)      { a00 += lo_; a01 += hi_; }               \
        else if (r_ == 1) { a10 += lo_; a11 += hi_; }               \
        else              { a20 += lo_; a21 += hi_; } }
    int i = beg;
    for (; i + 4 <= end; i += 4) {
        int w0 = sorted[i], w1 = sorted[i + 1], w2 = sorted[i + 2], w3 = sorted[i + 3];
        unsigned x0 = xp[((unsigned)(w0 & 0xFFFF) << 6) + lane];
        unsigned x1 = xp[((unsigned)(w1 & 0xFFFF) << 6) + lane];
        unsigned x2 = xp[((unsigned)(w2 & 0xFFFF) << 6) + lane];
        unsigned x3 = xp[((unsigned)(w3 & 0xFFFF) << 6) + lane];
        AGG_ACC(w0, x0); AGG_ACC(w1, x1); AGG_ACC(w2, x2); AGG_ACC(w3, x3);
    }
    for (; i < end; ++i) {
        int w0 = sorted[i];
        unsigned x0 = xp[((unsigned)(w0 & 0xFFFF) << 6) + lane];
        AGG_ACC(w0, x0);
    }
#undef AGG_ACC
    float rc0 = rcnt[d * 4 + 0], rc1 = rcnt[d * 4 + 1], rc2 = rcnt[d * 4 + 2];
    float* o = &A2[(size_t)d * 512 + (lane << 1)];
    *(float2*)(o)       = make_float2(a00 * rc0, a01 * rc0);
    *(float2*)(o + 128) = make_float2(a10 * rc1, a11 * rc1);
    *(float2*)(o + 256) = make_float2(a20 * rc2, a21 * rc2);
}

// ---------------- layer-1 fused GEMM (fp32, 64x128 tile, 4x8 microtile) ----------------
__global__ __launch_bounds__(256) void gemm1_kernel(
    const float* __restrict__ A, const float* __restrict__ B,
    const float* __restrict__ rcnt,
    const int* __restrict__ shape_id, const int* __restrict__ color_id,
    const float* __restrict__ pos, const float* __restrict__ rootTab,
    const float* __restrict__ bias,
    float* __restrict__ Cout, unsigned short* __restrict__ x1b) {
    constexpr int K = K1, BM = 64, BK = 16;
    __shared__ float As[BK][BM + 4];
    __shared__ float Bs[BK][HIDD];
    const int t  = threadIdx.x;
    const int m0 = blockIdx.x * BM;
    const int tx = t & 15, ty = t >> 4;
    const int arow = t >> 2, ac4 = (t & 3) * 4;
    const int brow = t >> 4, bc = (t & 15) * 8;
    float acc[4][8] = {};
    for (int kt = 0; kt < K; kt += BK) {
        {
            int gr = m0 + arow;
            float4 v = make_float4(0.f, 0.f, 0.f, 0.f);
            if (gr < NNODE) {
                v = *(const float4*)&A[(size_t)gr * K + kt + ac4];
                float* vp = &v.x;
#pragma unroll
                for (int i = 0; i < 4; ++i) {
                    int kk = kt + ac4 + i;
                    int r = min(kk / 33, 3);
                    vp[i] *= rcnt[gr * 4 + r];
                }
            }
            As[ac4 + 0][arow] = v.x;
            As[ac4 + 1][arow] = v.y;
            As[ac4 + 2][arow] = v.z;
            As[ac4 + 3][arow] = v.w;
        }
        {
            const float4* src = (const float4*)&B[(size_t)(kt + brow) * HIDD + bc];
            *(float4*)&Bs[brow][bc]     = src[0];
            *(float4*)&Bs[brow][bc + 4] = src[1];
        }
        __syncthreads();
#pragma unroll
        for (int k = 0; k < BK; ++k) {
            float a[4], b[8];
            *(float4*)a      = *(const float4*)&As[k][ty * 4];
            *(float4*)&b[0]  = *(const float4*)&Bs[k][tx * 8];
            *(float4*)&b[4]  = *(const float4*)&Bs[k][tx * 8 + 4];
#pragma unroll
            for (int i = 0; i < 4; ++i)
#pragma unroll
                for (int j = 0; j < 8; ++j)
                    acc[i][j] = fmaf(a[i], b[j], acc[i][j]);
        }
        __syncthreads();
    }
#pragma unroll
    for (int i = 0; i < 4; ++i) {
        int gr = m0 + ty * 4 + i;
        if (gr >= NNODE) continue;
        int sid = shape_id[gr], cid = color_id[gr];
        float p = pos[gr];
        vshort8 p8;
#pragma unroll
        for (int j = 0; j < 8; ++j) {
            int h = tx * 8 + j;
            float v = acc[i][j] + rootTab[sid * 128 + h] + rootTab[(16 + cid) * 128 + h]
                    + p * rootTab[32 * 128 + h] + bias[h];
            float rv = fmaxf(v, 0.f);
            Cout[(size_t)gr * 512 + 384 + h] = rv;
            p8[j] = bf16_rne(rv);
        }
        *(vshort8*)&x1b[(size_t)gr * 128 + tx * 8] = p8;
    }
}

// ---------------- layer-2 GEMM: MFMA bf16x3 split (fp32-accurate) ----------------
__global__ __launch_bounds__(256) void gemm2_mfma_kernel(
    const float* __restrict__ A,
    const short* __restrict__ Bt_hi, const short* __restrict__ Bt_lo,
    const float* __restrict__ bias,
    float* __restrict__ x2) {
    __shared__ short Ah[4][128][8];
    __shared__ short Al[4][128][8];
    __shared__ short Bh[4][128][8];
    __shared__ short Bl[4][128][8];
    const int t    = threadIdx.x;
    const int lane = t & 63;
    const int w    = t >> 6;
    const int wm   = w >> 1, wn = w & 1;
    const int bm0  = blockIdx.x * 128;
    const int lr   = lane & 15, lk = lane >> 4;
    f32x4 acc[4][4] = {};
    for (int kt = 0; kt < K2; kt += 32) {
        __syncthreads();
#pragma unroll
        for (int p = 0; p < 4; ++p) {
            int idx = p * 256 + t;
            int row = idx >> 3;
            int kq  = (idx & 7) * 4;
            int gr  = bm0 + row;
            float4 v = make_float4(0.f, 0.f, 0.f, 0.f);
            if (gr < NNODE) v = *(const float4*)&A[(size_t)gr * K2 + kt + kq];
            vshort4 h4, l4;
            float* vp = &v.x;
#pragma unroll
            for (int i = 0; i < 4; ++i) { short hh, ll; split_bf16(vp[i], hh, ll); h4[i] = hh; l4[i] = ll; }
            int kb = kq >> 3, j0 = kq & 7;
            *(vshort4*)&Ah[kb][row][j0] = h4;
            *(vshort4*)&Al[kb][row][j0] = l4;
        }
#pragma unroll
        for (int p = 0; p < 2; ++p) {
            int idx = p * 256 + t;
            int n = idx >> 2, kb = idx & 3;
            *(vshort8*)&Bh[kb][n][0] = *(const vshort8*)&Bt_hi[(size_t)n * K2 + kt + kb * 8];
            *(vshort8*)&Bl[kb][n][0] = *(const vshort8*)&Bt_lo[(size_t)n * K2 + kt + kb * 8];
        }
        __syncthreads();
        vshort8 af_h[4], af_l[4], bf_h[4], bf_l[4];
#pragma unroll
        for (int f = 0; f < 4; ++f) {
            af_h[f] = *(const vshort8*)&Ah[lk][wm * 64 + f * 16 + lr][0];
            af_l[f] = *(const vshort8*)&Al[lk][wm * 64 + f * 16 + lr][0];
            bf_h[f] = *(const vshort8*)&Bh[lk][wn * 64 + f * 16 + lr][0];
            bf_l[f] = *(const vshort8*)&Bl[lk][wn * 64 + f * 16 + lr][0];
        }
#pragma unroll
        for (int mf = 0; mf < 4; ++mf)
#pragma unroll
            for (int nf = 0; nf < 4; ++nf) {
                acc[mf][nf] = __builtin_amdgcn_mfma_f32_16x16x32_bf16(af_h[mf], bf_h[nf], acc[mf][nf], 0, 0, 0);
                acc[mf][nf] = __builtin_amdgcn_mfma_f32_16x16x32_bf16(af_l[mf], bf_h[nf], acc[mf][nf], 0, 0, 0);
                acc[mf][nf] = __builtin_amdgcn_mfma_f32_16x16x32_bf16(af_h[mf], bf_l[nf], acc[mf][nf], 0, 0, 0);
            }
    }
#pragma unroll
    for (int mf = 0; mf < 4; ++mf) {
        int mb = bm0 + wm * 64 + mf * 16 + (lane >> 4) * 4;
#pragma unroll
        for (int nf = 0; nf < 4; ++nf) {
            int n = wn * 64 + nf * 16 + lr;
            float bn = bias[n];
#pragma unroll
            for (int r = 0; r < 4; ++r) {
                int gm = mb + r;
                if (gm < NNODE)
                    x2[(size_t)gm * HIDD + n] = fmaxf(acc[mf][nf][r] + bn, 0.f);
            }
        }
    }
}

// ---------------- pooling (batch sorted -> run-length reduce), 64 nodes/block ----------------
__global__ void pool_kernel(const float* __restrict__ x2, const int* __restrict__ batch,
                            float* __restrict__ pooled, float* __restrict__ cntg) {
    const int CH = 64;
    int h  = threadIdx.x; // 128
    int n0 = blockIdx.x * CH;
    if (n0 >= NNODE) return;
    int n1 = min(n0 + CH, NNODE);
    int cur = batch[n0];
    float acc = 0.f;
    int run = 0;
    for (int n = n0; n < n1; ++n) {
        int g = batch[n];
        if (g != cur) {
            atomicAdd(&pooled[cur * 128 + h], acc);
            if (h == 0) atomicAdd(&cntg[cur], (float)run);
            acc = 0.f; run = 0; cur = g;
        }
        acc += x2[(size_t)n * 128 + h];
        ++run;
    }
    atomicAdd(&pooled[cur * 128 + h], acc);
    if (h == 0) atomicAdd(&cntg[cur], (float)run);
}

__global__ void final_kernel(const float* __restrict__ pooled, const float* __restrict__ cntg,
                             const float* __restrict__ lin_w, const float* __restrict__ lin_b,
                             float* __restrict__ out) {
    int idx = blockIdx.x * blockDim.x + threadIdx.x;
    if (idx >= GNUM * 4) return;
    int g = idx >> 2, c = idx & 3;
    float dot = 0.f;
    for (int k = 0; k < 128; ++k) dot += pooled[g * 128 + k] * lin_w[k * 4 + c];
    out[idx] = dot / fmaxf(cntg[g], 1.f) + lin_b[c];
}

// ---------------- launch ----------------
extern "C" void kernel_launch(void* const* d_in, const int* in_sizes, int n_in,
                              void* d_out, int out_size, void* d_ws, size_t ws_size,
                              hipStream_t stream) {
    const float* pos      = (const float*)d_in[0];
    const int*   shape_id = (const int*)d_in[1];
    const int*   color_id = (const int*)d_in[2];
    const int*   ei       = (const int*)d_in[3];
    const int*   et       = (const int*)d_in[4];
    const int*   batch    = (const int*)d_in[5];
    const float* shape_w  = (const float*)d_in[6];
    const float* color_w  = (const float*)d_in[7];
    const float* W1       = (const float*)d_in[8];
    const float* root1    = (const float*)d_in[9];
    const float* b1       = (const float*)d_in[10];
    const float* W2       = (const float*)d_in[11];
    const float* root2    = (const float*)d_in[12];
    const float* b2       = (const float*)d_in[13];
    const float* lin_w    = (const float*)d_in[14];
    const float* lin_b    = (const float*)d_in[15];
    float* out = (float*)d_out;

    char* p = (char*)d_ws;
    auto alloc = [&](size_t bytes) { char* r = p; p += (bytes + 255) & ~(size_t)255; return r; };
    int*   cnt     = (int*)alloc((size_t)NNODE * 3 * 4);
    float* A1      = (float*)alloc((size_t)NNODE * K1 * 4);
    float* rcntBuf = (float*)alloc((size_t)NNODE * 4 * 4);
    float* A2      = (float*)alloc((size_t)NNODE * 512 * 4);
    float* x2      = (float*)alloc((size_t)NNODE * 128 * 4);
    unsigned short* x1b = (unsigned short*)alloc((size_t)NNODE * 128 * 2);
    float* B1eff   = (float*)alloc((size_t)K1 * 128 * 4);
    float* rootTab = (float*)alloc((size_t)33 * 128 * 4);
    short* Bt_hi   = (short*)alloc((size_t)128 * K2 * 2);
    short* Bt_lo   = (short*)alloc((size_t)128 * K2 * 2);
    float* pooled  = (float*)alloc((size_t)GNUM * 128 * 4);
    float* cntg    = (float*)alloc((size_t)GNUM * 4);
    int2*  nfTab   = (int2*)alloc((size_t)NNODE * 8);
    // CSR temporaries alias into x2 (all consumed before gemm2 writes x2)
    char* xb = (char*)x2;
    int* sorted     = (int*)(xb);                       // E ints = 2.56 MB
    int* offs       = (int*)(xb + 2600960);             // NNODE+1 ints
    int* cursor     = (int*)(xb + 2900992);             // NNODE ints
    int* partial    = (int*)(xb + 3200000);             // NB ints
    int* partialPre = (int*)(xb + 3210240);             // NB ints

    hipMemsetAsync(cnt,    0, (size_t)NNODE * 3 * 4, stream);
    hipMemsetAsync(B1eff,  0, (size_t)K1 * 128 * 4, stream);
    hipMemsetAsync(pooled, 0, (size_t)GNUM * 128 * 4, stream);
    hipMemsetAsync(cntg,   0, (size_t)GNUM * 4, stream);

    build_tabs_kernel<<<(4 * 33 * 128 + 255) / 256, 256, 0, stream>>>(
        shape_w, color_w, W1, root1, B1eff, rootTab);
    build_B2t_kernel<<<(K2 * 128 + 255) / 256, 256, 0, stream>>>(W2, root2, Bt_hi, Bt_lo);

    count_nf_kernel<<<(NEDGE + 255) / 256, 256, 0, stream>>>(
        ei, et, shape_id, color_id, pos, cnt, nfTab);
    scan_partial_kernel<<<NB, 256, 0, stream>>>(cnt, partial);
    scan_mid_kernel<<<1, 256, 0, stream>>>(partial, partialPre, offs);
    scan_final_kernel<<<NB, 256, 0, stream>>>(cnt, partialPre, offs, cursor, rcntBuf);
    fill_kernel<<<(NEDGE + 255) / 256, 256, 0, stream>>>(ei, et, cursor, sorted);

    hist1_kernel<<<(NNODE + 3) / 4, 256, 0, stream>>>(offs, sorted, nfTab, A1);

    gemm1_kernel<<<(NNODE + 63) / 64, 256, 0, stream>>>(
        A1, B1eff, rcntBuf, shape_id, color_id, pos, rootTab, b1, A2, x1b);

    aggregate_kernel<<<(NNODE + 3) / 4, 256, 0, stream>>>(offs, sorted, rcntBuf, x1b, A2);

    gemm2_mfma_kernel<<<(NNODE + 127) / 128, 256, 0, stream>>>(
        A2, Bt_hi, Bt_lo, b2, x2);

    pool_kernel<<<(NNODE + 63) / 64, 128, 0, stream>>>(x2, batch, pooled, cntg);

    final_kernel<<<(GNUM * 4 + 255) / 256, 256, 0, stream>>>(
        pooled, cntg, lin_w, lin_b, out);
}

// Round 8
// 247.655 us; speedup vs baseline: 1.5277x; 1.0604x over previous
//
#include <hip/hip_runtime.h>
#include <hip/hip_bf16.h>

#define NNODE 50000
#define NEDGE 640000
#define NREL  3
#define HIDD  128
#define GNUM  512
#define K1    112   // layer-1 GEMM K (99 used + 13 zero pad)
#define K2    512   // layer-2 GEMM K (3*128 relations + 128 root)
#define NB    196   // scan blocks = ceil(NNODE/256)

typedef float  f32x4   __attribute__((ext_vector_type(4)));
typedef short  vshort8 __attribute__((ext_vector_type(8)));
typedef short  vshort4 __attribute__((ext_vector_type(4)));

// swizzled k-block position within a 32-short row: spreads ds_read_b128 rows
// across all 32 banks (verified: 8 consecutive rows -> 8 distinct 4-bank sets)
#define SWZ(row, kb) ((((kb) ^ (((row) >> 1) & 3)) << 3))

// ---------------- builders ----------------
__global__ void build_tabs_kernel(const float* __restrict__ shape_w,
                                  const float* __restrict__ color_w,
                                  const float* __restrict__ W1,
                                  const float* __restrict__ root1,
                                  float* __restrict__ B1eff,
                                  float* __restrict__ rootTab) {
    int idx = blockIdx.x * blockDim.x + threadIdx.x;
    if (idx >= 4 * 33 * 128) return;
    int h  = idx & 127;
    int j  = (idx >> 7) % 33;
    int rr = idx / (33 * 128);
    const float* Wsrc = (rr < 3) ? (W1 + (size_t)rr * 129 * 128) : root1; // [129][128]
    float v = 0.f;
    if (j < 16) {
        for (int e = 0; e < 64; ++e) v += shape_w[j * 64 + e] * Wsrc[e * 128 + h];
    } else if (j < 32) {
        int c = j - 16;
        for (int e = 0; e < 64; ++e) v += color_w[c * 64 + e] * Wsrc[(64 + e) * 128 + h];
    } else {
        v = Wsrc[128 * 128 + h];
    }
    if (rr < 3) B1eff[(rr * 33 + j) * 128 + h] = v;
    else        rootTab[j * 128 + h] = v;
}

__device__ __forceinline__ void split_bf16(float f, short& hi, short& lo) {
    unsigned u  = __float_as_uint(f);
    unsigned uh = (u + 0x7FFFu + ((u >> 16) & 1u)) >> 16;
    hi = (short)uh;
    float fl = f - __uint_as_float(uh << 16);
    unsigned ul  = __float_as_uint(fl);
    unsigned ulh = (ul + 0x7FFFu + ((ul >> 16) & 1u)) >> 16;
    lo = (short)ulh;
}

__device__ __forceinline__ short bf16_rne(float f) {
    unsigned u = __float_as_uint(f);
    return (short)((u + 0x7FFFu + ((u >> 16) & 1u)) >> 16);
}

// B2 transposed + split: Bt[n][k], k<384 -> W2, else root2
__global__ void build_B2t_kernel(const float* __restrict__ W2,
                                 const float* __restrict__ root2,
                                 short* __restrict__ Bt_hi,
                                 short* __restrict__ Bt_lo) {
    int idx = blockIdx.x * blockDim.x + threadIdx.x; // 512*128
    if (idx >= K2 * 128) return;
    int k = idx >> 7, n = idx & 127;
    float v = (k < 384) ? W2[idx] : root2[idx - 384 * 128];
    short h, l;
    split_bf16(v, h, l);
    Bt_hi[(size_t)n * K2 + k] = h;
    Bt_lo[(size_t)n * K2 + k] = l;
}

// ---------------- edge counting (1 int atomic/edge) + node-feature pack ----------------
__global__ void count_nf_kernel(const int* __restrict__ ei, const int* __restrict__ et,
                                const int* __restrict__ shape_id, const int* __restrict__ color_id,
                                const float* __restrict__ pos,
                                int* __restrict__ cnt, int2* __restrict__ nf) {
    int e = blockIdx.x * blockDim.x + threadIdx.x;
    if (e < NNODE) nf[e] = make_int2(shape_id[e] | (color_id[e] << 8), __float_as_int(pos[e]));
    if (e >= NEDGE) return;
    int d = ei[NEDGE + e], r = et[e];
    atomicAdd(&cnt[d * 3 + r], 1);
}

// ---------------- prefix scan over per-node degree (3-phase) ----------------
__global__ void scan_partial_kernel(const int* __restrict__ cnt, int* __restrict__ partial) {
    __shared__ int sh[256];
    int t = threadIdx.x, i = blockIdx.x * 256 + t;
    int v = (i < NNODE) ? cnt[3 * i] + cnt[3 * i + 1] + cnt[3 * i + 2] : 0;
    sh[t] = v; __syncthreads();
    for (int o = 128; o > 0; o >>= 1) { if (t < o) sh[t] += sh[t + o]; __syncthreads(); }
    if (t == 0) partial[blockIdx.x] = sh[0];
}

__global__ void scan_mid_kernel(const int* __restrict__ partial, int* __restrict__ partial_pre,
                                int* __restrict__ offs) {
    __shared__ int sh[256];
    int t = threadIdx.x;
    int v = (t < NB) ? partial[t] : 0;
    sh[t] = v; __syncthreads();
    for (int o = 1; o < 256; o <<= 1) {
        int x = (t >= o) ? sh[t - o] : 0; __syncthreads();
        sh[t] += x; __syncthreads();
    }
    if (t < NB) partial_pre[t] = sh[t] - v;
    if (t == 0) offs[NNODE] = NEDGE;
}

__global__ void scan_final_kernel(const int* __restrict__ cnt, const int* __restrict__ partial_pre,
                                  int* __restrict__ offs, int* __restrict__ cursor,
                                  float* __restrict__ rcnt) {
    __shared__ int sh[256];
    int t = threadIdx.x, i = blockIdx.x * 256 + t;
    int c0 = 0, c1 = 0, c2 = 0;
    if (i < NNODE) { c0 = cnt[3 * i]; c1 = cnt[3 * i + 1]; c2 = cnt[3 * i + 2]; }
    int v = c0 + c1 + c2;
    sh[t] = v; __syncthreads();
    for (int o = 1; o < 256; o <<= 1) {
        int x = (t >= o) ? sh[t - o] : 0; __syncthreads();
        sh[t] += x; __syncthreads();
    }
    int exc = sh[t] - v + partial_pre[blockIdx.x];
    if (i < NNODE) {
        offs[i] = exc; cursor[i] = exc;
        float4 rc = make_float4(1.f / fmaxf((float)c0, 1.f), 1.f / fmaxf((float)c1, 1.f),
                                1.f / fmaxf((float)c2, 1.f), 1.f);
        *(float4*)&rcnt[i * 4] = rc;
    }
}

// ---------------- fill: dst-sorted edge list, src|rel packed ----------------
__global__ void fill_kernel(const int* __restrict__ ei, const int* __restrict__ et,
                            int* __restrict__ cursor, int* __restrict__ sorted) {
    int e = blockIdx.x * blockDim.x + threadIdx.x;
    if (e >= NEDGE) return;
    int s = ei[e], d = ei[NEDGE + e], r = et[e];
    int p = atomicAdd(&cursor[d], 1);
    sorted[p] = s | (r << 16);   // NNODE < 65536, r < 4
}

// ---------------- layer-1 histogram: edge-parallel, per-wave LDS hist ----------------
__global__ __launch_bounds__(256) void hist1_kernel(const int* __restrict__ offs,
                                                    const int* __restrict__ sorted,
                                                    const int2* __restrict__ nf,
                                                    float* __restrict__ A1) {
    __shared__ float hist[4][3 * 34];
    int lane = threadIdx.x & 63;
    int wv   = threadIdx.x >> 6;
    int d    = (blockIdx.x << 2) + wv;
    float* hf = hist[wv];
    if (lane < 51) { hf[lane] = 0.f; hf[lane + 51] = 0.f; }
    if (d < NNODE) {
        int beg = offs[d], end = offs[d + 1];
        for (int i = beg + lane; i < end; i += 64) {
            int w = sorted[i];
            int s = w & 0xFFFF, r = (w >> 16) & 3;
            int2 f = nf[s];
            atomicAdd(&hf[r * 34 + (f.x & 0xFF)], 1.f);
            atomicAdd(&hf[r * 34 + 16 + (f.x >> 8)], 1.f);
            atomicAdd(&hf[r * 34 + 32], __int_as_float(f.y));
        }
        float* row = &A1[(size_t)d * K1];
        row[lane] = hf[(lane / 33) * 34 + lane % 33];           // lanes 0..63 < 99
        int j = lane + 64;                                      // 64..127
        if (j < K1)                                             // bound guard
            row[j] = (j < 99) ? hf[(j / 33) * 34 + j % 33] : 0.f;
    }
}

// ---------------- layer-2 aggregation: wave-per-node, scalar regs, 4-deep ILP ----------------
// reads x1 (bf16-hi) from A2h root block; writes per-rel means split hi/lo.
__global__ __launch_bounds__(256) void aggregate_kernel(const int* __restrict__ offs,
                                                        const int* __restrict__ sorted,
                                                        const float* __restrict__ rcnt,
                                                        unsigned short* __restrict__ A2h,
                                                        unsigned short* __restrict__ A2l) {
    int lane = threadIdx.x & 63;
    int d = (blockIdx.x << 2) + (threadIdx.x >> 6);
    if (d >= NNODE) return;
    int beg = __builtin_amdgcn_readfirstlane(offs[d]);
    int end = __builtin_amdgcn_readfirstlane(offs[d + 1]);
    const unsigned* xp = (const unsigned*)A2h;   // row = 256 unsigneds; root block at +192
    float a00 = 0.f, a01 = 0.f, a10 = 0.f, a11 = 0.f, a20 = 0.f, a21 = 0.f;
#define AGG_ACC(w, x) {                                             \
        int r_ = ((w) >> 16) & 3;                                   \
        float lo_ = __uint_as_float((x) << 16);                     \
        float hi_ = __uint_as_float((x) & 0xFFFF0000u);             \
        if (r_ == 0)      { a00 += lo_; a01 += hi_; }               \
        else if (r_ == 1) { a10 += lo_; a11 += hi_; }               \
        else              { a20 += lo_; a21 += hi_; } }
    int i = beg;
    for (; i + 4 <= end; i += 4) {
        int w0 = sorted[i], w1 = sorted[i + 1], w2 = sorted[i + 2], w3 = sorted[i + 3];
        unsigned x0 = xp[((size_t)(unsigned)(w0 & 0xFFFF) << 8) + 192 + lane];
        unsigned x1 = xp[((size_t)(unsigned)(w1 & 0xFFFF) << 8) + 192 + lane];
        unsigned x2 = xp[((size_t)(unsigned)(w2 & 0xFFFF) << 8) + 192 + lane];
        unsigned x3 = xp[((size_t)(unsigned)(w3 & 0xFFFF) << 8) + 192 + lane];
        AGG_ACC(w0, x0); AGG_ACC(w1, x1); AGG_ACC(w2, x2); AGG_ACC(w3, x3);
    }
    for (; i < end; ++i) {
        int w0 = sorted[i];
        unsigned x0 = xp[((size_t)(unsigned)(w0 & 0xFFFF) << 8) + 192 + lane];
        AGG_ACC(w0, x0);
    }
#undef AGG_ACC
    float rc0 = rcnt[d * 4 + 0], rc1 = rcnt[d * 4 + 1], rc2 = rcnt[d * 4 + 2];
    // write 2 cols per rel, split hi/lo
    size_t base = (size_t)d * 512 + (lane << 1);
#define AGG_OUT(vA, vB, rel) {                                        \
        short h0_, l0_, h1_, l1_;                                     \
        split_bf16(vA, h0_, l0_); split_bf16(vB, h1_, l1_);           \
        *(unsigned*)&A2h[base + (rel) * 128] =                        \
            (unsigned)(unsigned short)h0_ | ((unsigned)(unsigned short)h1_ << 16); \
        *(unsigned*)&A2l[base + (rel) * 128] =                        \
            (unsigned)(unsigned short)l0_ | ((unsigned)(unsigned short)l1_ << 16); }
    AGG_OUT(a00 * rc0, a01 * rc0, 0);
    AGG_OUT(a10 * rc1, a11 * rc1, 1);
    AGG_OUT(a20 * rc2, a21 * rc2, 2);
#undef AGG_OUT
}

// ---------------- layer-1 fused GEMM (fp32, 64x128 tile, 4x8 microtile) ----------------
// epilogue: relu, split to bf16 hi/lo, write A2h/A2l root block (cols 384..511)
__global__ __launch_bounds__(256) void gemm1_kernel(
    const float* __restrict__ A, const float* __restrict__ B,
    const float* __restrict__ rcnt,
    const int* __restrict__ shape_id, const int* __restrict__ color_id,
    const float* __restrict__ pos, const float* __restrict__ rootTab,
    const float* __restrict__ bias,
    unsigned short* __restrict__ A2h, unsigned short* __restrict__ A2l) {
    constexpr int K = K1, BM = 64, BK = 16;
    __shared__ float As[BK][BM + 4];
    __shared__ float Bs[BK][HIDD];
    const int t  = threadIdx.x;
    const int m0 = blockIdx.x * BM;
    const int tx = t & 15, ty = t >> 4;
    const int arow = t >> 2, ac4 = (t & 3) * 4;
    const int brow = t >> 4, bc = (t & 15) * 8;
    float acc[4][8] = {};
    for (int kt = 0; kt < K; kt += BK) {
        {
            int gr = m0 + arow;
            float4 v = make_float4(0.f, 0.f, 0.f, 0.f);
            if (gr < NNODE) {
                v = *(const float4*)&A[(size_t)gr * K + kt + ac4];
                float* vp = &v.x;
#pragma unroll
                for (int i = 0; i < 4; ++i) {
                    int kk = kt + ac4 + i;
                    int r = min(kk / 33, 3);
                    vp[i] *= rcnt[gr * 4 + r];
                }
            }
            As[ac4 + 0][arow] = v.x;
            As[ac4 + 1][arow] = v.y;
            As[ac4 + 2][arow] = v.z;
            As[ac4 + 3][arow] = v.w;
        }
        {
            const float4* src = (const float4*)&B[(size_t)(kt + brow) * HIDD + bc];
            *(float4*)&Bs[brow][bc]     = src[0];
            *(float4*)&Bs[brow][bc + 4] = src[1];
        }
        __syncthreads();
#pragma unroll
        for (int k = 0; k < BK; ++k) {
            float a[4], b[8];
            *(float4*)a      = *(const float4*)&As[k][ty * 4];
            *(float4*)&b[0]  = *(const float4*)&Bs[k][tx * 8];
            *(float4*)&b[4]  = *(const float4*)&Bs[k][tx * 8 + 4];
#pragma unroll
            for (int i = 0; i < 4; ++i)
#pragma unroll
                for (int j = 0; j < 8; ++j)
                    acc[i][j] = fmaf(a[i], b[j], acc[i][j]);
        }
        __syncthreads();
    }
#pragma unroll
    for (int i = 0; i < 4; ++i) {
        int gr = m0 + ty * 4 + i;
        if (gr >= NNODE) continue;
        int sid = shape_id[gr], cid = color_id[gr];
        float p = pos[gr];
        vshort8 p8, l8;
#pragma unroll
        for (int j = 0; j < 8; ++j) {
            int h = tx * 8 + j;
            float v = acc[i][j] + rootTab[sid * 128 + h] + rootTab[(16 + cid) * 128 + h]
                    + p * rootTab[32 * 128 + h] + bias[h];
            float rv = fmaxf(v, 0.f);
            short hh = bf16_rne(rv);
            p8[j] = hh;
            float hf = __uint_as_float((unsigned)(unsigned short)hh << 16);
            l8[j] = bf16_rne(rv - hf);
        }
        *(vshort8*)&A2h[(size_t)gr * 512 + 384 + tx * 8] = p8;
        *(vshort8*)&A2l[(size_t)gr * 512 + 384 + tx * 8] = l8;
    }
}

// ---------------- layer-2 GEMM: MFMA bf16x3, BM=64, swizzled LDS, pre-split A ----------------
__global__ __launch_bounds__(256) void gemm2_mfma_kernel(
    const unsigned short* __restrict__ A2h, const unsigned short* __restrict__ A2l,
    const short* __restrict__ Bt_hi, const short* __restrict__ Bt_lo,
    const float* __restrict__ bias,
    float* __restrict__ x2) {
    __shared__ short Ah[64][32];   // [row][swizzled k] bf16-hi
    __shared__ short Al[64][32];
    __shared__ short Bh[128][32];
    __shared__ short Bl[128][32];
    const int t    = threadIdx.x;
    const int lane = t & 63;
    const int w    = t >> 6;
    const int wm   = w >> 1, wn = w & 1;     // wave tile 32(M) x 64(N)
    const int bm0  = blockIdx.x * 64;
    const int lr   = lane & 15, lk = lane >> 4;
    // staging assignment: thread covers (row = t>>2, kb = t&3)
    const int sr = t >> 2, skb = t & 3;
    int gra = bm0 + sr; if (gra >= NNODE) gra = NNODE - 1;   // clamp (C-write guarded)
    f32x4 acc[2][4] = {};
    for (int kt = 0; kt < K2; kt += 32) {
        vshort8 avh = *(const vshort8*)&A2h[(size_t)gra * K2 + kt + skb * 8];
        vshort8 avl = *(const vshort8*)&A2l[(size_t)gra * K2 + kt + skb * 8];
        vshort8 bvh0 = *(const vshort8*)&Bt_hi[(size_t)sr * K2 + kt + skb * 8];
        vshort8 bvh1 = *(const vshort8*)&Bt_hi[(size_t)(sr + 64) * K2 + kt + skb * 8];
        vshort8 bvl0 = *(const vshort8*)&Bt_lo[(size_t)sr * K2 + kt + skb * 8];
        vshort8 bvl1 = *(const vshort8*)&Bt_lo[(size_t)(sr + 64) * K2 + kt + skb * 8];
        __syncthreads();
        *(vshort8*)&Ah[sr][SWZ(sr, skb)]           = avh;
        *(vshort8*)&Al[sr][SWZ(sr, skb)]           = avl;
        *(vshort8*)&Bh[sr][SWZ(sr, skb)]           = bvh0;
        *(vshort8*)&Bh[sr + 64][SWZ(sr + 64, skb)] = bvh1;
        *(vshort8*)&Bl[sr][SWZ(sr, skb)]           = bvl0;
        *(vshort8*)&Bl[sr + 64][SWZ(sr + 64, skb)] = bvl1;
        __syncthreads();
        vshort8 afh[2], afl[2], bfh[4], bfl[4];
#pragma unroll
        for (int mf = 0; mf < 2; ++mf) {
            int row = wm * 32 + mf * 16 + lr;
            afh[mf] = *(const vshort8*)&Ah[row][SWZ(row, lk)];
            afl[mf] = *(const vshort8*)&Al[row][SWZ(row, lk)];
        }
#pragma unroll
        for (int nf = 0; nf < 4; ++nf) {
            int row = wn * 64 + nf * 16 + lr;
            bfh[nf] = *(const vshort8*)&Bh[row][SWZ(row, lk)];
            bfl[nf] = *(const vshort8*)&Bl[row][SWZ(row, lk)];
        }
#pragma unroll
        for (int mf = 0; mf < 2; ++mf)
#pragma unroll
            for (int nf = 0; nf < 4; ++nf) {
                acc[mf][nf] = __builtin_amdgcn_mfma_f32_16x16x32_bf16(afh[mf], bfh[nf], acc[mf][nf], 0, 0, 0);
                acc[mf][nf] = __builtin_amdgcn_mfma_f32_16x16x32_bf16(afl[mf], bfh[nf], acc[mf][nf], 0, 0, 0);
                acc[mf][nf] = __builtin_amdgcn_mfma_f32_16x16x32_bf16(afh[mf], bfl[nf], acc[mf][nf], 0, 0, 0);
            }
    }
#pragma unroll
    for (int mf = 0; mf < 2; ++mf) {
        int mb = bm0 + wm * 32 + mf * 16 + (lane >> 4) * 4;
#pragma unroll
        for (int nf = 0; nf < 4; ++nf) {
            int n = wn * 64 + nf * 16 + lr;
            float bn = bias[n];
#pragma unroll
            for (int r = 0; r < 4; ++r) {
                int gm = mb + r;
                if (gm < NNODE)
                    x2[(size_t)gm * HIDD + n] = fmaxf(acc[mf][nf][r] + bn, 0.f);
            }
        }
    }
}

// ---------------- pooling (batch sorted -> run-length reduce), 64 nodes/block ----------------
__global__ void pool_kernel(const float* __restrict__ x2, const int* __restrict__ batch,
                            float* __restrict__ pooled, float* __restrict__ cntg) {
    const int CH = 64;
    int h  = threadIdx.x; // 128
    int n0 = blockIdx.x * CH;
    if (n0 >= NNODE) return;
    int n1 = min(n0 + CH, NNODE);
    int cur = batch[n0];
    float acc = 0.f;
    int run = 0;
    for (int n = n0; n < n1; ++n) {
        int g = batch[n];
        if (g != cur) {
            atomicAdd(&pooled[cur * 128 + h], acc);
            if (h == 0) atomicAdd(&cntg[cur], (float)run);
            acc = 0.f; run = 0; cur = g;
        }
        acc += x2[(size_t)n * 128 + h];
        ++run;
    }
    atomicAdd(&pooled[cur * 128 + h], acc);
    if (h == 0) atomicAdd(&cntg[cur], (float)run);
}

__global__ void final_kernel(const float* __restrict__ pooled, const float* __restrict__ cntg,
                             const float* __restrict__ lin_w, const float* __restrict__ lin_b,
                             float* __restrict__ out) {
    int idx = blockIdx.x * blockDim.x + threadIdx.x;
    if (idx >= GNUM * 4) return;
    int g = idx >> 2, c = idx & 3;
    float dot = 0.f;
    for (int k = 0; k < 128; ++k) dot += pooled[g * 128 + k] * lin_w[k * 4 + c];
    out[idx] = dot / fmaxf(cntg[g], 1.f) + lin_b[c];
}

// ---------------- launch ----------------
extern "C" void kernel_launch(void* const* d_in, const int* in_sizes, int n_in,
                              void* d_out, int out_size, void* d_ws, size_t ws_size,
                              hipStream_t stream) {
    const float* pos      = (const float*)d_in[0];
    const int*   shape_id = (const int*)d_in[1];
    const int*   color_id = (const int*)d_in[2];
    const int*   ei       = (const int*)d_in[3];
    const int*   et       = (const int*)d_in[4];
    const int*   batch    = (const int*)d_in[5];
    const float* shape_w  = (const float*)d_in[6];
    const float* color_w  = (const float*)d_in[7];
    const float* W1       = (const float*)d_in[8];
    const float* root1    = (const float*)d_in[9];
    const float* b1       = (const float*)d_in[10];
    const float* W2       = (const float*)d_in[11];
    const float* root2    = (const float*)d_in[12];
    const float* b2       = (const float*)d_in[13];
    const float* lin_w    = (const float*)d_in[14];
    const float* lin_b    = (const float*)d_in[15];
    float* out = (float*)d_out;

    char* p = (char*)d_ws;
    auto alloc = [&](size_t bytes) { char* r = p; p += (bytes + 255) & ~(size_t)255; return r; };
    int*   cnt     = (int*)alloc((size_t)NNODE * 3 * 4);
    float* A1      = (float*)alloc((size_t)NNODE * K1 * 4);
    float* rcntBuf = (float*)alloc((size_t)NNODE * 4 * 4);
    unsigned short* A2h = (unsigned short*)alloc((size_t)NNODE * K2 * 2);
    unsigned short* A2l = (unsigned short*)alloc((size_t)NNODE * K2 * 2);
    float* x2      = (float*)alloc((size_t)NNODE * 128 * 4);
    float* B1eff   = (float*)alloc((size_t)K1 * 128 * 4);
    float* rootTab = (float*)alloc((size_t)33 * 128 * 4);
    short* Bt_hi   = (short*)alloc((size_t)128 * K2 * 2);
    short* Bt_lo   = (short*)alloc((size_t)128 * K2 * 2);
    float* pooled  = (float*)alloc((size_t)GNUM * 128 * 4);
    float* cntg    = (float*)alloc((size_t)GNUM * 4);
    int2*  nfTab   = (int2*)alloc((size_t)NNODE * 8);
    // CSR temporaries alias into x2 (all consumed before gemm2 writes x2)
    char* xb = (char*)x2;
    int* sorted     = (int*)(xb);                       // E ints = 2.56 MB
    int* offs       = (int*)(xb + 2600960);             // NNODE+1 ints
    int* cursor     = (int*)(xb + 2900992);             // NNODE ints
    int* partial    = (int*)(xb + 3200000);             // NB ints
    int* partialPre = (int*)(xb + 3210240);             // NB ints

    hipMemsetAsync(cnt,    0, (size_t)NNODE * 3 * 4, stream);
    hipMemsetAsync(B1eff,  0, (size_t)K1 * 128 * 4, stream);
    hipMemsetAsync(pooled, 0, (size_t)GNUM * 128 * 4, stream);
    hipMemsetAsync(cntg,   0, (size_t)GNUM * 4, stream);

    build_tabs_kernel<<<(4 * 33 * 128 + 255) / 256, 256, 0, stream>>>(
        shape_w, color_w, W1, root1, B1eff, rootTab);
    build_B2t_kernel<<<(K2 * 128 + 255) / 256, 256, 0, stream>>>(W2, root2, Bt_hi, Bt_lo);

    count_nf_kernel<<<(NEDGE + 255) / 256, 256, 0, stream>>>(
        ei, et, shape_id, color_id, pos, cnt, nfTab);
    scan_partial_kernel<<<NB, 256, 0, stream>>>(cnt, partial);
    scan_mid_kernel<<<1, 256, 0, stream>>>(partial, partialPre, offs);
    scan_final_kernel<<<NB, 256, 0, stream>>>(cnt, partialPre, offs, cursor, rcntBuf);
    fill_kernel<<<(NEDGE + 255) / 256, 256, 0, stream>>>(ei, et, cursor, sorted);

    hist1_kernel<<<(NNODE + 3) / 4, 256, 0, stream>>>(offs, sorted, nfTab, A1);

    gemm1_kernel<<<(NNODE + 63) / 64, 256, 0, stream>>>(
        A1, B1eff, rcntBuf, shape_id, color_id, pos, rootTab, b1, A2h, A2l);

    aggregate_kernel<<<(NNODE + 3) / 4, 256, 0, stream>>>(offs, sorted, rcntBuf, A2h, A2l);

    gemm2_mfma_kernel<<<(NNODE + 63) / 64, 256, 0, stream>>>(
        A2h, A2l, Bt_hi, Bt_lo, b2, x2);

    pool_kernel<<<(NNODE + 63) / 64, 128, 0, stream>>>(x2, batch, pooled, cntg);

    final_kernel<<<(GNUM * 4 + 255) / 256, 256, 0, stream>>>(
        pooled, cntg, lin_w, lin_b, out);
}

// Round 9
// 245.123 us; speedup vs baseline: 1.5434x; 1.0103x over previous
//
#include <hip/hip_runtime.h>
#include <hip/hip_bf16.h>

#define NNODE 50000
#define NEDGE 640000
#define NREL  3
#define HIDD  128
#define GNUM  512
#define K1    112   // layer-1 GEMM K (99 used + 13 zero pad)
#define K2    512   // layer-2 GEMM K (3*128 relations + 128 root)
#define NB    196   // scan blocks = ceil(NNODE/256)

typedef float  f32x4   __attribute__((ext_vector_type(4)));
typedef short  vshort8 __attribute__((ext_vector_type(8)));
typedef short  vshort4 __attribute__((ext_vector_type(4)));

// swizzled k-block position within a 32-short row (gemm2 LDS, conflict-free)
#define SWZ(row, kb) ((((kb) ^ (((row) >> 1) & 3)) << 3))

// ---------------- builders ----------------
__global__ void build_tabs_kernel(const float* __restrict__ shape_w,
                                  const float* __restrict__ color_w,
                                  const float* __restrict__ W1,
                                  const float* __restrict__ root1,
                                  float* __restrict__ B1eff,
                                  float* __restrict__ rootTab) {
    int idx = blockIdx.x * blockDim.x + threadIdx.x;
    if (idx >= 4 * 33 * 128) return;
    int h  = idx & 127;
    int j  = (idx >> 7) % 33;
    int rr = idx / (33 * 128);
    const float* Wsrc = (rr < 3) ? (W1 + (size_t)rr * 129 * 128) : root1; // [129][128]
    float v = 0.f;
    if (j < 16) {
        for (int e = 0; e < 64; ++e) v += shape_w[j * 64 + e] * Wsrc[e * 128 + h];
    } else if (j < 32) {
        int c = j - 16;
        for (int e = 0; e < 64; ++e) v += color_w[c * 64 + e] * Wsrc[(64 + e) * 128 + h];
    } else {
        v = Wsrc[128 * 128 + h];
    }
    if (rr < 3) B1eff[(rr * 33 + j) * 128 + h] = v;
    else        rootTab[j * 128 + h] = v;
}

__device__ __forceinline__ void split_bf16(float f, short& hi, short& lo) {
    unsigned u  = __float_as_uint(f);
    unsigned uh = (u + 0x7FFFu + ((u >> 16) & 1u)) >> 16;
    hi = (short)uh;
    float fl = f - __uint_as_float(uh << 16);
    unsigned ul  = __float_as_uint(fl);
    unsigned ulh = (ul + 0x7FFFu + ((ul >> 16) & 1u)) >> 16;
    lo = (short)ulh;
}

__device__ __forceinline__ short bf16_rne(float f) {
    unsigned u = __float_as_uint(f);
    return (short)((u + 0x7FFFu + ((u >> 16) & 1u)) >> 16);
}

// B2 transposed + split: Bt[n][k], k<384 -> W2, else root2
__global__ void build_B2t_kernel(const float* __restrict__ W2,
                                 const float* __restrict__ root2,
                                 short* __restrict__ Bt_hi,
                                 short* __restrict__ Bt_lo) {
    int idx = blockIdx.x * blockDim.x + threadIdx.x; // 512*128
    if (idx >= K2 * 128) return;
    int k = idx >> 7, n = idx & 127;
    float v = (k < 384) ? W2[idx] : root2[idx - 384 * 128];
    short h, l;
    split_bf16(v, h, l);
    Bt_hi[(size_t)n * K2 + k] = h;
    Bt_lo[(size_t)n * K2 + k] = l;
}

// ---------------- edge counting (1 int atomic/edge) + node-feature pack ----------------
__global__ void count_nf_kernel(const int* __restrict__ ei, const int* __restrict__ et,
                                const int* __restrict__ shape_id, const int* __restrict__ color_id,
                                const float* __restrict__ pos,
                                int* __restrict__ cnt, int2* __restrict__ nf) {
    int e = blockIdx.x * blockDim.x + threadIdx.x;
    if (e < NNODE) nf[e] = make_int2(shape_id[e] | (color_id[e] << 8), __float_as_int(pos[e]));
    if (e >= NEDGE) return;
    int d = ei[NEDGE + e], r = et[e];
    atomicAdd(&cnt[d * 3 + r], 1);
}

// ---------------- prefix scan over per-node degree (3-phase), relation-major CSR ----------------
__global__ void scan_partial_kernel(const int* __restrict__ cnt, int* __restrict__ partial) {
    __shared__ int sh[256];
    int t = threadIdx.x, i = blockIdx.x * 256 + t;
    int v = (i < NNODE) ? cnt[3 * i] + cnt[3 * i + 1] + cnt[3 * i + 2] : 0;
    sh[t] = v; __syncthreads();
    for (int o = 128; o > 0; o >>= 1) { if (t < o) sh[t] += sh[t + o]; __syncthreads(); }
    if (t == 0) partial[blockIdx.x] = sh[0];
}

__global__ void scan_mid_kernel(const int* __restrict__ partial, int* __restrict__ partial_pre,
                                int* __restrict__ offs3) {
    __shared__ int sh[256];
    int t = threadIdx.x;
    int v = (t < NB) ? partial[t] : 0;
    sh[t] = v; __syncthreads();
    for (int o = 1; o < 256; o <<= 1) {
        int x = (t >= o) ? sh[t - o] : 0; __syncthreads();
        sh[t] += x; __syncthreads();
    }
    if (t < NB) partial_pre[t] = sh[t] - v;
    if (t == 0) offs3[3 * NNODE] = NEDGE;
}

// writes offs3/cursor3 at (node,rel) granularity: offs3[3d+r]
__global__ void scan_final_kernel(const int* __restrict__ cnt, const int* __restrict__ partial_pre,
                                  int* __restrict__ offs3, int* __restrict__ cursor3,
                                  float* __restrict__ rcnt) {
    __shared__ int sh[256];
    int t = threadIdx.x, i = blockIdx.x * 256 + t;
    int c0 = 0, c1 = 0, c2 = 0;
    if (i < NNODE) { c0 = cnt[3 * i]; c1 = cnt[3 * i + 1]; c2 = cnt[3 * i + 2]; }
    int v = c0 + c1 + c2;
    sh[t] = v; __syncthreads();
    for (int o = 1; o < 256; o <<= 1) {
        int x = (t >= o) ? sh[t - o] : 0; __syncthreads();
        sh[t] += x; __syncthreads();
    }
    int exc = sh[t] - v + partial_pre[blockIdx.x];
    if (i < NNODE) {
        int3 o3 = make_int3(exc, exc + c0, exc + c0 + c1);
        offs3[3 * i]     = o3.x;  cursor3[3 * i]     = o3.x;
        offs3[3 * i + 1] = o3.y;  cursor3[3 * i + 1] = o3.y;
        offs3[3 * i + 2] = o3.z;  cursor3[3 * i + 2] = o3.z;
        float4 rc = make_float4(1.f / fmaxf((float)c0, 1.f), 1.f / fmaxf((float)c1, 1.f),
                                1.f / fmaxf((float)c2, 1.f), 1.f);
        *(float4*)&rcnt[i * 4] = rc;
    }
}

// ---------------- fill: (dst,rel)-sorted edge list; atomics on 3N cursors ----------------
__global__ void fill_kernel(const int* __restrict__ ei, const int* __restrict__ et,
                            int* __restrict__ cursor3, int* __restrict__ sorted) {
    int e = blockIdx.x * blockDim.x + threadIdx.x;
    if (e >= NEDGE) return;
    int s = ei[e], d = ei[NEDGE + e], r = et[e];
    int p = atomicAdd(&cursor3[d * 3 + r], 1);
    sorted[p] = s | (r << 16);   // NNODE < 65536, r < 4
}

// ---------------- layer-1 histogram: edge-parallel, per-wave LDS hist ----------------
__global__ __launch_bounds__(256) void hist1_kernel(const int* __restrict__ offs3,
                                                    const int* __restrict__ sorted,
                                                    const int2* __restrict__ nf,
                                                    float* __restrict__ A1) {
    __shared__ float hist[4][3 * 34];
    int lane = threadIdx.x & 63;
    int wv   = threadIdx.x >> 6;
    int d    = (blockIdx.x << 2) + wv;
    float* hf = hist[wv];
    if (lane < 51) { hf[lane] = 0.f; hf[lane + 51] = 0.f; }
    if (d < NNODE) {
        int beg = offs3[3 * d], end = offs3[3 * d + 3];
        for (int i = beg + lane; i < end; i += 64) {
            int w = sorted[i];
            int s = w & 0xFFFF, r = (w >> 16) & 3;
            int2 f = nf[s];
            atomicAdd(&hf[r * 34 + (f.x & 0xFF)], 1.f);
            atomicAdd(&hf[r * 34 + 16 + (f.x >> 8)], 1.f);
            atomicAdd(&hf[r * 34 + 32], __int_as_float(f.y));
        }
        float* row = &A1[(size_t)d * K1];
        row[lane] = hf[(lane / 33) * 34 + lane % 33];           // lanes 0..63 < 99
        int j = lane + 64;                                      // 64..127
        if (j < K1)                                             // bound guard
            row[j] = (j < 99) ? hf[(j / 33) * 34 + j % 33] : 0.f;
    }
}

// ---------------- layer-2 aggregation: wave-per-node, segmented (uniform-r), 4-deep ILP ----------------
// reads x1 (bf16-hi) from A2h root block; writes per-rel means split hi/lo.
__global__ __launch_bounds__(256) void aggregate_kernel(const int* __restrict__ offs3,
                                                        const int* __restrict__ sorted,
                                                        const float* __restrict__ rcnt,
                                                        unsigned short* __restrict__ A2h,
                                                        unsigned short* __restrict__ A2l) {
    int lane = threadIdx.x & 63;
    int d = (blockIdx.x << 2) + (threadIdx.x >> 6);
    if (d >= NNODE) return;
    int b0  = __builtin_amdgcn_readfirstlane(offs3[3 * d]);
    int b1  = __builtin_amdgcn_readfirstlane(offs3[3 * d + 1]);
    int b2  = __builtin_amdgcn_readfirstlane(offs3[3 * d + 2]);
    int end = __builtin_amdgcn_readfirstlane(offs3[3 * d + 3]);
    const unsigned* xp = (const unsigned*)A2h;   // row = 256 unsigneds; root block at +192
    float a00 = 0.f, a01 = 0.f, a10 = 0.f, a11 = 0.f, a20 = 0.f, a21 = 0.f;
    // r is determined by index position (wave-uniform compare, scalar branch)
#define AGG_ACC(ii, x) {                                            \
        float lo_ = __uint_as_float((x) << 16);                     \
        float hi_ = __uint_as_float((x) & 0xFFFF0000u);             \
        if ((ii) >= b2)      { a20 += lo_; a21 += hi_; }            \
        else if ((ii) >= b1) { a10 += lo_; a11 += hi_; }            \
        else                 { a00 += lo_; a01 += hi_; } }
    int i = b0;
    for (; i + 4 <= end; i += 4) {
        int w0 = sorted[i], w1 = sorted[i + 1], w2 = sorted[i + 2], w3 = sorted[i + 3];
        unsigned x0 = xp[((size_t)(unsigned)(w0 & 0xFFFF) << 8) + 192 + lane];
        unsigned x1 = xp[((size_t)(unsigned)(w1 & 0xFFFF) << 8) + 192 + lane];
        unsigned x2 = xp[((size_t)(unsigned)(w2 & 0xFFFF) << 8) + 192 + lane];
        unsigned x3 = xp[((size_t)(unsigned)(w3 & 0xFFFF) << 8) + 192 + lane];
        AGG_ACC(i, x0); AGG_ACC(i + 1, x1); AGG_ACC(i + 2, x2); AGG_ACC(i + 3, x3);
    }
    for (; i < end; ++i) {
        int w0 = sorted[i];
        unsigned x0 = xp[((size_t)(unsigned)(w0 & 0xFFFF) << 8) + 192 + lane];
        AGG_ACC(i, x0);
    }
#undef AGG_ACC
    float rc0 = rcnt[d * 4 + 0], rc1 = rcnt[d * 4 + 1], rc2 = rcnt[d * 4 + 2];
    size_t base = (size_t)d * 512 + (lane << 1);
#define AGG_OUT(vA, vB, rel) {                                        \
        short h0_, l0_, h1_, l1_;                                     \
        split_bf16(vA, h0_, l0_); split_bf16(vB, h1_, l1_);           \
        *(unsigned*)&A2h[base + (rel) * 128] =                        \
            (unsigned)(unsigned short)h0_ | ((unsigned)(unsigned short)h1_ << 16); \
        *(unsigned*)&A2l[base + (rel) * 128] =                        \
            (unsigned)(unsigned short)l0_ | ((unsigned)(unsigned short)l1_ << 16); }
    AGG_OUT(a00 * rc0, a01 * rc0, 0);
    AGG_OUT(a10 * rc1, a11 * rc1, 1);
    AGG_OUT(a20 * rc2, a21 * rc2, 2);
#undef AGG_OUT
}

// ---------------- layer-1 fused GEMM (fp32, 64x128 tile, 4x8 microtile) ----------------
__global__ __launch_bounds__(256) void gemm1_kernel(
    const float* __restrict__ A, const float* __restrict__ B,
    const float* __restrict__ rcnt,
    const int* __restrict__ shape_id, const int* __restrict__ color_id,
    const float* __restrict__ pos, const float* __restrict__ rootTab,
    const float* __restrict__ bias,
    unsigned short* __restrict__ A2h, unsigned short* __restrict__ A2l) {
    constexpr int K = K1, BM = 64, BK = 16;
    __shared__ float As[BK][BM + 4];
    __shared__ float Bs[BK][HIDD];
    const int t  = threadIdx.x;
    const int m0 = blockIdx.x * BM;
    const int tx = t & 15, ty = t >> 4;
    const int arow = t >> 2, ac4 = (t & 3) * 4;
    const int brow = t >> 4, bc = (t & 15) * 8;
    float acc[4][8] = {};
    for (int kt = 0; kt < K; kt += BK) {
        {
            int gr = m0 + arow;
            float4 v = make_float4(0.f, 0.f, 0.f, 0.f);
            if (gr < NNODE) {
                v = *(const float4*)&A[(size_t)gr * K + kt + ac4];
                float* vp = &v.x;
#pragma unroll
                for (int i = 0; i < 4; ++i) {
                    int kk = kt + ac4 + i;
                    int r = min(kk / 33, 3);
                    vp[i] *= rcnt[gr * 4 + r];
                }
            }
            As[ac4 + 0][arow] = v.x;
            As[ac4 + 1][arow] = v.y;
            As[ac4 + 2][arow] = v.z;
            As[ac4 + 3][arow] = v.w;
        }
        {
            const float4* src = (const float4*)&B[(size_t)(kt + brow) * HIDD + bc];
            *(float4*)&Bs[brow][bc]     = src[0];
            *(float4*)&Bs[brow][bc + 4] = src[1];
        }
        __syncthreads();
#pragma unroll
        for (int k = 0; k < BK; ++k) {
            float a[4], b[8];
            *(float4*)a      = *(const float4*)&As[k][ty * 4];
            *(float4*)&b[0]  = *(const float4*)&Bs[k][tx * 8];
            *(float4*)&b[4]  = *(const float4*)&Bs[k][tx * 8 + 4];
#pragma unroll
            for (int i = 0; i < 4; ++i)
#pragma unroll
                for (int j = 0; j < 8; ++j)
                    acc[i][j] = fmaf(a[i], b[j], acc[i][j]);
        }
        __syncthreads();
    }
#pragma unroll
    for (int i = 0; i < 4; ++i) {
        int gr = m0 + ty * 4 + i;
        if (gr >= NNODE) continue;
        int sid = shape_id[gr], cid = color_id[gr];
        float p = pos[gr];
        vshort8 p8, l8;
#pragma unroll
        for (int j = 0; j < 8; ++j) {
            int h = tx * 8 + j;
            float v = acc[i][j] + rootTab[sid * 128 + h] + rootTab[(16 + cid) * 128 + h]
                    + p * rootTab[32 * 128 + h] + bias[h];
            float rv = fmaxf(v, 0.f);
            short hh = bf16_rne(rv);
            p8[j] = hh;
            float hf = __uint_as_float((unsigned)(unsigned short)hh << 16);
            l8[j] = bf16_rne(rv - hf);
        }
        *(vshort8*)&A2h[(size_t)gr * 512 + 384 + tx * 8] = p8;
        *(vshort8*)&A2l[(size_t)gr * 512 + 384 + tx * 8] = l8;
    }
}

// ---------------- layer-2 GEMM: MFMA bf16x3, BM=64, swizzled LDS, pre-split A ----------------
__global__ __launch_bounds__(256) void gemm2_mfma_kernel(
    const unsigned short* __restrict__ A2h, const unsigned short* __restrict__ A2l,
    const short* __restrict__ Bt_hi, const short* __restrict__ Bt_lo,
    const float* __restrict__ bias,
    float* __restrict__ x2) {
    __shared__ short Ah[64][32];   // [row][swizzled k] bf16-hi
    __shared__ short Al[64][32];
    __shared__ short Bh[128][32];
    __shared__ short Bl[128][32];
    const int t    = threadIdx.x;
    const int lane = t & 63;
    const int w    = t >> 6;
    const int wm   = w >> 1, wn = w & 1;     // wave tile 32(M) x 64(N)
    const int bm0  = blockIdx.x * 64;
    const int lr   = lane & 15, lk = lane >> 4;
    const int sr = t >> 2, skb = t & 3;
    int gra = bm0 + sr; if (gra >= NNODE) gra = NNODE - 1;   // clamp (C-write guarded)
    f32x4 acc[2][4] = {};
    for (int kt = 0; kt < K2; kt += 32) {
        vshort8 avh = *(const vshort8*)&A2h[(size_t)gra * K2 + kt + skb * 8];
        vshort8 avl = *(const vshort8*)&A2l[(size_t)gra * K2 + kt + skb * 8];
        vshort8 bvh0 = *(const vshort8*)&Bt_hi[(size_t)sr * K2 + kt + skb * 8];
        vshort8 bvh1 = *(const vshort8*)&Bt_hi[(size_t)(sr + 64) * K2 + kt + skb * 8];
        vshort8 bvl0 = *(const vshort8*)&Bt_lo[(size_t)sr * K2 + kt + skb * 8];
        vshort8 bvl1 = *(const vshort8*)&Bt_lo[(size_t)(sr + 64) * K2 + kt + skb * 8];
        __syncthreads();
        *(vshort8*)&Ah[sr][SWZ(sr, skb)]           = avh;
        *(vshort8*)&Al[sr][SWZ(sr, skb)]           = avl;
        *(vshort8*)&Bh[sr][SWZ(sr, skb)]           = bvh0;
        *(vshort8*)&Bh[sr + 64][SWZ(sr + 64, skb)] = bvh1;
        *(vshort8*)&Bl[sr][SWZ(sr, skb)]           = bvl0;
        *(vshort8*)&Bl[sr + 64][SWZ(sr + 64, skb)] = bvl1;
        __syncthreads();
        vshort8 afh[2], afl[2], bfh[4], bfl[4];
#pragma unroll
        for (int mf = 0; mf < 2; ++mf) {
            int row = wm * 32 + mf * 16 + lr;
            afh[mf] = *(const vshort8*)&Ah[row][SWZ(row, lk)];
            afl[mf] = *(const vshort8*)&Al[row][SWZ(row, lk)];
        }
#pragma unroll
        for (int nf = 0; nf < 4; ++nf) {
            int row = wn * 64 + nf * 16 + lr;
            bfh[nf] = *(const vshort8*)&Bh[row][SWZ(row, lk)];
            bfl[nf] = *(const vshort8*)&Bl[row][SWZ(row, lk)];
        }
#pragma unroll
        for (int mf = 0; mf < 2; ++mf)
#pragma unroll
            for (int nf = 0; nf < 4; ++nf) {
                acc[mf][nf] = __builtin_amdgcn_mfma_f32_16x16x32_bf16(afh[mf], bfh[nf], acc[mf][nf], 0, 0, 0);
                acc[mf][nf] = __builtin_amdgcn_mfma_f32_16x16x32_bf16(afl[mf], bfh[nf], acc[mf][nf], 0, 0, 0);
                acc[mf][nf] = __builtin_amdgcn_mfma_f32_16x16x32_bf16(afh[mf], bfl[nf], acc[mf][nf], 0, 0, 0);
            }
    }
#pragma unroll
    for (int mf = 0; mf < 2; ++mf) {
        int mb = bm0 + wm * 32 + mf * 16 + (lane >> 4) * 4;
#pragma unroll
        for (int nf = 0; nf < 4; ++nf) {
            int n = wn * 64 + nf * 16 + lr;
            float bn = bias[n];
#pragma unroll
            for (int r = 0; r < 4; ++r) {
                int gm = mb + r;
                if (gm < NNODE)
                    x2[(size_t)gm * HIDD + n] = fmaxf(acc[mf][nf][r] + bn, 0.f);
            }
        }
    }
}

// ---------------- pooling (batch sorted -> run-length reduce), 64 nodes/block ----------------
__global__ void pool_kernel(const float* __restrict__ x2, const int* __restrict__ batch,
                            float* __restrict__ pooled, float* __restrict__ cntg) {
    const int CH = 64;
    int h  = threadIdx.x; // 128
    int n0 = blockIdx.x * CH;
    if (n0 >= NNODE) return;
    int n1 = min(n0 + CH, NNODE);
    int cur = batch[n0];
    float acc = 0.f;
    int run = 0;
    for (int n = n0; n < n1; ++n) {
        int g = batch[n];
        if (g != cur) {
            atomicAdd(&pooled[cur * 128 + h], acc);
            if (h == 0) atomicAdd(&cntg[cur], (float)run);
            acc = 0.f; run = 0; cur = g;
        }
        acc += x2[(size_t)n * 128 + h];
        ++run;
    }
    atomicAdd(&pooled[cur * 128 + h], acc);
    if (h == 0) atomicAdd(&cntg[cur], (float)run);
}

__global__ void final_kernel(const float* __restrict__ pooled, const float* __restrict__ cntg,
                             const float* __restrict__ lin_w, const float* __restrict__ lin_b,
                             float* __restrict__ out) {
    int idx = blockIdx.x * blockDim.x + threadIdx.x;
    if (idx >= GNUM * 4) return;
    int g = idx >> 2, c = idx & 3;
    float dot = 0.f;
    for (int k = 0; k < 128; ++k) dot += pooled[g * 128 + k] * lin_w[k * 4 + c];
    out[idx] = dot / fmaxf(cntg[g], 1.f) + lin_b[c];
}

// ---------------- launch ----------------
extern "C" void kernel_launch(void* const* d_in, const int* in_sizes, int n_in,
                              void* d_out, int out_size, void* d_ws, size_t ws_size,
                              hipStream_t stream) {
    const float* pos      = (const float*)d_in[0];
    const int*   shape_id = (const int*)d_in[1];
    const int*   color_id = (const int*)d_in[2];
    const int*   ei       = (const int*)d_in[3];
    const int*   et       = (const int*)d_in[4];
    const int*   batch    = (const int*)d_in[5];
    const float* shape_w  = (const float*)d_in[6];
    const float* color_w  = (const float*)d_in[7];
    const float* W1       = (const float*)d_in[8];
    const float* root1    = (const float*)d_in[9];
    const float* b1       = (const float*)d_in[10];
    const float* W2       = (const float*)d_in[11];
    const float* root2    = (const float*)d_in[12];
    const float* b2       = (const float*)d_in[13];
    const float* lin_w    = (const float*)d_in[14];
    const float* lin_b    = (const float*)d_in[15];
    float* out = (float*)d_out;

    char* p = (char*)d_ws;
    auto alloc = [&](size_t bytes) { char* r = p; p += (bytes + 255) & ~(size_t)255; return r; };
    int*   cnt     = (int*)alloc((size_t)NNODE * 3 * 4);
    float* A1      = (float*)alloc((size_t)NNODE * K1 * 4);
    float* rcntBuf = (float*)alloc((size_t)NNODE * 4 * 4);
    unsigned short* A2h = (unsigned short*)alloc((size_t)NNODE * K2 * 2);
    unsigned short* A2l = (unsigned short*)alloc((size_t)NNODE * K2 * 2);
    float* x2      = (float*)alloc((size_t)NNODE * 128 * 4);
    float* B1eff   = (float*)alloc((size_t)K1 * 128 * 4);
    float* rootTab = (float*)alloc((size_t)33 * 128 * 4);
    short* Bt_hi   = (short*)alloc((size_t)128 * K2 * 2);
    short* Bt_lo   = (short*)alloc((size_t)128 * K2 * 2);
    float* pooled  = (float*)alloc((size_t)GNUM * 128 * 4);
    float* cntg    = (float*)alloc((size_t)GNUM * 4);
    int2*  nfTab   = (int2*)alloc((size_t)NNODE * 8);
    // CSR temporaries alias into x2 (all consumed before gemm2 writes x2)
    char* xb = (char*)x2;
    int* sorted     = (int*)(xb);                       // E ints = 2.56 MB
    int* offs3      = (int*)(xb + 2600960);             // 3*NNODE+1 ints = 600 KB
    int* cursor3    = (int*)(xb + 3201280);             // 3*NNODE ints   = 600 KB
    int* partial    = (int*)(xb + 3801600);             // NB ints
    int* partialPre = (int*)(xb + 3811840);             // NB ints

    hipMemsetAsync(cnt,    0, (size_t)NNODE * 3 * 4, stream);
    hipMemsetAsync(B1eff,  0, (size_t)K1 * 128 * 4, stream);
    hipMemsetAsync(pooled, 0, (size_t)GNUM * 128 * 4, stream);
    hipMemsetAsync(cntg,   0, (size_t)GNUM * 4, stream);

    build_tabs_kernel<<<(4 * 33 * 128 + 255) / 256, 256, 0, stream>>>(
        shape_w, color_w, W1, root1, B1eff, rootTab);
    build_B2t_kernel<<<(K2 * 128 + 255) / 256, 256, 0, stream>>>(W2, root2, Bt_hi, Bt_lo);

    count_nf_kernel<<<(NEDGE + 255) / 256, 256, 0, stream>>>(
        ei, et, shape_id, color_id, pos, cnt, nfTab);
    scan_partial_kernel<<<NB, 256, 0, stream>>>(cnt, partial);
    scan_mid_kernel<<<1, 256, 0, stream>>>(partial, partialPre, offs3);
    scan_final_kernel<<<NB, 256, 0, stream>>>(cnt, partialPre, offs3, cursor3, rcntBuf);
    fill_kernel<<<(NEDGE + 255) / 256, 256, 0, stream>>>(ei, et, cursor3, sorted);

    hist1_kernel<<<(NNODE + 3) / 4, 256, 0, stream>>>(offs3, sorted, nfTab, A1);

    gemm1_kernel<<<(NNODE + 63) / 64, 256, 0, stream>>>(
        A1, B1eff, rcntBuf, shape_id, color_id, pos, rootTab, b1, A2h, A2l);

    aggregate_kernel<<<(NNODE + 3) / 4, 256, 0, stream>>>(offs3, sorted, rcntBuf, A2h, A2l);

    gemm2_mfma_kernel<<<(NNODE + 63) / 64, 256, 0, stream>>>(
        A2h, A2l, Bt_hi, Bt_lo, b2, x2);

    pool_kernel<<<(NNODE + 63) / 64, 128, 0, stream>>>(x2, batch, pooled, cntg);

    final_kernel<<<(GNUM * 4 + 255) / 256, 256, 0, stream>>>(
        pooled, cntg, lin_w, lin_b, out);
}

// Round 10
// 236.466 us; speedup vs baseline: 1.5999x; 1.0366x over previous
//
#include <hip/hip_runtime.h>
#include <hip/hip_bf16.h>

#define NNODE 50000
#define NEDGE 640000
#define NREL  3
#define HIDD  128
#define GNUM  512
#define K1M   128   // layer-1 GEMM K (99 used + pad to 128 for MFMA)
#define K2    512   // layer-2 GEMM K (3*128 relations + 128 root)
#define NB    196   // scan blocks = ceil(NNODE/256)

typedef float  f32x4   __attribute__((ext_vector_type(4)));
typedef short  vshort8 __attribute__((ext_vector_type(8)));
typedef short  vshort4 __attribute__((ext_vector_type(4)));

// swizzled k-block position within a 32-short row (MFMA LDS, conflict-free)
#define SWZ(row, kb) ((((kb) ^ (((row) >> 1) & 3)) << 3))

// ---------------- builders ----------------
__global__ void build_tabs_kernel(const float* __restrict__ shape_w,
                                  const float* __restrict__ color_w,
                                  const float* __restrict__ W1,
                                  const float* __restrict__ root1,
                                  float* __restrict__ B1eff,
                                  float* __restrict__ rootTab) {
    int idx = blockIdx.x * blockDim.x + threadIdx.x;
    if (idx >= 4 * 33 * 128) return;
    int h  = idx & 127;
    int j  = (idx >> 7) % 33;
    int rr = idx / (33 * 128);
    const float* Wsrc = (rr < 3) ? (W1 + (size_t)rr * 129 * 128) : root1; // [129][128]
    float v = 0.f;
    if (j < 16) {
        for (int e = 0; e < 64; ++e) v += shape_w[j * 64 + e] * Wsrc[e * 128 + h];
    } else if (j < 32) {
        int c = j - 16;
        for (int e = 0; e < 64; ++e) v += color_w[c * 64 + e] * Wsrc[(64 + e) * 128 + h];
    } else {
        v = Wsrc[128 * 128 + h];
    }
    if (rr < 3) B1eff[(rr * 33 + j) * 128 + h] = v;
    else        rootTab[j * 128 + h] = v;
}

__device__ __forceinline__ void split_bf16(float f, short& hi, short& lo) {
    unsigned u  = __float_as_uint(f);
    unsigned uh = (u + 0x7FFFu + ((u >> 16) & 1u)) >> 16;
    hi = (short)uh;
    float fl = f - __uint_as_float(uh << 16);
    unsigned ul  = __float_as_uint(fl);
    unsigned ulh = (ul + 0x7FFFu + ((ul >> 16) & 1u)) >> 16;
    lo = (short)ulh;
}

__device__ __forceinline__ short bf16_rne(float f) {
    unsigned u = __float_as_uint(f);
    return (short)((u + 0x7FFFu + ((u >> 16) & 1u)) >> 16);
}

// B1eff [99..112 rows used of 112][128] -> transposed split B1t[n=128][k=128]
__global__ void build_B1t_kernel(const float* __restrict__ B1eff,
                                 short* __restrict__ B1th,
                                 short* __restrict__ B1tl) {
    int idx = blockIdx.x * blockDim.x + threadIdx.x; // 128*128
    if (idx >= K1M * 128) return;
    int k = idx >> 7, n = idx & 127;
    float v = (k < 99) ? B1eff[k * 128 + n] : 0.f;
    short h, l;
    split_bf16(v, h, l);
    B1th[(size_t)n * K1M + k] = h;
    B1tl[(size_t)n * K1M + k] = l;
}

// B2 transposed + split: Bt[n][k], k<384 -> W2, else root2
__global__ void build_B2t_kernel(const float* __restrict__ W2,
                                 const float* __restrict__ root2,
                                 short* __restrict__ Bt_hi,
                                 short* __restrict__ Bt_lo) {
    int idx = blockIdx.x * blockDim.x + threadIdx.x; // 512*128
    if (idx >= K2 * 128) return;
    int k = idx >> 7, n = idx & 127;
    float v = (k < 384) ? W2[idx] : root2[idx - 384 * 128];
    short h, l;
    split_bf16(v, h, l);
    Bt_hi[(size_t)n * K2 + k] = h;
    Bt_lo[(size_t)n * K2 + k] = l;
}

// ---------------- edge counting (1 int atomic/edge) + node-feature pack ----------------
__global__ void count_nf_kernel(const int* __restrict__ ei, const int* __restrict__ et,
                                const int* __restrict__ shape_id, const int* __restrict__ color_id,
                                const float* __restrict__ pos,
                                int* __restrict__ cnt, int2* __restrict__ nf) {
    int e = blockIdx.x * blockDim.x + threadIdx.x;
    if (e < NNODE) nf[e] = make_int2(shape_id[e] | (color_id[e] << 8), __float_as_int(pos[e]));
    if (e >= NEDGE) return;
    int d = ei[NEDGE + e], r = et[e];
    atomicAdd(&cnt[d * 3 + r], 1);
}

// ---------------- prefix scan over per-node degree (3-phase), relation-major CSR ----------------
__global__ void scan_partial_kernel(const int* __restrict__ cnt, int* __restrict__ partial) {
    __shared__ int sh[256];
    int t = threadIdx.x, i = blockIdx.x * 256 + t;
    int v = (i < NNODE) ? cnt[3 * i] + cnt[3 * i + 1] + cnt[3 * i + 2] : 0;
    sh[t] = v; __syncthreads();
    for (int o = 128; o > 0; o >>= 1) { if (t < o) sh[t] += sh[t + o]; __syncthreads(); }
    if (t == 0) partial[blockIdx.x] = sh[0];
}

__global__ void scan_mid_kernel(const int* __restrict__ partial, int* __restrict__ partial_pre,
                                int* __restrict__ offs3) {
    __shared__ int sh[256];
    int t = threadIdx.x;
    int v = (t < NB) ? partial[t] : 0;
    sh[t] = v; __syncthreads();
    for (int o = 1; o < 256; o <<= 1) {
        int x = (t >= o) ? sh[t - o] : 0; __syncthreads();
        sh[t] += x; __syncthreads();
    }
    if (t < NB) partial_pre[t] = sh[t] - v;
    if (t == 0) offs3[3 * NNODE] = NEDGE;
}

// writes offs3/cursor3 at (node,rel) granularity: offs3[3d+r]
__global__ void scan_final_kernel(const int* __restrict__ cnt, const int* __restrict__ partial_pre,
                                  int* __restrict__ offs3, int* __restrict__ cursor3,
                                  float* __restrict__ rcnt) {
    __shared__ int sh[256];
    int t = threadIdx.x, i = blockIdx.x * 256 + t;
    int c0 = 0, c1 = 0, c2 = 0;
    if (i < NNODE) { c0 = cnt[3 * i]; c1 = cnt[3 * i + 1]; c2 = cnt[3 * i + 2]; }
    int v = c0 + c1 + c2;
    sh[t] = v; __syncthreads();
    for (int o = 1; o < 256; o <<= 1) {
        int x = (t >= o) ? sh[t - o] : 0; __syncthreads();
        sh[t] += x; __syncthreads();
    }
    int exc = sh[t] - v + partial_pre[blockIdx.x];
    if (i < NNODE) {
        int3 o3 = make_int3(exc, exc + c0, exc + c0 + c1);
        offs3[3 * i]     = o3.x;  cursor3[3 * i]     = o3.x;
        offs3[3 * i + 1] = o3.y;  cursor3[3 * i + 1] = o3.y;
        offs3[3 * i + 2] = o3.z;  cursor3[3 * i + 2] = o3.z;
        float4 rc = make_float4(1.f / fmaxf((float)c0, 1.f), 1.f / fmaxf((float)c1, 1.f),
                                1.f / fmaxf((float)c2, 1.f), 1.f);
        *(float4*)&rcnt[i * 4] = rc;
    }
}

// ---------------- fill: (dst,rel)-sorted edge list; atomics on 3N cursors ----------------
__global__ void fill_kernel(const int* __restrict__ ei, const int* __restrict__ et,
                            int* __restrict__ cursor3, int* __restrict__ sorted) {
    int e = blockIdx.x * blockDim.x + threadIdx.x;
    if (e >= NEDGE) return;
    int s = ei[e], d = ei[NEDGE + e], r = et[e];
    int p = atomicAdd(&cursor3[d * 3 + r], 1);
    sorted[p] = s | (r << 16);   // NNODE < 65536, r < 4
}

// ---------------- layer-1 histogram: edge-parallel LDS hist; emits scaled bf16 hi/lo ----------------
__global__ __launch_bounds__(256) void hist1_kernel(const int* __restrict__ offs3,
                                                    const int* __restrict__ sorted,
                                                    const int2* __restrict__ nf,
                                                    const float* __restrict__ rcnt,
                                                    unsigned short* __restrict__ A1h,
                                                    unsigned short* __restrict__ A1l) {
    __shared__ float hist[4][3 * 34];
    int lane = threadIdx.x & 63;
    int wv   = threadIdx.x >> 6;
    int d    = (blockIdx.x << 2) + wv;
    float* hf = hist[wv];
    if (lane < 51) { hf[lane] = 0.f; hf[lane + 51] = 0.f; }
    if (d < NNODE) {
        int beg = offs3[3 * d], end = offs3[3 * d + 3];
        for (int i = beg + lane; i < end; i += 64) {
            int w = sorted[i];
            int s = w & 0xFFFF, r = (w >> 16) & 3;
            int2 f = nf[s];
            atomicAdd(&hf[r * 34 + (f.x & 0xFF)], 1.f);
            atomicAdd(&hf[r * 34 + 16 + (f.x >> 8)], 1.f);
            atomicAdd(&hf[r * 34 + 32], __int_as_float(f.y));
        }
        // emit mean-scaled features, split hi/lo bf16; slots lane and lane+64
#pragma unroll
        for (int half = 0; half < 2; ++half) {
            int slot = lane + half * 64;                 // 0..127
            float v = 0.f;
            if (slot < 99) {
                int r = slot / 33;
                v = hf[r * 34 + (slot - r * 33)] * rcnt[d * 4 + r];
            }
            short hh, ll;
            split_bf16(v, hh, ll);
            A1h[(size_t)d * K1M + slot] = (unsigned short)hh;
            A1l[(size_t)d * K1M + slot] = (unsigned short)ll;
        }
    }
}

// ---------------- layer-2 aggregation: wave-per-node, segmented, 8-deep ILP ----------------
__global__ __launch_bounds__(256) void aggregate_kernel(const int* __restrict__ offs3,
                                                        const int* __restrict__ sorted,
                                                        const float* __restrict__ rcnt,
                                                        unsigned short* __restrict__ A2h,
                                                        unsigned short* __restrict__ A2l) {
    int lane = threadIdx.x & 63;
    int d = (blockIdx.x << 2) + (threadIdx.x >> 6);
    if (d >= NNODE) return;
    int b0  = __builtin_amdgcn_readfirstlane(offs3[3 * d]);
    int b1  = __builtin_amdgcn_readfirstlane(offs3[3 * d + 1]);
    int b2  = __builtin_amdgcn_readfirstlane(offs3[3 * d + 2]);
    int end = __builtin_amdgcn_readfirstlane(offs3[3 * d + 3]);
    const unsigned* xp = (const unsigned*)A2h;   // row = 256 unsigneds; root block at +192
    float a00 = 0.f, a01 = 0.f, a10 = 0.f, a11 = 0.f, a20 = 0.f, a21 = 0.f;
#define AGG_ACC(ii, x) {                                            \
        float lo_ = __uint_as_float((x) << 16);                     \
        float hi_ = __uint_as_float((x) & 0xFFFF0000u);             \
        if ((ii) >= b2)      { a20 += lo_; a21 += hi_; }            \
        else if ((ii) >= b1) { a10 += lo_; a11 += hi_; }            \
        else                 { a00 += lo_; a01 += hi_; } }
#define AGG_LD(j)  unsigned x##j = xp[((size_t)(unsigned)(sorted[i + j] & 0xFFFF) << 8) + 192 + lane]
    int i = b0;
    for (; i + 8 <= end; i += 8) {
        AGG_LD(0); AGG_LD(1); AGG_LD(2); AGG_LD(3);
        AGG_LD(4); AGG_LD(5); AGG_LD(6); AGG_LD(7);
        AGG_ACC(i, x0); AGG_ACC(i + 1, x1); AGG_ACC(i + 2, x2); AGG_ACC(i + 3, x3);
        AGG_ACC(i + 4, x4); AGG_ACC(i + 5, x5); AGG_ACC(i + 6, x6); AGG_ACC(i + 7, x7);
    }
    for (; i + 4 <= end; i += 4) {
        AGG_LD(0); AGG_LD(1); AGG_LD(2); AGG_LD(3);
        AGG_ACC(i, x0); AGG_ACC(i + 1, x1); AGG_ACC(i + 2, x2); AGG_ACC(i + 3, x3);
    }
    for (; i < end; ++i) {
        AGG_LD(0);
        AGG_ACC(i, x0);
    }
#undef AGG_LD
#undef AGG_ACC
    float rc0 = rcnt[d * 4 + 0], rc1 = rcnt[d * 4 + 1], rc2 = rcnt[d * 4 + 2];
    size_t base = (size_t)d * 512 + (lane << 1);
#define AGG_OUT(vA, vB, rel) {                                        \
        short h0_, l0_, h1_, l1_;                                     \
        split_bf16(vA, h0_, l0_); split_bf16(vB, h1_, l1_);           \
        *(unsigned*)&A2h[base + (rel) * 128] =                        \
            (unsigned)(unsigned short)h0_ | ((unsigned)(unsigned short)h1_ << 16); \
        *(unsigned*)&A2l[base + (rel) * 128] =                        \
            (unsigned)(unsigned short)l0_ | ((unsigned)(unsigned short)l1_ << 16); }
    AGG_OUT(a00 * rc0, a01 * rc0, 0);
    AGG_OUT(a10 * rc1, a11 * rc1, 1);
    AGG_OUT(a20 * rc2, a21 * rc2, 2);
#undef AGG_OUT
}

// ---------------- layer-1 GEMM: MFMA bf16x3, BM=64, swizzled LDS, fused root epilogue ----------------
__global__ __launch_bounds__(256) void gemm1_mfma_kernel(
    const unsigned short* __restrict__ A1h, const unsigned short* __restrict__ A1l,
    const short* __restrict__ B1th, const short* __restrict__ B1tl,
    const int* __restrict__ shape_id, const int* __restrict__ color_id,
    const float* __restrict__ pos, const float* __restrict__ rootTab,
    const float* __restrict__ bias,
    unsigned short* __restrict__ A2h, unsigned short* __restrict__ A2l) {
    __shared__ short Ah[64][32];
    __shared__ short Al[64][32];
    __shared__ short Bh[128][32];
    __shared__ short Bl[128][32];
    const int t    = threadIdx.x;
    const int lane = t & 63;
    const int w    = t >> 6;
    const int wm   = w >> 1, wn = w & 1;     // wave tile 32(M) x 64(N)
    const int bm0  = blockIdx.x * 64;
    const int lr   = lane & 15, lk = lane >> 4;
    const int sr = t >> 2, skb = t & 3;
    int gra = bm0 + sr; if (gra >= NNODE) gra = NNODE - 1;   // clamp (C-write guarded)
    f32x4 acc[2][4] = {};
    for (int kt = 0; kt < K1M; kt += 32) {
        vshort8 avh = *(const vshort8*)&A1h[(size_t)gra * K1M + kt + skb * 8];
        vshort8 avl = *(const vshort8*)&A1l[(size_t)gra * K1M + kt + skb * 8];
        vshort8 bvh0 = *(const vshort8*)&B1th[(size_t)sr * K1M + kt + skb * 8];
        vshort8 bvh1 = *(const vshort8*)&B1th[(size_t)(sr + 64) * K1M + kt + skb * 8];
        vshort8 bvl0 = *(const vshort8*)&B1tl[(size_t)sr * K1M + kt + skb * 8];
        vshort8 bvl1 = *(const vshort8*)&B1tl[(size_t)(sr + 64) * K1M + kt + skb * 8];
        __syncthreads();
        *(vshort8*)&Ah[sr][SWZ(sr, skb)]           = avh;
        *(vshort8*)&Al[sr][SWZ(sr, skb)]           = avl;
        *(vshort8*)&Bh[sr][SWZ(sr, skb)]           = bvh0;
        *(vshort8*)&Bh[sr + 64][SWZ(sr + 64, skb)] = bvh1;
        *(vshort8*)&Bl[sr][SWZ(sr, skb)]           = bvl0;
        *(vshort8*)&Bl[sr + 64][SWZ(sr + 64, skb)] = bvl1;
        __syncthreads();
        vshort8 afh[2], afl[2], bfh[4], bfl[4];
#pragma unroll
        for (int mf = 0; mf < 2; ++mf) {
            int row = wm * 32 + mf * 16 + lr;
            afh[mf] = *(const vshort8*)&Ah[row][SWZ(row, lk)];
            afl[mf] = *(const vshort8*)&Al[row][SWZ(row, lk)];
        }
#pragma unroll
        for (int nf = 0; nf < 4; ++nf) {
            int row = wn * 64 + nf * 16 + lr;
            bfh[nf] = *(const vshort8*)&Bh[row][SWZ(row, lk)];
            bfl[nf] = *(const vshort8*)&Bl[row][SWZ(row, lk)];
        }
#pragma unroll
        for (int mf = 0; mf < 2; ++mf)
#pragma unroll
            for (int nf = 0; nf < 4; ++nf) {
                acc[mf][nf] = __builtin_amdgcn_mfma_f32_16x16x32_bf16(afh[mf], bfh[nf], acc[mf][nf], 0, 0, 0);
                acc[mf][nf] = __builtin_amdgcn_mfma_f32_16x16x32_bf16(afl[mf], bfh[nf], acc[mf][nf], 0, 0, 0);
                acc[mf][nf] = __builtin_amdgcn_mfma_f32_16x16x32_bf16(afh[mf], bfl[nf], acc[mf][nf], 0, 0, 0);
            }
    }
    // epilogue: + root lookups + bias, relu, split hi/lo, write A2 root block
#pragma unroll
    for (int mf = 0; mf < 2; ++mf) {
        int mb = bm0 + wm * 32 + mf * 16 + (lane >> 4) * 4;
#pragma unroll
        for (int r = 0; r < 4; ++r) {
            int gm = mb + r;
            if (gm >= NNODE) continue;
            int sid = shape_id[gm], cid = color_id[gm];
            float pv = pos[gm];
#pragma unroll
            for (int nf = 0; nf < 4; ++nf) {
                int n = wn * 64 + nf * 16 + lr;
                float v = acc[mf][nf][r] + rootTab[sid * 128 + n] + rootTab[(16 + cid) * 128 + n]
                        + pv * rootTab[32 * 128 + n] + bias[n];
                float rv = fmaxf(v, 0.f);
                short hh = bf16_rne(rv);
                float hf = __uint_as_float((unsigned)(unsigned short)hh << 16);
                short ll = bf16_rne(rv - hf);
                A2h[(size_t)gm * 512 + 384 + n] = (unsigned short)hh;
                A2l[(size_t)gm * 512 + 384 + n] = (unsigned short)ll;
            }
        }
    }
}

// ---------------- layer-2 GEMM: MFMA bf16x3, BM=64, swizzled LDS, pre-split A ----------------
__global__ __launch_bounds__(256) void gemm2_mfma_kernel(
    const unsigned short* __restrict__ A2h, const unsigned short* __restrict__ A2l,
    const short* __restrict__ Bt_hi, const short* __restrict__ Bt_lo,
    const float* __restrict__ bias,
    float* __restrict__ x2) {
    __shared__ short Ah[64][32];   // [row][swizzled k] bf16-hi
    __shared__ short Al[64][32];
    __shared__ short Bh[128][32];
    __shared__ short Bl[128][32];
    const int t    = threadIdx.x;
    const int lane = t & 63;
    const int w    = t >> 6;
    const int wm   = w >> 1, wn = w & 1;     // wave tile 32(M) x 64(N)
    const int bm0  = blockIdx.x * 64;
    const int lr   = lane & 15, lk = lane >> 4;
    const int sr = t >> 2, skb = t & 3;
    int gra = bm0 + sr; if (gra >= NNODE) gra = NNODE - 1;   // clamp (C-write guarded)
    f32x4 acc[2][4] = {};
    for (int kt = 0; kt < K2; kt += 32) {
        vshort8 avh = *(const vshort8*)&A2h[(size_t)gra * K2 + kt + skb * 8];
        vshort8 avl = *(const vshort8*)&A2l[(size_t)gra * K2 + kt + skb * 8];
        vshort8 bvh0 = *(const vshort8*)&Bt_hi[(size_t)sr * K2 + kt + skb * 8];
        vshort8 bvh1 = *(const vshort8*)&Bt_hi[(size_t)(sr + 64) * K2 + kt + skb * 8];
        vshort8 bvl0 = *(const vshort8*)&Bt_lo[(size_t)sr * K2 + kt + skb * 8];
        vshort8 bvl1 = *(const vshort8*)&Bt_lo[(size_t)(sr + 64) * K2 + kt + skb * 8];
        __syncthreads();
        *(vshort8*)&Ah[sr][SWZ(sr, skb)]           = avh;
        *(vshort8*)&Al[sr][SWZ(sr, skb)]           = avl;
        *(vshort8*)&Bh[sr][SWZ(sr, skb)]           = bvh0;
        *(vshort8*)&Bh[sr + 64][SWZ(sr + 64, skb)] = bvh1;
        *(vshort8*)&Bl[sr][SWZ(sr, skb)]           = bvl0;
        *(vshort8*)&Bl[sr + 64][SWZ(sr + 64, skb)] = bvl1;
        __syncthreads();
        vshort8 afh[2], afl[2], bfh[4], bfl[4];
#pragma unroll
        for (int mf = 0; mf < 2; ++mf) {
            int row = wm * 32 + mf * 16 + lr;
            afh[mf] = *(const vshort8*)&Ah[row][SWZ(row, lk)];
            afl[mf] = *(const vshort8*)&Al[row][SWZ(row, lk)];
        }
#pragma unroll
        for (int nf = 0; nf < 4; ++nf) {
            int row = wn * 64 + nf * 16 + lr;
            bfh[nf] = *(const vshort8*)&Bh[row][SWZ(row, lk)];
            bfl[nf] = *(const vshort8*)&Bl[row][SWZ(row, lk)];
        }
#pragma unroll
        for (int mf = 0; mf < 2; ++mf)
#pragma unroll
            for (int nf = 0; nf < 4; ++nf) {
                acc[mf][nf] = __builtin_amdgcn_mfma_f32_16x16x32_bf16(afh[mf], bfh[nf], acc[mf][nf], 0, 0, 0);
                acc[mf][nf] = __builtin_amdgcn_mfma_f32_16x16x32_bf16(afl[mf], bfh[nf], acc[mf][nf], 0, 0, 0);
                acc[mf][nf] = __builtin_amdgcn_mfma_f32_16x16x32_bf16(afh[mf], bfl[nf], acc[mf][nf], 0, 0, 0);
            }
    }
#pragma unroll
    for (int mf = 0; mf < 2; ++mf) {
        int mb = bm0 + wm * 32 + mf * 16 + (lane >> 4) * 4;
#pragma unroll
        for (int nf = 0; nf < 4; ++nf) {
            int n = wn * 64 + nf * 16 + lr;
            float bn = bias[n];
#pragma unroll
            for (int r = 0; r < 4; ++r) {
                int gm = mb + r;
                if (gm < NNODE)
                    x2[(size_t)gm * HIDD + n] = fmaxf(acc[mf][nf][r] + bn, 0.f);
            }
        }
    }
}

// ---------------- pooling (batch sorted -> run-length reduce), 64 nodes/block ----------------
__global__ void pool_kernel(const float* __restrict__ x2, const int* __restrict__ batch,
                            float* __restrict__ pooled, float* __restrict__ cntg) {
    const int CH = 64;
    int h  = threadIdx.x; // 128
    int n0 = blockIdx.x * CH;
    if (n0 >= NNODE) return;
    int n1 = min(n0 + CH, NNODE);
    int cur = batch[n0];
    float acc = 0.f;
    int run = 0;
    for (int n = n0; n < n1; ++n) {
        int g = batch[n];
        if (g != cur) {
            atomicAdd(&pooled[cur * 128 + h], acc);
            if (h == 0) atomicAdd(&cntg[cur], (float)run);
            acc = 0.f; run = 0; cur = g;
        }
        acc += x2[(size_t)n * 128 + h];
        ++run;
    }
    atomicAdd(&pooled[cur * 128 + h], acc);
    if (h == 0) atomicAdd(&cntg[cur], (float)run);
}

__global__ void final_kernel(const float* __restrict__ pooled, const float* __restrict__ cntg,
                             const float* __restrict__ lin_w, const float* __restrict__ lin_b,
                             float* __restrict__ out) {
    int idx = blockIdx.x * blockDim.x + threadIdx.x;
    if (idx >= GNUM * 4) return;
    int g = idx >> 2, c = idx & 3;
    float dot = 0.f;
    for (int k = 0; k < 128; ++k) dot += pooled[g * 128 + k] * lin_w[k * 4 + c];
    out[idx] = dot / fmaxf(cntg[g], 1.f) + lin_b[c];
}

// ---------------- launch ----------------
extern "C" void kernel_launch(void* const* d_in, const int* in_sizes, int n_in,
                              void* d_out, int out_size, void* d_ws, size_t ws_size,
                              hipStream_t stream) {
    const float* pos      = (const float*)d_in[0];
    const int*   shape_id = (const int*)d_in[1];
    const int*   color_id = (const int*)d_in[2];
    const int*   ei       = (const int*)d_in[3];
    const int*   et       = (const int*)d_in[4];
    const int*   batch    = (const int*)d_in[5];
    const float* shape_w  = (const float*)d_in[6];
    const float* color_w  = (const float*)d_in[7];
    const float* W1       = (const float*)d_in[8];
    const float* root1    = (const float*)d_in[9];
    const float* b1       = (const float*)d_in[10];
    const float* W2       = (const float*)d_in[11];
    const float* root2    = (const float*)d_in[12];
    const float* b2       = (const float*)d_in[13];
    const float* lin_w    = (const float*)d_in[14];
    const float* lin_b    = (const float*)d_in[15];
    float* out = (float*)d_out;

    char* p = (char*)d_ws;
    auto alloc = [&](size_t bytes) { char* r = p; p += (bytes + 255) & ~(size_t)255; return r; };
    int*   cnt     = (int*)alloc((size_t)NNODE * 3 * 4);
    unsigned short* A1h = (unsigned short*)alloc((size_t)NNODE * K1M * 2);
    unsigned short* A1l = (unsigned short*)alloc((size_t)NNODE * K1M * 2);
    float* rcntBuf = (float*)alloc((size_t)NNODE * 4 * 4);
    unsigned short* A2h = (unsigned short*)alloc((size_t)NNODE * K2 * 2);
    unsigned short* A2l = (unsigned short*)alloc((size_t)NNODE * K2 * 2);
    float* x2      = (float*)alloc((size_t)NNODE * 128 * 4);
    float* B1eff   = (float*)alloc((size_t)112 * 128 * 4);
    float* rootTab = (float*)alloc((size_t)33 * 128 * 4);
    short* B1th    = (short*)alloc((size_t)128 * K1M * 2);
    short* B1tl    = (short*)alloc((size_t)128 * K1M * 2);
    short* Bt_hi   = (short*)alloc((size_t)128 * K2 * 2);
    short* Bt_lo   = (short*)alloc((size_t)128 * K2 * 2);
    float* pooled  = (float*)alloc((size_t)GNUM * 128 * 4);
    float* cntg    = (float*)alloc((size_t)GNUM * 4);
    int2*  nfTab   = (int2*)alloc((size_t)NNODE * 8);
    // CSR temporaries alias into x2 (all consumed before gemm2 writes x2)
    char* xb = (char*)x2;
    int* sorted     = (int*)(xb);                       // E ints = 2.56 MB
    int* offs3      = (int*)(xb + 2600960);             // 3*NNODE+1 ints = 600 KB
    int* cursor3    = (int*)(xb + 3201280);             // 3*NNODE ints   = 600 KB
    int* partial    = (int*)(xb + 3801600);             // NB ints
    int* partialPre = (int*)(xb + 3811840);             // NB ints

    hipMemsetAsync(cnt,    0, (size_t)NNODE * 3 * 4, stream);
    hipMemsetAsync(B1eff,  0, (size_t)112 * 128 * 4, stream);
    hipMemsetAsync(pooled, 0, (size_t)GNUM * 128 * 4, stream);
    hipMemsetAsync(cntg,   0, (size_t)GNUM * 4, stream);

    build_tabs_kernel<<<(4 * 33 * 128 + 255) / 256, 256, 0, stream>>>(
        shape_w, color_w, W1, root1, B1eff, rootTab);
    build_B1t_kernel<<<(K1M * 128 + 255) / 256, 256, 0, stream>>>(B1eff, B1th, B1tl);
    build_B2t_kernel<<<(K2 * 128 + 255) / 256, 256, 0, stream>>>(W2, root2, Bt_hi, Bt_lo);

    count_nf_kernel<<<(NEDGE + 255) / 256, 256, 0, stream>>>(
        ei, et, shape_id, color_id, pos, cnt, nfTab);
    scan_partial_kernel<<<NB, 256, 0, stream>>>(cnt, partial);
    scan_mid_kernel<<<1, 256, 0, stream>>>(partial, partialPre, offs3);
    scan_final_kernel<<<NB, 256, 0, stream>>>(cnt, partialPre, offs3, cursor3, rcntBuf);
    fill_kernel<<<(NEDGE + 255) / 256, 256, 0, stream>>>(ei, et, cursor3, sorted);

    hist1_kernel<<<(NNODE + 3) / 4, 256, 0, stream>>>(offs3, sorted, nfTab, rcntBuf, A1h, A1l);

    gemm1_mfma_kernel<<<(NNODE + 63) / 64, 256, 0, stream>>>(
        A1h, A1l, B1th, B1tl, shape_id, color_id, pos, rootTab, b1, A2h, A2l);

    aggregate_kernel<<<(NNODE + 3) / 4, 256, 0, stream>>>(offs3, sorted, rcntBuf, A2h, A2l);

    gemm2_mfma_kernel<<<(NNODE + 63) / 64, 256, 0, stream>>>(
        A2h, A2l, Bt_hi, Bt_lo, b2, x2);

    pool_kernel<<<(NNODE + 63) / 64, 128, 0, stream>>>(x2, batch, pooled, cntg);

    final_kernel<<<(GNUM * 4 + 255) / 256, 256, 0, stream>>>(
        pooled, cntg, lin_w, lin_b, out);
}

// Round 11
// 195.317 us; speedup vs baseline: 1.9370x; 1.2107x over previous
//
#include <hip/hip_runtime.h>
#include <hip/hip_bf16.h>

#define NNODE 50000
#define NEDGE 640000
#define NREL  3
#define HIDD  128
#define GNUM  512
#define K1M   128   // layer-1 GEMM K (99 used + pad to 128 for MFMA)
#define K2    512   // layer-2 GEMM K (3*128 relations + 128 root)
#define NB    196   // scan blocks = ceil(NNODE/256)

typedef float  f32x4   __attribute__((ext_vector_type(4)));
typedef short  vshort8 __attribute__((ext_vector_type(8)));
typedef short  vshort4 __attribute__((ext_vector_type(4)));

// swizzled k-block position within a 32-short row (MFMA LDS, conflict-free)
#define SWZ(row, kb) ((((kb) ^ (((row) >> 1) & 3)) << 3))

// ---------------- builders ----------------
__global__ void build_tabs_kernel(const float* __restrict__ shape_w,
                                  const float* __restrict__ color_w,
                                  const float* __restrict__ W1,
                                  const float* __restrict__ root1,
                                  float* __restrict__ B1eff,
                                  float* __restrict__ rootTab) {
    int idx = blockIdx.x * blockDim.x + threadIdx.x;
    if (idx >= 4 * 33 * 128) return;
    int h  = idx & 127;
    int j  = (idx >> 7) % 33;
    int rr = idx / (33 * 128);
    const float* Wsrc = (rr < 3) ? (W1 + (size_t)rr * 129 * 128) : root1; // [129][128]
    float v = 0.f;
    if (j < 16) {
        for (int e = 0; e < 64; ++e) v += shape_w[j * 64 + e] * Wsrc[e * 128 + h];
    } else if (j < 32) {
        int c = j - 16;
        for (int e = 0; e < 64; ++e) v += color_w[c * 64 + e] * Wsrc[(64 + e) * 128 + h];
    } else {
        v = Wsrc[128 * 128 + h];
    }
    if (rr < 3) B1eff[(rr * 33 + j) * 128 + h] = v;
    else        rootTab[j * 128 + h] = v;
}

__device__ __forceinline__ void split_bf16(float f, short& hi, short& lo) {
    unsigned u  = __float_as_uint(f);
    unsigned uh = (u + 0x7FFFu + ((u >> 16) & 1u)) >> 16;
    hi = (short)uh;
    float fl = f - __uint_as_float(uh << 16);
    unsigned ul  = __float_as_uint(fl);
    unsigned ulh = (ul + 0x7FFFu + ((ul >> 16) & 1u)) >> 16;
    lo = (short)ulh;
}

__device__ __forceinline__ short bf16_rne(float f) {
    unsigned u = __float_as_uint(f);
    return (short)((u + 0x7FFFu + ((u >> 16) & 1u)) >> 16);
}

// B1eff [99 used rows][128] -> transposed bf16-hi B1t[n=128][k=128]
__global__ void build_B1t_kernel(const float* __restrict__ B1eff,
                                 short* __restrict__ B1th) {
    int idx = blockIdx.x * blockDim.x + threadIdx.x; // 128*128
    if (idx >= K1M * 128) return;
    int k = idx >> 7, n = idx & 127;
    float v = (k < 99) ? B1eff[k * 128 + n] : 0.f;
    B1th[(size_t)n * K1M + k] = bf16_rne(v);
}

// B2 transposed bf16-hi: Bt[n][k], k<384 -> W2, else root2
__global__ void build_B2t_kernel(const float* __restrict__ W2,
                                 const float* __restrict__ root2,
                                 short* __restrict__ Bt_hi) {
    int idx = blockIdx.x * blockDim.x + threadIdx.x; // 512*128
    if (idx >= K2 * 128) return;
    int k = idx >> 7, n = idx & 127;
    float v = (k < 384) ? W2[idx] : root2[idx - 384 * 128];
    Bt_hi[(size_t)n * K2 + k] = bf16_rne(v);
}

// ---------------- edge counting (atomic returns per-edge rank) + node-feature pack ----------------
__global__ void count_nf_kernel(const int* __restrict__ ei, const int* __restrict__ et,
                                const int* __restrict__ shape_id, const int* __restrict__ color_id,
                                const float* __restrict__ pos,
                                int* __restrict__ cnt, int* __restrict__ rank,
                                int2* __restrict__ nf) {
    int e = blockIdx.x * blockDim.x + threadIdx.x;
    if (e < NNODE) nf[e] = make_int2(shape_id[e] | (color_id[e] << 8), __float_as_int(pos[e]));
    if (e >= NEDGE) return;
    int d = ei[NEDGE + e], r = et[e];
    rank[e] = atomicAdd(&cnt[d * 3 + r], 1);   // rank within (d,r) segment
}

// ---------------- prefix scan over per-node degree (3-phase), relation-major CSR ----------------
__global__ void scan_partial_kernel(const int* __restrict__ cnt, int* __restrict__ partial) {
    __shared__ int sh[256];
    int t = threadIdx.x, i = blockIdx.x * 256 + t;
    int v = (i < NNODE) ? cnt[3 * i] + cnt[3 * i + 1] + cnt[3 * i + 2] : 0;
    sh[t] = v; __syncthreads();
    for (int o = 128; o > 0; o >>= 1) { if (t < o) sh[t] += sh[t + o]; __syncthreads(); }
    if (t == 0) partial[blockIdx.x] = sh[0];
}

__global__ void scan_mid_kernel(const int* __restrict__ partial, int* __restrict__ partial_pre,
                                int* __restrict__ offs3) {
    __shared__ int sh[256];
    int t = threadIdx.x;
    int v = (t < NB) ? partial[t] : 0;
    sh[t] = v; __syncthreads();
    for (int o = 1; o < 256; o <<= 1) {
        int x = (t >= o) ? sh[t - o] : 0; __syncthreads();
        sh[t] += x; __syncthreads();
    }
    if (t < NB) partial_pre[t] = sh[t] - v;
    if (t == 0) offs3[3 * NNODE] = NEDGE;
}

// writes offs3 at (node,rel) granularity: offs3[3d+r]
__global__ void scan_final_kernel(const int* __restrict__ cnt, const int* __restrict__ partial_pre,
                                  int* __restrict__ offs3, float* __restrict__ rcnt) {
    __shared__ int sh[256];
    int t = threadIdx.x, i = blockIdx.x * 256 + t;
    int c0 = 0, c1 = 0, c2 = 0;
    if (i < NNODE) { c0 = cnt[3 * i]; c1 = cnt[3 * i + 1]; c2 = cnt[3 * i + 2]; }
    int v = c0 + c1 + c2;
    sh[t] = v; __syncthreads();
    for (int o = 1; o < 256; o <<= 1) {
        int x = (t >= o) ? sh[t - o] : 0; __syncthreads();
        sh[t] += x; __syncthreads();
    }
    int exc = sh[t] - v + partial_pre[blockIdx.x];
    if (i < NNODE) {
        offs3[3 * i]     = exc;
        offs3[3 * i + 1] = exc + c0;
        offs3[3 * i + 2] = exc + c0 + c1;
        float4 rc = make_float4(1.f / fmaxf((float)c0, 1.f), 1.f / fmaxf((float)c1, 1.f),
                                1.f / fmaxf((float)c2, 1.f), 1.f);
        *(float4*)&rcnt[i * 4] = rc;
    }
}

// ---------------- fill: atomic-free (p = offs3 + precomputed rank) ----------------
__global__ void fill_kernel(const int* __restrict__ ei, const int* __restrict__ et,
                            const int* __restrict__ rank, const int* __restrict__ offs3,
                            int* __restrict__ sorted) {
    int e = blockIdx.x * blockDim.x + threadIdx.x;
    if (e >= NEDGE) return;
    int s = ei[e], d = ei[NEDGE + e], r = et[e];
    int p = offs3[d * 3 + r] + rank[e];
    sorted[p] = s | (r << 16);   // NNODE < 65536, r < 4
}

// ---------------- layer-1 histogram: edge-parallel LDS hist; emits scaled bf16 hi/lo ----------------
__global__ __launch_bounds__(256) void hist1_kernel(const int* __restrict__ offs3,
                                                    const int* __restrict__ sorted,
                                                    const int2* __restrict__ nf,
                                                    const float* __restrict__ rcnt,
                                                    unsigned short* __restrict__ A1h,
                                                    unsigned short* __restrict__ A1l) {
    __shared__ float hist[4][3 * 34];
    int lane = threadIdx.x & 63;
    int wv   = threadIdx.x >> 6;
    int d    = (blockIdx.x << 2) + wv;
    float* hf = hist[wv];
    if (lane < 51) { hf[lane] = 0.f; hf[lane + 51] = 0.f; }
    if (d < NNODE) {
        int beg = offs3[3 * d], end = offs3[3 * d + 3];
        for (int i = beg + lane; i < end; i += 64) {
            int w = sorted[i];
            int s = w & 0xFFFF, r = (w >> 16) & 3;
            int2 f = nf[s];
            atomicAdd(&hf[r * 34 + (f.x & 0xFF)], 1.f);
            atomicAdd(&hf[r * 34 + 16 + (f.x >> 8)], 1.f);
            atomicAdd(&hf[r * 34 + 32], __int_as_float(f.y));
        }
#pragma unroll
        for (int half = 0; half < 2; ++half) {
            int slot = lane + half * 64;                 // 0..127
            float v = 0.f;
            if (slot < 99) {
                int r = slot / 33;
                v = hf[r * 34 + (slot - r * 33)] * rcnt[d * 4 + r];
            }
            short hh, ll;
            split_bf16(v, hh, ll);
            A1h[(size_t)d * K1M + slot] = (unsigned short)hh;
            A1l[(size_t)d * K1M + slot] = (unsigned short)ll;
        }
    }
}

// ---------------- layer-2 aggregation: wave-per-node, segmented, 8-deep ILP ----------------
__global__ __launch_bounds__(256) void aggregate_kernel(const int* __restrict__ offs3,
                                                        const int* __restrict__ sorted,
                                                        const float* __restrict__ rcnt,
                                                        unsigned short* __restrict__ A2h,
                                                        unsigned short* __restrict__ A2l) {
    int lane = threadIdx.x & 63;
    int d = (blockIdx.x << 2) + (threadIdx.x >> 6);
    if (d >= NNODE) return;
    int b0  = __builtin_amdgcn_readfirstlane(offs3[3 * d]);
    int b1  = __builtin_amdgcn_readfirstlane(offs3[3 * d + 1]);
    int b2  = __builtin_amdgcn_readfirstlane(offs3[3 * d + 2]);
    int end = __builtin_amdgcn_readfirstlane(offs3[3 * d + 3]);
    const unsigned* xp = (const unsigned*)A2h;   // row = 256 unsigneds; root block at +192
    float a00 = 0.f, a01 = 0.f, a10 = 0.f, a11 = 0.f, a20 = 0.f, a21 = 0.f;
#define AGG_ACC(ii, x) {                                            \
        float lo_ = __uint_as_float((x) << 16);                     \
        float hi_ = __uint_as_float((x) & 0xFFFF0000u);             \
        if ((ii) >= b2)      { a20 += lo_; a21 += hi_; }            \
        else if ((ii) >= b1) { a10 += lo_; a11 += hi_; }            \
        else                 { a00 += lo_; a01 += hi_; } }
#define AGG_LD(j)  unsigned x##j = xp[((size_t)(unsigned)(sorted[i + j] & 0xFFFF) << 8) + 192 + lane]
    int i = b0;
    for (; i + 8 <= end; i += 8) {
        AGG_LD(0); AGG_LD(1); AGG_LD(2); AGG_LD(3);
        AGG_LD(4); AGG_LD(5); AGG_LD(6); AGG_LD(7);
        AGG_ACC(i, x0); AGG_ACC(i + 1, x1); AGG_ACC(i + 2, x2); AGG_ACC(i + 3, x3);
        AGG_ACC(i + 4, x4); AGG_ACC(i + 5, x5); AGG_ACC(i + 6, x6); AGG_ACC(i + 7, x7);
    }
    for (; i + 4 <= end; i += 4) {
        AGG_LD(0); AGG_LD(1); AGG_LD(2); AGG_LD(3);
        AGG_ACC(i, x0); AGG_ACC(i + 1, x1); AGG_ACC(i + 2, x2); AGG_ACC(i + 3, x3);
    }
    for (; i < end; ++i) {
        AGG_LD(0);
        AGG_ACC(i, x0);
    }
#undef AGG_LD
#undef AGG_ACC
    float rc0 = rcnt[d * 4 + 0], rc1 = rcnt[d * 4 + 1], rc2 = rcnt[d * 4 + 2];
    size_t base = (size_t)d * 512 + (lane << 1);
#define AGG_OUT(vA, vB, rel) {                                        \
        short h0_, l0_, h1_, l1_;                                     \
        split_bf16(vA, h0_, l0_); split_bf16(vB, h1_, l1_);           \
        *(unsigned*)&A2h[base + (rel) * 128] =                        \
            (unsigned)(unsigned short)h0_ | ((unsigned)(unsigned short)h1_ << 16); \
        *(unsigned*)&A2l[base + (rel) * 128] =                        \
            (unsigned)(unsigned short)l0_ | ((unsigned)(unsigned short)l1_ << 16); }
    AGG_OUT(a00 * rc0, a01 * rc0, 0);
    AGG_OUT(a10 * rc1, a11 * rc1, 1);
    AGG_OUT(a20 * rc2, a21 * rc2, 2);
#undef AGG_OUT
}

// ---------------- layer-1 GEMM: MFMA bf16x2 (Ah+Al)xBh, BM=64, swizzled LDS ----------------
__global__ __launch_bounds__(256) void gemm1_mfma_kernel(
    const unsigned short* __restrict__ A1h, const unsigned short* __restrict__ A1l,
    const short* __restrict__ B1th,
    const int* __restrict__ shape_id, const int* __restrict__ color_id,
    const float* __restrict__ pos, const float* __restrict__ rootTab,
    const float* __restrict__ bias,
    unsigned short* __restrict__ A2h, unsigned short* __restrict__ A2l) {
    __shared__ short Ah[64][32];
    __shared__ short Al[64][32];
    __shared__ short Bh[128][32];
    const int t    = threadIdx.x;
    const int lane = t & 63;
    const int w    = t >> 6;
    const int wm   = w >> 1, wn = w & 1;     // wave tile 32(M) x 64(N)
    const int bm0  = blockIdx.x * 64;
    const int lr   = lane & 15, lk = lane >> 4;
    const int sr = t >> 2, skb = t & 3;
    int gra = bm0 + sr; if (gra >= NNODE) gra = NNODE - 1;   // clamp (C-write guarded)
    f32x4 acc[2][4] = {};
    for (int kt = 0; kt < K1M; kt += 32) {
        vshort8 avh = *(const vshort8*)&A1h[(size_t)gra * K1M + kt + skb * 8];
        vshort8 avl = *(const vshort8*)&A1l[(size_t)gra * K1M + kt + skb * 8];
        vshort8 bvh0 = *(const vshort8*)&B1th[(size_t)sr * K1M + kt + skb * 8];
        vshort8 bvh1 = *(const vshort8*)&B1th[(size_t)(sr + 64) * K1M + kt + skb * 8];
        __syncthreads();
        *(vshort8*)&Ah[sr][SWZ(sr, skb)]           = avh;
        *(vshort8*)&Al[sr][SWZ(sr, skb)]           = avl;
        *(vshort8*)&Bh[sr][SWZ(sr, skb)]           = bvh0;
        *(vshort8*)&Bh[sr + 64][SWZ(sr + 64, skb)] = bvh1;
        __syncthreads();
        vshort8 afh[2], afl[2], bfh[4];
#pragma unroll
        for (int mf = 0; mf < 2; ++mf) {
            int row = wm * 32 + mf * 16 + lr;
            afh[mf] = *(const vshort8*)&Ah[row][SWZ(row, lk)];
            afl[mf] = *(const vshort8*)&Al[row][SWZ(row, lk)];
        }
#pragma unroll
        for (int nf = 0; nf < 4; ++nf) {
            int row = wn * 64 + nf * 16 + lr;
            bfh[nf] = *(const vshort8*)&Bh[row][SWZ(row, lk)];
        }
#pragma unroll
        for (int mf = 0; mf < 2; ++mf)
#pragma unroll
            for (int nf = 0; nf < 4; ++nf) {
                acc[mf][nf] = __builtin_amdgcn_mfma_f32_16x16x32_bf16(afh[mf], bfh[nf], acc[mf][nf], 0, 0, 0);
                acc[mf][nf] = __builtin_amdgcn_mfma_f32_16x16x32_bf16(afl[mf], bfh[nf], acc[mf][nf], 0, 0, 0);
            }
    }
    // epilogue: + root lookups + bias, relu, split hi/lo, write A2 root block
#pragma unroll
    for (int mf = 0; mf < 2; ++mf) {
        int mb = bm0 + wm * 32 + mf * 16 + (lane >> 4) * 4;
#pragma unroll
        for (int r = 0; r < 4; ++r) {
            int gm = mb + r;
            if (gm >= NNODE) continue;
            int sid = shape_id[gm], cid = color_id[gm];
            float pv = pos[gm];
#pragma unroll
            for (int nf = 0; nf < 4; ++nf) {
                int n = wn * 64 + nf * 16 + lr;
                float v = acc[mf][nf][r] + rootTab[sid * 128 + n] + rootTab[(16 + cid) * 128 + n]
                        + pv * rootTab[32 * 128 + n] + bias[n];
                float rv = fmaxf(v, 0.f);
                short hh = bf16_rne(rv);
                float hf = __uint_as_float((unsigned)(unsigned short)hh << 16);
                short ll = bf16_rne(rv - hf);
                A2h[(size_t)gm * 512 + 384 + n] = (unsigned short)hh;
                A2l[(size_t)gm * 512 + 384 + n] = (unsigned short)ll;
            }
        }
    }
}

// ---------------- layer-2 GEMM: MFMA bf16x2 (Ah+Al)xBh, BM=64, swizzled LDS ----------------
__global__ __launch_bounds__(256) void gemm2_mfma_kernel(
    const unsigned short* __restrict__ A2h, const unsigned short* __restrict__ A2l,
    const short* __restrict__ Bt_hi,
    const float* __restrict__ bias,
    float* __restrict__ x2) {
    __shared__ short Ah[64][32];   // [row][swizzled k] bf16-hi
    __shared__ short Al[64][32];
    __shared__ short Bh[128][32];
    const int t    = threadIdx.x;
    const int lane = t & 63;
    const int w    = t >> 6;
    const int wm   = w >> 1, wn = w & 1;     // wave tile 32(M) x 64(N)
    const int bm0  = blockIdx.x * 64;
    const int lr   = lane & 15, lk = lane >> 4;
    const int sr = t >> 2, skb = t & 3;
    int gra = bm0 + sr; if (gra >= NNODE) gra = NNODE - 1;   // clamp (C-write guarded)
    f32x4 acc[2][4] = {};
    for (int kt = 0; kt < K2; kt += 32) {
        vshort8 avh = *(const vshort8*)&A2h[(size_t)gra * K2 + kt + skb * 8];
        vshort8 avl = *(const vshort8*)&A2l[(size_t)gra * K2 + kt + skb * 8];
        vshort8 bvh0 = *(const vshort8*)&Bt_hi[(size_t)sr * K2 + kt + skb * 8];
        vshort8 bvh1 = *(const vshort8*)&Bt_hi[(size_t)(sr + 64) * K2 + kt + skb * 8];
        __syncthreads();
        *(vshort8*)&Ah[sr][SWZ(sr, skb)]           = avh;
        *(vshort8*)&Al[sr][SWZ(sr, skb)]           = avl;
        *(vshort8*)&Bh[sr][SWZ(sr, skb)]           = bvh0;
        *(vshort8*)&Bh[sr + 64][SWZ(sr + 64, skb)] = bvh1;
        __syncthreads();
        vshort8 afh[2], afl[2], bfh[4];
#pragma unroll
        for (int mf = 0; mf < 2; ++mf) {
            int row = wm * 32 + mf * 16 + lr;
            afh[mf] = *(const vshort8*)&Ah[row][SWZ(row, lk)];
            afl[mf] = *(const vshort8*)&Al[row][SWZ(row, lk)];
        }
#pragma unroll
        for (int nf = 0; nf < 4; ++nf) {
            int row = wn * 64 + nf * 16 + lr;
            bfh[nf] = *(const vshort8*)&Bh[row][SWZ(row, lk)];
        }
#pragma unroll
        for (int mf = 0; mf < 2; ++mf)
#pragma unroll
            for (int nf = 0; nf < 4; ++nf) {
                acc[mf][nf] = __builtin_amdgcn_mfma_f32_16x16x32_bf16(afh[mf], bfh[nf], acc[mf][nf], 0, 0, 0);
                acc[mf][nf] = __builtin_amdgcn_mfma_f32_16x16x32_bf16(afl[mf], bfh[nf], acc[mf][nf], 0, 0, 0);
            }
    }
#pragma unroll
    for (int mf = 0; mf < 2; ++mf) {
        int mb = bm0 + wm * 32 + mf * 16 + (lane >> 4) * 4;
#pragma unroll
        for (int nf = 0; nf < 4; ++nf) {
            int n = wn * 64 + nf * 16 + lr;
            float bn = bias[n];
#pragma unroll
            for (int r = 0; r < 4; ++r) {
                int gm = mb + r;
                if (gm < NNODE)
                    x2[(size_t)gm * HIDD + n] = fmaxf(acc[mf][nf][r] + bn, 0.f);
            }
        }
    }
}

// ---------------- pooling (batch sorted -> run-length reduce), 64 nodes/block ----------------
__global__ void pool_kernel(const float* __restrict__ x2, const int* __restrict__ batch,
                            float* __restrict__ pooled, float* __restrict__ cntg) {
    const int CH = 64;
    int h  = threadIdx.x; // 128
    int n0 = blockIdx.x * CH;
    if (n0 >= NNODE) return;
    int n1 = min(n0 + CH, NNODE);
    int cur = batch[n0];
    float acc = 0.f;
    int run = 0;
    for (int n = n0; n < n1; ++n) {
        int g = batch[n];
        if (g != cur) {
            atomicAdd(&pooled[cur * 128 + h], acc);
            if (h == 0) atomicAdd(&cntg[cur], (float)run);
            acc = 0.f; run = 0; cur = g;
        }
        acc += x2[(size_t)n * 128 + h];
        ++run;
    }
    atomicAdd(&pooled[cur * 128 + h], acc);
    if (h == 0) atomicAdd(&cntg[cur], (float)run);
}

__global__ void final_kernel(const float* __restrict__ pooled, const float* __restrict__ cntg,
                             const float* __restrict__ lin_w, const float* __restrict__ lin_b,
                             float* __restrict__ out) {
    int idx = blockIdx.x * blockDim.x + threadIdx.x;
    if (idx >= GNUM * 4) return;
    int g = idx >> 2, c = idx & 3;
    float dot = 0.f;
    for (int k = 0; k < 128; ++k) dot += pooled[g * 128 + k] * lin_w[k * 4 + c];
    out[idx] = dot / fmaxf(cntg[g], 1.f) + lin_b[c];
}

// ---------------- launch ----------------
extern "C" void kernel_launch(void* const* d_in, const int* in_sizes, int n_in,
                              void* d_out, int out_size, void* d_ws, size_t ws_size,
                              hipStream_t stream) {
    const float* pos      = (const float*)d_in[0];
    const int*   shape_id = (const int*)d_in[1];
    const int*   color_id = (const int*)d_in[2];
    const int*   ei       = (const int*)d_in[3];
    const int*   et       = (const int*)d_in[4];
    const int*   batch    = (const int*)d_in[5];
    const float* shape_w  = (const float*)d_in[6];
    const float* color_w  = (const float*)d_in[7];
    const float* W1       = (const float*)d_in[8];
    const float* root1    = (const float*)d_in[9];
    const float* b1       = (const float*)d_in[10];
    const float* W2       = (const float*)d_in[11];
    const float* root2    = (const float*)d_in[12];
    const float* b2       = (const float*)d_in[13];
    const float* lin_w    = (const float*)d_in[14];
    const float* lin_b    = (const float*)d_in[15];
    float* out = (float*)d_out;

    char* p = (char*)d_ws;
    auto alloc = [&](size_t bytes) { char* r = p; p += (bytes + 255) & ~(size_t)255; return r; };
    int*   cnt     = (int*)alloc((size_t)NNODE * 3 * 4);
    unsigned short* A1h = (unsigned short*)alloc((size_t)NNODE * K1M * 2);
    unsigned short* A1l = (unsigned short*)alloc((size_t)NNODE * K1M * 2);
    float* rcntBuf = (float*)alloc((size_t)NNODE * 4 * 4);
    unsigned short* A2h = (unsigned short*)alloc((size_t)NNODE * K2 * 2);
    unsigned short* A2l = (unsigned short*)alloc((size_t)NNODE * K2 * 2);
    float* x2      = (float*)alloc((size_t)NNODE * 128 * 4);
    float* B1eff   = (float*)alloc((size_t)112 * 128 * 4);
    float* rootTab = (float*)alloc((size_t)33 * 128 * 4);
    short* B1th    = (short*)alloc((size_t)128 * K1M * 2);
    short* Bt_hi   = (short*)alloc((size_t)128 * K2 * 2);
    float* pooled  = (float*)alloc((size_t)GNUM * 128 * 4);
    float* cntg    = (float*)alloc((size_t)GNUM * 4);
    int2*  nfTab   = (int2*)alloc((size_t)NNODE * 8);
    // CSR temporaries alias into x2 (all consumed before gemm2 writes x2)
    char* xb = (char*)x2;
    int* sorted     = (int*)(xb);                       // E ints  = 2.56 MB
    int* offs3      = (int*)(xb + 2600960);             // 3*NNODE+1 ints = 600 KB
    int* rank       = (int*)(xb + 3201280);             // E ints  = 2.56 MB
    int* partial    = (int*)(xb + 5761536);             // NB ints
    int* partialPre = (int*)(xb + 5771776);             // NB ints

    hipMemsetAsync(cnt,    0, (size_t)NNODE * 3 * 4, stream);
    hipMemsetAsync(B1eff,  0, (size_t)112 * 128 * 4, stream);
    hipMemsetAsync(pooled, 0, (size_t)GNUM * 128 * 4, stream);
    hipMemsetAsync(cntg,   0, (size_t)GNUM * 4, stream);

    build_tabs_kernel<<<(4 * 33 * 128 + 255) / 256, 256, 0, stream>>>(
        shape_w, color_w, W1, root1, B1eff, rootTab);
    build_B1t_kernel<<<(K1M * 128 + 255) / 256, 256, 0, stream>>>(B1eff, B1th);
    build_B2t_kernel<<<(K2 * 128 + 255) / 256, 256, 0, stream>>>(W2, root2, Bt_hi);

    count_nf_kernel<<<(NEDGE + 255) / 256, 256, 0, stream>>>(
        ei, et, shape_id, color_id, pos, cnt, rank, nfTab);
    scan_partial_kernel<<<NB, 256, 0, stream>>>(cnt, partial);
    scan_mid_kernel<<<1, 256, 0, stream>>>(partial, partialPre, offs3);
    scan_final_kernel<<<NB, 256, 0, stream>>>(cnt, partialPre, offs3, rcntBuf);
    fill_kernel<<<(NEDGE + 255) / 256, 256, 0, stream>>>(ei, et, rank, offs3, sorted);

    hist1_kernel<<<(NNODE + 3) / 4, 256, 0, stream>>>(offs3, sorted, nfTab, rcntBuf, A1h, A1l);

    gemm1_mfma_kernel<<<(NNODE + 63) / 64, 256, 0, stream>>>(
        A1h, A1l, B1th, shape_id, color_id, pos, rootTab, b1, A2h, A2l);

    aggregate_kernel<<<(NNODE + 3) / 4, 256, 0, stream>>>(offs3, sorted, rcntBuf, A2h, A2l);

    gemm2_mfma_kernel<<<(NNODE + 63) / 64, 256, 0, stream>>>(
        A2h, A2l, Bt_hi, b2, x2);

    pool_kernel<<<(NNODE + 63) / 64, 128, 0, stream>>>(x2, batch, pooled, cntg);

    final_kernel<<<(GNUM * 4 + 255) / 256, 256, 0, stream>>>(
        pooled, cntg, lin_w, lin_b, out);
}

// Round 12
// 188.693 us; speedup vs baseline: 2.0050x; 1.0351x over previous
//
#include <hip/hip_runtime.h>
#include <hip/hip_bf16.h>

#define NNODE 50000
#define NEDGE 640000
#define NREL  3
#define HIDD  128
#define GNUM  512
#define K1M   128   // layer-1 GEMM K (99 used + pad to 128 for MFMA)
#define K2    512   // layer-2 GEMM K (3*128 relations + 128 root)
#define NB    196   // scan blocks = ceil(NNODE/256)

typedef float  f32x4   __attribute__((ext_vector_type(4)));
typedef short  vshort8 __attribute__((ext_vector_type(8)));

// swizzled k-block position within a 32-short row (MFMA LDS, conflict-free)
#define SWZ(row, kb) ((((kb) ^ (((row) >> 1) & 3)) << 3))

__device__ __forceinline__ void split_bf16(float f, short& hi, short& lo) {
    unsigned u  = __float_as_uint(f);
    unsigned uh = (u + 0x7FFFu + ((u >> 16) & 1u)) >> 16;
    hi = (short)uh;
    float fl = f - __uint_as_float(uh << 16);
    unsigned ul  = __float_as_uint(fl);
    unsigned ulh = (ul + 0x7FFFu + ((ul >> 16) & 1u)) >> 16;
    lo = (short)ulh;
}

__device__ __forceinline__ short bf16_rne(float f) {
    unsigned u = __float_as_uint(f);
    return (short)((u + 0x7FFFu + ((u >> 16) & 1u)) >> 16);
}

// ---------------- builders ----------------
// emits B1th (transposed bf16-hi, k-padded) AND rootTab in one dispatch
__global__ void build_tabs_kernel(const float* __restrict__ shape_w,
                                  const float* __restrict__ color_w,
                                  const float* __restrict__ W1,
                                  const float* __restrict__ root1,
                                  short* __restrict__ B1th,
                                  float* __restrict__ rootTab) {
    int idx = blockIdx.x * blockDim.x + threadIdx.x;
    if (idx < K1M * 128) {                    // B1th[n][k]
        int k = idx >> 7, n = idx & 127;
        float v = 0.f;
        if (k < 99) {
            int r = k / 33, j = k - r * 33;
            const float* Wsrc = W1 + (size_t)r * 129 * 128;
            if (j < 16) {
                for (int e = 0; e < 64; ++e) v += shape_w[j * 64 + e] * Wsrc[e * 128 + n];
            } else if (j < 32) {
                int c = j - 16;
                for (int e = 0; e < 64; ++e) v += color_w[c * 64 + e] * Wsrc[(64 + e) * 128 + n];
            } else {
                v = Wsrc[128 * 128 + n];
            }
        }
        B1th[(size_t)n * K1M + k] = bf16_rne(v);
        return;
    }
    int idx2 = idx - K1M * 128;
    if (idx2 >= 33 * 128) return;             // rootTab[j][h]
    int h = idx2 & 127, j = idx2 >> 7;
    float v;
    if (j < 16) {
        v = 0.f;
        for (int e = 0; e < 64; ++e) v += shape_w[j * 64 + e] * root1[e * 128 + h];
    } else if (j < 32) {
        int c = j - 16;
        v = 0.f;
        for (int e = 0; e < 64; ++e) v += color_w[c * 64 + e] * root1[(64 + e) * 128 + h];
    } else {
        v = root1[128 * 128 + h];
    }
    rootTab[j * 128 + h] = v;
}

// B2 transposed bf16-hi: Bt[n][k], k<384 -> W2, else root2
__global__ void build_B2t_kernel(const float* __restrict__ W2,
                                 const float* __restrict__ root2,
                                 short* __restrict__ Bt_hi) {
    int idx = blockIdx.x * blockDim.x + threadIdx.x; // 512*128
    if (idx >= K2 * 128) return;
    int k = idx >> 7, n = idx & 127;
    float v = (k < 384) ? W2[idx] : root2[idx - 384 * 128];
    Bt_hi[(size_t)n * K2 + k] = bf16_rne(v);
}

// ---------------- edge counting (atomic returns per-edge rank) + node-feature pack ----------------
__global__ void count_nf_kernel(const int* __restrict__ ei, const int* __restrict__ et,
                                const int* __restrict__ shape_id, const int* __restrict__ color_id,
                                const float* __restrict__ pos,
                                int* __restrict__ cnt, int* __restrict__ rank,
                                int2* __restrict__ nf) {
    int e = blockIdx.x * blockDim.x + threadIdx.x;
    if (e < NNODE) nf[e] = make_int2(shape_id[e] | (color_id[e] << 8), __float_as_int(pos[e]));
    if (e >= NEDGE) return;
    int d = ei[NEDGE + e], r = et[e];
    rank[e] = atomicAdd(&cnt[d * 3 + r], 1);   // rank within (d,r) segment
}

// ---------------- prefix scan over per-node degree (3-phase), relation-major CSR ----------------
__global__ void scan_partial_kernel(const int* __restrict__ cnt, int* __restrict__ partial) {
    __shared__ int sh[256];
    int t = threadIdx.x, i = blockIdx.x * 256 + t;
    int v = (i < NNODE) ? cnt[3 * i] + cnt[3 * i + 1] + cnt[3 * i + 2] : 0;
    sh[t] = v; __syncthreads();
    for (int o = 128; o > 0; o >>= 1) { if (t < o) sh[t] += sh[t + o]; __syncthreads(); }
    if (t == 0) partial[blockIdx.x] = sh[0];
}

__global__ void scan_mid_kernel(const int* __restrict__ partial, int* __restrict__ partial_pre,
                                int* __restrict__ offs3) {
    __shared__ int sh[256];
    int t = threadIdx.x;
    int v = (t < NB) ? partial[t] : 0;
    sh[t] = v; __syncthreads();
    for (int o = 1; o < 256; o <<= 1) {
        int x = (t >= o) ? sh[t - o] : 0; __syncthreads();
        sh[t] += x; __syncthreads();
    }
    if (t < NB) partial_pre[t] = sh[t] - v;
    if (t == 0) offs3[3 * NNODE] = NEDGE;
}

// writes offs3 at (node,rel) granularity: offs3[3d+r]
__global__ void scan_final_kernel(const int* __restrict__ cnt, const int* __restrict__ partial_pre,
                                  int* __restrict__ offs3, float* __restrict__ rcnt) {
    __shared__ int sh[256];
    int t = threadIdx.x, i = blockIdx.x * 256 + t;
    int c0 = 0, c1 = 0, c2 = 0;
    if (i < NNODE) { c0 = cnt[3 * i]; c1 = cnt[3 * i + 1]; c2 = cnt[3 * i + 2]; }
    int v = c0 + c1 + c2;
    sh[t] = v; __syncthreads();
    for (int o = 1; o < 256; o <<= 1) {
        int x = (t >= o) ? sh[t - o] : 0; __syncthreads();
        sh[t] += x; __syncthreads();
    }
    int exc = sh[t] - v + partial_pre[blockIdx.x];
    if (i < NNODE) {
        offs3[3 * i]     = exc;
        offs3[3 * i + 1] = exc + c0;
        offs3[3 * i + 2] = exc + c0 + c1;
        float4 rc = make_float4(1.f / fmaxf((float)c0, 1.f), 1.f / fmaxf((float)c1, 1.f),
                                1.f / fmaxf((float)c2, 1.f), 1.f);
        *(float4*)&rcnt[i * 4] = rc;
    }
}

// ---------------- fill: atomic-free (p = offs3 + precomputed rank) ----------------
__global__ void fill_kernel(const int* __restrict__ ei, const int* __restrict__ et,
                            const int* __restrict__ rank, const int* __restrict__ offs3,
                            int* __restrict__ sorted) {
    int e = blockIdx.x * blockDim.x + threadIdx.x;
    if (e >= NEDGE) return;
    int s = ei[e], d = ei[NEDGE + e], r = et[e];
    int p = offs3[d * 3 + r] + rank[e];
    sorted[p] = s | (r << 16);   // NNODE < 65536, r < 4
}

// ---------------- layer-1 histogram: edge-parallel LDS hist; emits scaled bf16-hi ----------------
__global__ __launch_bounds__(256) void hist1_kernel(const int* __restrict__ offs3,
                                                    const int* __restrict__ sorted,
                                                    const int2* __restrict__ nf,
                                                    const float* __restrict__ rcnt,
                                                    unsigned short* __restrict__ A1h) {
    __shared__ float hist[4][3 * 34];
    int lane = threadIdx.x & 63;
    int wv   = threadIdx.x >> 6;
    int d    = (blockIdx.x << 2) + wv;
    float* hf = hist[wv];
    if (lane < 51) { hf[lane] = 0.f; hf[lane + 51] = 0.f; }
    if (d < NNODE) {
        int beg = offs3[3 * d], end = offs3[3 * d + 3];
        for (int i = beg + lane; i < end; i += 64) {
            int w = sorted[i];
            int s = w & 0xFFFF, r = (w >> 16) & 3;
            int2 f = nf[s];
            atomicAdd(&hf[r * 34 + (f.x & 0xFF)], 1.f);
            atomicAdd(&hf[r * 34 + 16 + (f.x >> 8)], 1.f);
            atomicAdd(&hf[r * 34 + 32], __int_as_float(f.y));
        }
#pragma unroll
        for (int half = 0; half < 2; ++half) {
            int slot = lane + half * 64;                 // 0..127
            float v = 0.f;
            if (slot < 99) {
                int r = slot / 33;
                v = hf[r * 34 + (slot - r * 33)] * rcnt[d * 4 + r];
            }
            A1h[(size_t)d * K1M + slot] = (unsigned short)bf16_rne(v);
        }
    }
}

// ---------------- layer-2 aggregation: wave-per-node, segmented, 8-deep ILP ----------------
__global__ __launch_bounds__(256) void aggregate_kernel(const int* __restrict__ offs3,
                                                        const int* __restrict__ sorted,
                                                        const float* __restrict__ rcnt,
                                                        unsigned short* __restrict__ A2h,
                                                        unsigned short* __restrict__ A2l) {
    int lane = threadIdx.x & 63;
    int d = (blockIdx.x << 2) + (threadIdx.x >> 6);
    if (d >= NNODE) return;
    int b0  = __builtin_amdgcn_readfirstlane(offs3[3 * d]);
    int b1  = __builtin_amdgcn_readfirstlane(offs3[3 * d + 1]);
    int b2  = __builtin_amdgcn_readfirstlane(offs3[3 * d + 2]);
    int end = __builtin_amdgcn_readfirstlane(offs3[3 * d + 3]);
    const unsigned* xp = (const unsigned*)A2h;   // row = 256 unsigneds; root block at +192
    float a00 = 0.f, a01 = 0.f, a10 = 0.f, a11 = 0.f, a20 = 0.f, a21 = 0.f;
#define AGG_ACC(ii, x) {                                            \
        float lo_ = __uint_as_float((x) << 16);                     \
        float hi_ = __uint_as_float((x) & 0xFFFF0000u);             \
        if ((ii) >= b2)      { a20 += lo_; a21 += hi_; }            \
        else if ((ii) >= b1) { a10 += lo_; a11 += hi_; }            \
        else                 { a00 += lo_; a01 += hi_; } }
#define AGG_LD(j)  unsigned x##j = xp[((size_t)(unsigned)(sorted[i + j] & 0xFFFF) << 8) + 192 + lane]
    int i = b0;
    for (; i + 8 <= end; i += 8) {
        AGG_LD(0); AGG_LD(1); AGG_LD(2); AGG_LD(3);
        AGG_LD(4); AGG_LD(5); AGG_LD(6); AGG_LD(7);
        AGG_ACC(i, x0); AGG_ACC(i + 1, x1); AGG_ACC(i + 2, x2); AGG_ACC(i + 3, x3);
        AGG_ACC(i + 4, x4); AGG_ACC(i + 5, x5); AGG_ACC(i + 6, x6); AGG_ACC(i + 7, x7);
    }
    for (; i + 4 <= end; i += 4) {
        AGG_LD(0); AGG_LD(1); AGG_LD(2); AGG_LD(3);
        AGG_ACC(i, x0); AGG_ACC(i + 1, x1); AGG_ACC(i + 2, x2); AGG_ACC(i + 3, x3);
    }
    for (; i < end; ++i) {
        AGG_LD(0);
        AGG_ACC(i, x0);
    }
#undef AGG_LD
#undef AGG_ACC
    float rc0 = rcnt[d * 4 + 0], rc1 = rcnt[d * 4 + 1], rc2 = rcnt[d * 4 + 2];
    size_t base = (size_t)d * 512 + (lane << 1);
#define AGG_OUT(vA, vB, rel) {                                        \
        short h0_, l0_, h1_, l1_;                                     \
        split_bf16(vA, h0_, l0_); split_bf16(vB, h1_, l1_);           \
        *(unsigned*)&A2h[base + (rel) * 128] =                        \
            (unsigned)(unsigned short)h0_ | ((unsigned)(unsigned short)h1_ << 16); \
        *(unsigned*)&A2l[base + (rel) * 128] =                        \
            (unsigned)(unsigned short)l0_ | ((unsigned)(unsigned short)l1_ << 16); }
    AGG_OUT(a00 * rc0, a01 * rc0, 0);
    AGG_OUT(a10 * rc1, a11 * rc1, 1);
    AGG_OUT(a20 * rc2, a21 * rc2, 2);
#undef AGG_OUT
}

// ---------------- layer-1 GEMM: MFMA bf16 AhxBh, BM=64, swizzled LDS, fused root epilogue ----------------
__global__ __launch_bounds__(256) void gemm1_mfma_kernel(
    const unsigned short* __restrict__ A1h,
    const short* __restrict__ B1th,
    const int* __restrict__ shape_id, const int* __restrict__ color_id,
    const float* __restrict__ pos, const float* __restrict__ rootTab,
    const float* __restrict__ bias,
    unsigned short* __restrict__ A2h, unsigned short* __restrict__ A2l) {
    __shared__ short Ah[64][32];
    __shared__ short Bh[128][32];
    const int t    = threadIdx.x;
    const int lane = t & 63;
    const int w    = t >> 6;
    const int wm   = w >> 1, wn = w & 1;     // wave tile 32(M) x 64(N)
    const int bm0  = blockIdx.x * 64;
    const int lr   = lane & 15, lk = lane >> 4;
    const int sr = t >> 2, skb = t & 3;
    int gra = bm0 + sr; if (gra >= NNODE) gra = NNODE - 1;   // clamp (C-write guarded)
    f32x4 acc[2][4] = {};
    for (int kt = 0; kt < K1M; kt += 32) {
        vshort8 avh = *(const vshort8*)&A1h[(size_t)gra * K1M + kt + skb * 8];
        vshort8 bvh0 = *(const vshort8*)&B1th[(size_t)sr * K1M + kt + skb * 8];
        vshort8 bvh1 = *(const vshort8*)&B1th[(size_t)(sr + 64) * K1M + kt + skb * 8];
        __syncthreads();
        *(vshort8*)&Ah[sr][SWZ(sr, skb)]           = avh;
        *(vshort8*)&Bh[sr][SWZ(sr, skb)]           = bvh0;
        *(vshort8*)&Bh[sr + 64][SWZ(sr + 64, skb)] = bvh1;
        __syncthreads();
        vshort8 afh[2], bfh[4];
#pragma unroll
        for (int mf = 0; mf < 2; ++mf) {
            int row = wm * 32 + mf * 16 + lr;
            afh[mf] = *(const vshort8*)&Ah[row][SWZ(row, lk)];
        }
#pragma unroll
        for (int nf = 0; nf < 4; ++nf) {
            int row = wn * 64 + nf * 16 + lr;
            bfh[nf] = *(const vshort8*)&Bh[row][SWZ(row, lk)];
        }
#pragma unroll
        for (int mf = 0; mf < 2; ++mf)
#pragma unroll
            for (int nf = 0; nf < 4; ++nf)
                acc[mf][nf] = __builtin_amdgcn_mfma_f32_16x16x32_bf16(afh[mf], bfh[nf], acc[mf][nf], 0, 0, 0);
    }
    // epilogue: + root lookups + bias, relu, split hi/lo, write A2 root block
#pragma unroll
    for (int mf = 0; mf < 2; ++mf) {
        int mb = bm0 + wm * 32 + mf * 16 + (lane >> 4) * 4;
#pragma unroll
        for (int r = 0; r < 4; ++r) {
            int gm = mb + r;
            if (gm >= NNODE) continue;
            int sid = shape_id[gm], cid = color_id[gm];
            float pv = pos[gm];
#pragma unroll
            for (int nf = 0; nf < 4; ++nf) {
                int n = wn * 64 + nf * 16 + lr;
                float v = acc[mf][nf][r] + rootTab[sid * 128 + n] + rootTab[(16 + cid) * 128 + n]
                        + pv * rootTab[32 * 128 + n] + bias[n];
                float rv = fmaxf(v, 0.f);
                short hh = bf16_rne(rv);
                float hf = __uint_as_float((unsigned)(unsigned short)hh << 16);
                short ll = bf16_rne(rv - hf);
                A2h[(size_t)gm * 512 + 384 + n] = (unsigned short)hh;
                A2l[(size_t)gm * 512 + 384 + n] = (unsigned short)ll;
            }
        }
    }
}

// ---------------- layer-2 GEMM: MFMA bf16x2 (Ah+Al)xBh, BM=64, swizzled LDS ----------------
__global__ __launch_bounds__(256) void gemm2_mfma_kernel(
    const unsigned short* __restrict__ A2h, const unsigned short* __restrict__ A2l,
    const short* __restrict__ Bt_hi,
    const float* __restrict__ bias,
    unsigned short* __restrict__ x2b) {
    __shared__ short Ah[64][32];   // [row][swizzled k] bf16-hi
    __shared__ short Al[64][32];
    __shared__ short Bh[128][32];
    const int t    = threadIdx.x;
    const int lane = t & 63;
    const int w    = t >> 6;
    const int wm   = w >> 1, wn = w & 1;     // wave tile 32(M) x 64(N)
    const int bm0  = blockIdx.x * 64;
    const int lr   = lane & 15, lk = lane >> 4;
    const int sr = t >> 2, skb = t & 3;
    int gra = bm0 + sr; if (gra >= NNODE) gra = NNODE - 1;   // clamp (C-write guarded)
    f32x4 acc[2][4] = {};
    for (int kt = 0; kt < K2; kt += 32) {
        vshort8 avh = *(const vshort8*)&A2h[(size_t)gra * K2 + kt + skb * 8];
        vshort8 avl = *(const vshort8*)&A2l[(size_t)gra * K2 + kt + skb * 8];
        vshort8 bvh0 = *(const vshort8*)&Bt_hi[(size_t)sr * K2 + kt + skb * 8];
        vshort8 bvh1 = *(const vshort8*)&Bt_hi[(size_t)(sr + 64) * K2 + kt + skb * 8];
        __syncthreads();
        *(vshort8*)&Ah[sr][SWZ(sr, skb)]           = avh;
        *(vshort8*)&Al[sr][SWZ(sr, skb)]           = avl;
        *(vshort8*)&Bh[sr][SWZ(sr, skb)]           = bvh0;
        *(vshort8*)&Bh[sr + 64][SWZ(sr + 64, skb)] = bvh1;
        __syncthreads();
        vshort8 afh[2], afl[2], bfh[4];
#pragma unroll
        for (int mf = 0; mf < 2; ++mf) {
            int row = wm * 32 + mf * 16 + lr;
            afh[mf] = *(const vshort8*)&Ah[row][SWZ(row, lk)];
            afl[mf] = *(const vshort8*)&Al[row][SWZ(row, lk)];
        }
#pragma unroll
        for (int nf = 0; nf < 4; ++nf) {
            int row = wn * 64 + nf * 16 + lr;
            bfh[nf] = *(const vshort8*)&Bh[row][SWZ(row, lk)];
        }
#pragma unroll
        for (int mf = 0; mf < 2; ++mf)
#pragma unroll
            for (int nf = 0; nf < 4; ++nf) {
                acc[mf][nf] = __builtin_amdgcn_mfma_f32_16x16x32_bf16(afh[mf], bfh[nf], acc[mf][nf], 0, 0, 0);
                acc[mf][nf] = __builtin_amdgcn_mfma_f32_16x16x32_bf16(afl[mf], bfh[nf], acc[mf][nf], 0, 0, 0);
            }
    }
#pragma unroll
    for (int mf = 0; mf < 2; ++mf) {
        int mb = bm0 + wm * 32 + mf * 16 + (lane >> 4) * 4;
#pragma unroll
        for (int nf = 0; nf < 4; ++nf) {
            int n = wn * 64 + nf * 16 + lr;
            float bn = bias[n];
#pragma unroll
            for (int r = 0; r < 4; ++r) {
                int gm = mb + r;
                if (gm < NNODE)
                    x2b[(size_t)gm * HIDD + n] =
                        (unsigned short)bf16_rne(fmaxf(acc[mf][nf][r] + bn, 0.f));
            }
        }
    }
}

// ---------------- pooling (batch sorted -> run-length reduce), bf16 input ----------------
__global__ void pool_kernel(const unsigned short* __restrict__ x2b, const int* __restrict__ batch,
                            float* __restrict__ pooled, float* __restrict__ cntg) {
    const int CH = 64;
    int h  = threadIdx.x; // 128
    int n0 = blockIdx.x * CH;
    if (n0 >= NNODE) return;
    int n1 = min(n0 + CH, NNODE);
    int cur = batch[n0];
    float acc = 0.f;
    int run = 0;
    for (int n = n0; n < n1; ++n) {
        int g = batch[n];
        if (g != cur) {
            atomicAdd(&pooled[cur * 128 + h], acc);
            if (h == 0) atomicAdd(&cntg[cur], (float)run);
            acc = 0.f; run = 0; cur = g;
        }
        acc += __uint_as_float((unsigned)x2b[(size_t)n * 128 + h] << 16);
        ++run;
    }
    atomicAdd(&pooled[cur * 128 + h], acc);
    if (h == 0) atomicAdd(&cntg[cur], (float)run);
}

__global__ void final_kernel(const float* __restrict__ pooled, const float* __restrict__ cntg,
                             const float* __restrict__ lin_w, const float* __restrict__ lin_b,
                             float* __restrict__ out) {
    int idx = blockIdx.x * blockDim.x + threadIdx.x;
    if (idx >= GNUM * 4) return;
    int g = idx >> 2, c = idx & 3;
    float dot = 0.f;
    for (int k = 0; k < 128; ++k) dot += pooled[g * 128 + k] * lin_w[k * 4 + c];
    out[idx] = dot / fmaxf(cntg[g], 1.f) + lin_b[c];
}

// ---------------- launch ----------------
extern "C" void kernel_launch(void* const* d_in, const int* in_sizes, int n_in,
                              void* d_out, int out_size, void* d_ws, size_t ws_size,
                              hipStream_t stream) {
    const float* pos      = (const float*)d_in[0];
    const int*   shape_id = (const int*)d_in[1];
    const int*   color_id = (const int*)d_in[2];
    const int*   ei       = (const int*)d_in[3];
    const int*   et       = (const int*)d_in[4];
    const int*   batch    = (const int*)d_in[5];
    const float* shape_w  = (const float*)d_in[6];
    const float* color_w  = (const float*)d_in[7];
    const float* W1       = (const float*)d_in[8];
    const float* root1    = (const float*)d_in[9];
    const float* b1       = (const float*)d_in[10];
    const float* W2       = (const float*)d_in[11];
    const float* root2    = (const float*)d_in[12];
    const float* b2       = (const float*)d_in[13];
    const float* lin_w    = (const float*)d_in[14];
    const float* lin_b    = (const float*)d_in[15];
    float* out = (float*)d_out;

    char* p = (char*)d_ws;
    auto alloc = [&](size_t bytes) { char* r = p; p += (bytes + 255) & ~(size_t)255; return r; };
    int*   cnt     = (int*)alloc((size_t)NNODE * 3 * 4);
    unsigned short* A1h = (unsigned short*)alloc((size_t)NNODE * K1M * 2);
    float* rcntBuf = (float*)alloc((size_t)NNODE * 4 * 4);
    unsigned short* A2h = (unsigned short*)alloc((size_t)NNODE * K2 * 2);
    unsigned short* A2l = (unsigned short*)alloc((size_t)NNODE * K2 * 2);
    unsigned short* x2b = (unsigned short*)alloc((size_t)NNODE * 128 * 2);
    float* rootTab = (float*)alloc((size_t)33 * 128 * 4);
    short* B1th    = (short*)alloc((size_t)128 * K1M * 2);
    short* Bt_hi   = (short*)alloc((size_t)128 * K2 * 2);
    float* pooled  = (float*)alloc((size_t)GNUM * 128 * 4);
    float* cntg    = (float*)alloc((size_t)GNUM * 4);
    int2*  nfTab   = (int2*)alloc((size_t)NNODE * 8);
    // CSR temporaries alias into x2b (12.8 MB; all consumed before gemm2 writes x2b)
    char* xb = (char*)x2b;
    int* sorted     = (int*)(xb);                       // E ints  = 2.56 MB
    int* offs3      = (int*)(xb + 2600960);             // 3*NNODE+1 ints = 600 KB
    int* rank       = (int*)(xb + 3201280);             // E ints  = 2.56 MB
    int* partial    = (int*)(xb + 5761536);             // NB ints
    int* partialPre = (int*)(xb + 5771776);             // NB ints

    hipMemsetAsync(cnt,    0, (size_t)NNODE * 3 * 4, stream);
    hipMemsetAsync(pooled, 0, (size_t)GNUM * 128 * 4, stream);
    hipMemsetAsync(cntg,   0, (size_t)GNUM * 4, stream);

    build_tabs_kernel<<<(K1M * 128 + 33 * 128 + 255) / 256, 256, 0, stream>>>(
        shape_w, color_w, W1, root1, B1th, rootTab);
    build_B2t_kernel<<<(K2 * 128 + 255) / 256, 256, 0, stream>>>(W2, root2, Bt_hi);

    count_nf_kernel<<<(NEDGE + 255) / 256, 256, 0, stream>>>(
        ei, et, shape_id, color_id, pos, cnt, rank, nfTab);
    scan_partial_kernel<<<NB, 256, 0, stream>>>(cnt, partial);
    scan_mid_kernel<<<1, 256, 0, stream>>>(partial, partialPre, offs3);
    scan_final_kernel<<<NB, 256, 0, stream>>>(cnt, partialPre, offs3, rcntBuf);
    fill_kernel<<<(NEDGE + 255) / 256, 256, 0, stream>>>(ei, et, rank, offs3, sorted);

    hist1_kernel<<<(NNODE + 3) / 4, 256, 0, stream>>>(offs3, sorted, nfTab, rcntBuf, A1h);

    gemm1_mfma_kernel<<<(NNODE + 63) / 64, 256, 0, stream>>>(
        A1h, B1th, shape_id, color_id, pos, rootTab, b1, A2h, A2l);

    aggregate_kernel<<<(NNODE + 3) / 4, 256, 0, stream>>>(offs3, sorted, rcntBuf, A2h, A2l);

    gemm2_mfma_kernel<<<(NNODE + 63) / 64, 256, 0, stream>>>(
        A2h, A2l, Bt_hi, b2, x2b);

    pool_kernel<<<(NNODE + 63) / 64, 128, 0, stream>>>(x2b, batch, pooled, cntg);

    final_kernel<<<(GNUM * 4 + 255) / 256, 256, 0, stream>>>(
        pooled, cntg, lin_w, lin_b, out);
}

// Round 13
// 172.376 us; speedup vs baseline: 2.1948x; 1.0947x over previous
//
#include <hip/hip_runtime.h>
#include <hip/hip_bf16.h>

#define NNODE 50000
#define NEDGE 640000
#define NREL  3
#define HIDD  128
#define GNUM  512
#define K1M   128   // layer-1 GEMM K (99 used + pad to 128 for MFMA)
#define K2    512   // layer-2 GEMM K (3*128 relations + 128 root)
#define NB    196   // scan blocks = ceil(NNODE/256)

typedef float  f32x4   __attribute__((ext_vector_type(4)));
typedef short  vshort8 __attribute__((ext_vector_type(8)));

// swizzled k-block position within a 32-short row (MFMA LDS, conflict-free)
#define SWZ(row, kb) ((((kb) ^ (((row) >> 1) & 3)) << 3))

__device__ __forceinline__ short bf16_rne(float f) {
    unsigned u = __float_as_uint(f);
    return (short)((u + 0x7FFFu + ((u >> 16) & 1u)) >> 16);
}

// ---------------- single builder: B1th + rootTab + Bt_hi ----------------
__global__ void build_tabs_kernel(const float* __restrict__ shape_w,
                                  const float* __restrict__ color_w,
                                  const float* __restrict__ W1,
                                  const float* __restrict__ root1,
                                  const float* __restrict__ W2,
                                  const float* __restrict__ root2,
                                  short* __restrict__ B1th,
                                  float* __restrict__ rootTab,
                                  short* __restrict__ Bt_hi) {
    int idx = blockIdx.x * blockDim.x + threadIdx.x;
    if (idx < K1M * 128) {                    // B1th[n][k]
        int k = idx >> 7, n = idx & 127;
        float v = 0.f;
        if (k < 99) {
            int r = k / 33, j = k - r * 33;
            const float* Wsrc = W1 + (size_t)r * 129 * 128;
            if (j < 16) {
                for (int e = 0; e < 64; ++e) v += shape_w[j * 64 + e] * Wsrc[e * 128 + n];
            } else if (j < 32) {
                int c = j - 16;
                for (int e = 0; e < 64; ++e) v += color_w[c * 64 + e] * Wsrc[(64 + e) * 128 + n];
            } else {
                v = Wsrc[128 * 128 + n];
            }
        }
        B1th[(size_t)n * K1M + k] = bf16_rne(v);
        return;
    }
    int idx2 = idx - K1M * 128;
    if (idx2 < 33 * 128) {                    // rootTab[j][h]
        int h = idx2 & 127, j = idx2 >> 7;
        float v;
        if (j < 16) {
            v = 0.f;
            for (int e = 0; e < 64; ++e) v += shape_w[j * 64 + e] * root1[e * 128 + h];
        } else if (j < 32) {
            int c = j - 16;
            v = 0.f;
            for (int e = 0; e < 64; ++e) v += color_w[c * 64 + e] * root1[(64 + e) * 128 + h];
        } else {
            v = root1[128 * 128 + h];
        }
        rootTab[j * 128 + h] = v;
        return;
    }
    int idx3 = idx2 - 33 * 128;               // Bt_hi[n][k] (B2 transposed)
    if (idx3 >= K2 * 128) return;
    int k = idx3 >> 7, n = idx3 & 127;
    float v = (k < 384) ? W2[idx3] : root2[idx3 - 384 * 128];
    Bt_hi[(size_t)n * K2 + k] = bf16_rne(v);
}

// ---------------- edge counting (atomic returns per-edge rank) + node-feature pack ----------------
__global__ void count_nf_kernel(const int* __restrict__ ei, const int* __restrict__ et,
                                const int* __restrict__ shape_id, const int* __restrict__ color_id,
                                const float* __restrict__ pos,
                                int* __restrict__ cnt, int* __restrict__ rank,
                                int2* __restrict__ nf) {
    int e = blockIdx.x * blockDim.x + threadIdx.x;
    if (e < NNODE) nf[e] = make_int2(shape_id[e] | (color_id[e] << 8), __float_as_int(pos[e]));
    if (e >= NEDGE) return;
    int d = ei[NEDGE + e], r = et[e];
    rank[e] = atomicAdd(&cnt[d * 3 + r], 1);   // rank within (d,r) segment
}

// ---------------- prefix scan over per-node degree (2-phase), relation-major CSR ----------------
__global__ void scan_partial_kernel(const int* __restrict__ cnt, int* __restrict__ partial) {
    __shared__ int sh[256];
    int t = threadIdx.x, i = blockIdx.x * 256 + t;
    int v = (i < NNODE) ? cnt[3 * i] + cnt[3 * i + 1] + cnt[3 * i + 2] : 0;
    sh[t] = v; __syncthreads();
    for (int o = 128; o > 0; o >>= 1) { if (t < o) sh[t] += sh[t + o]; __syncthreads(); }
    if (t == 0) partial[blockIdx.x] = sh[0];
}

// merged mid+final: each block redundantly scans the 196 partials in LDS
__global__ void scan_final_kernel(const int* __restrict__ cnt, const int* __restrict__ partial,
                                  int* __restrict__ offs3, float* __restrict__ rcnt) {
    __shared__ int shp[256];
    __shared__ int sh[256];
    int t = threadIdx.x, i = blockIdx.x * 256 + t;
    // inclusive scan of block partials (NB <= 256)
    int pv = (t < NB) ? partial[t] : 0;
    shp[t] = pv; __syncthreads();
    for (int o = 1; o < 256; o <<= 1) {
        int x = (t >= o) ? shp[t - o] : 0; __syncthreads();
        shp[t] += x; __syncthreads();
    }
    int blockOff = (blockIdx.x > 0) ? shp[blockIdx.x - 1] : 0;
    // per-element scan within block
    int c0 = 0, c1 = 0, c2 = 0;
    if (i < NNODE) { c0 = cnt[3 * i]; c1 = cnt[3 * i + 1]; c2 = cnt[3 * i + 2]; }
    int v = c0 + c1 + c2;
    sh[t] = v; __syncthreads();
    for (int o = 1; o < 256; o <<= 1) {
        int x = (t >= o) ? sh[t - o] : 0; __syncthreads();
        sh[t] += x; __syncthreads();
    }
    int exc = sh[t] - v + blockOff;
    if (i < NNODE) {
        offs3[3 * i]     = exc;
        offs3[3 * i + 1] = exc + c0;
        offs3[3 * i + 2] = exc + c0 + c1;
        float4 rc = make_float4(1.f / fmaxf((float)c0, 1.f), 1.f / fmaxf((float)c1, 1.f),
                                1.f / fmaxf((float)c2, 1.f), 1.f);
        *(float4*)&rcnt[i * 4] = rc;
    }
    if (blockIdx.x == 0 && t == 0) offs3[3 * NNODE] = NEDGE;
}

// ---------------- fill: atomic-free (p = offs3 + precomputed rank) ----------------
__global__ void fill_kernel(const int* __restrict__ ei, const int* __restrict__ et,
                            const int* __restrict__ rank, const int* __restrict__ offs3,
                            int* __restrict__ sorted) {
    int e = blockIdx.x * blockDim.x + threadIdx.x;
    if (e >= NEDGE) return;
    int s = ei[e], d = ei[NEDGE + e], r = et[e];
    int p = offs3[d * 3 + r] + rank[e];
    sorted[p] = s | (r << 16);   // NNODE < 65536, r < 4
}

// ---------------- layer-1 histogram: edge-parallel LDS hist; emits scaled bf16-hi ----------------
__global__ __launch_bounds__(256) void hist1_kernel(const int* __restrict__ offs3,
                                                    const int* __restrict__ sorted,
                                                    const int2* __restrict__ nf,
                                                    const float* __restrict__ rcnt,
                                                    unsigned short* __restrict__ A1h) {
    __shared__ float hist[4][3 * 34];
    int lane = threadIdx.x & 63;
    int wv   = threadIdx.x >> 6;
    int d    = (blockIdx.x << 2) + wv;
    float* hf = hist[wv];
    if (lane < 51) { hf[lane] = 0.f; hf[lane + 51] = 0.f; }
    if (d < NNODE) {
        int beg = offs3[3 * d], end = offs3[3 * d + 3];
        for (int i = beg + lane; i < end; i += 64) {
            int w = sorted[i];
            int s = w & 0xFFFF, r = (w >> 16) & 3;
            int2 f = nf[s];
            atomicAdd(&hf[r * 34 + (f.x & 0xFF)], 1.f);
            atomicAdd(&hf[r * 34 + 16 + (f.x >> 8)], 1.f);
            atomicAdd(&hf[r * 34 + 32], __int_as_float(f.y));
        }
#pragma unroll
        for (int half = 0; half < 2; ++half) {
            int slot = lane + half * 64;                 // 0..127
            float v = 0.f;
            if (slot < 99) {
                int r = slot / 33;
                v = hf[r * 34 + (slot - r * 33)] * rcnt[d * 4 + r];
            }
            A1h[(size_t)d * K1M + slot] = (unsigned short)bf16_rne(v);
        }
    }
}

// ---------------- layer-2 aggregation: wave-per-node, segmented, 8-deep ILP, hi-only out ----------------
__global__ __launch_bounds__(256) void aggregate_kernel(const int* __restrict__ offs3,
                                                        const int* __restrict__ sorted,
                                                        const float* __restrict__ rcnt,
                                                        unsigned short* __restrict__ A2h) {
    int lane = threadIdx.x & 63;
    int d = (blockIdx.x << 2) + (threadIdx.x >> 6);
    if (d >= NNODE) return;
    int b0  = __builtin_amdgcn_readfirstlane(offs3[3 * d]);
    int b1  = __builtin_amdgcn_readfirstlane(offs3[3 * d + 1]);
    int b2  = __builtin_amdgcn_readfirstlane(offs3[3 * d + 2]);
    int end = __builtin_amdgcn_readfirstlane(offs3[3 * d + 3]);
    const unsigned* xp = (const unsigned*)A2h;   // row = 256 unsigneds; root block at +192
    float a00 = 0.f, a01 = 0.f, a10 = 0.f, a11 = 0.f, a20 = 0.f, a21 = 0.f;
#define AGG_ACC(ii, x) {                                            \
        float lo_ = __uint_as_float((x) << 16);                     \
        float hi_ = __uint_as_float((x) & 0xFFFF0000u);             \
        if ((ii) >= b2)      { a20 += lo_; a21 += hi_; }            \
        else if ((ii) >= b1) { a10 += lo_; a11 += hi_; }            \
        else                 { a00 += lo_; a01 += hi_; } }
#define AGG_LD(j)  unsigned x##j = xp[((size_t)(unsigned)(sorted[i + j] & 0xFFFF) << 8) + 192 + lane]
    int i = b0;
    for (; i + 8 <= end; i += 8) {
        AGG_LD(0); AGG_LD(1); AGG_LD(2); AGG_LD(3);
        AGG_LD(4); AGG_LD(5); AGG_LD(6); AGG_LD(7);
        AGG_ACC(i, x0); AGG_ACC(i + 1, x1); AGG_ACC(i + 2, x2); AGG_ACC(i + 3, x3);
        AGG_ACC(i + 4, x4); AGG_ACC(i + 5, x5); AGG_ACC(i + 6, x6); AGG_ACC(i + 7, x7);
    }
    for (; i + 4 <= end; i += 4) {
        AGG_LD(0); AGG_LD(1); AGG_LD(2); AGG_LD(3);
        AGG_ACC(i, x0); AGG_ACC(i + 1, x1); AGG_ACC(i + 2, x2); AGG_ACC(i + 3, x3);
    }
    for (; i < end; ++i) {
        AGG_LD(0);
        AGG_ACC(i, x0);
    }
#undef AGG_LD
#undef AGG_ACC
    float rc0 = rcnt[d * 4 + 0], rc1 = rcnt[d * 4 + 1], rc2 = rcnt[d * 4 + 2];
    size_t base = (size_t)d * 512 + (lane << 1);
#define AGG_OUT(vA, vB, rel) {                                        \
        unsigned short h0_ = (unsigned short)bf16_rne(vA);            \
        unsigned short h1_ = (unsigned short)bf16_rne(vB);            \
        *(unsigned*)&A2h[base + (rel) * 128] = (unsigned)h0_ | ((unsigned)h1_ << 16); }
    AGG_OUT(a00 * rc0, a01 * rc0, 0);
    AGG_OUT(a10 * rc1, a11 * rc1, 1);
    AGG_OUT(a20 * rc2, a21 * rc2, 2);
#undef AGG_OUT
}

// ---------------- layer-1 GEMM: MFMA bf16 AhxBh, BM=64, swizzled LDS, fused root epilogue ----------------
__global__ __launch_bounds__(256) void gemm1_mfma_kernel(
    const unsigned short* __restrict__ A1h,
    const short* __restrict__ B1th,
    const int* __restrict__ shape_id, const int* __restrict__ color_id,
    const float* __restrict__ pos, const float* __restrict__ rootTab,
    const float* __restrict__ bias,
    unsigned short* __restrict__ A2h) {
    __shared__ short Ah[64][32];
    __shared__ short Bh[128][32];
    const int t    = threadIdx.x;
    const int lane = t & 63;
    const int w    = t >> 6;
    const int wm   = w >> 1, wn = w & 1;     // wave tile 32(M) x 64(N)
    const int bm0  = blockIdx.x * 64;
    const int lr   = lane & 15, lk = lane >> 4;
    const int sr = t >> 2, skb = t & 3;
    int gra = bm0 + sr; if (gra >= NNODE) gra = NNODE - 1;   // clamp (C-write guarded)
    f32x4 acc[2][4] = {};
    for (int kt = 0; kt < K1M; kt += 32) {
        vshort8 avh = *(const vshort8*)&A1h[(size_t)gra * K1M + kt + skb * 8];
        vshort8 bvh0 = *(const vshort8*)&B1th[(size_t)sr * K1M + kt + skb * 8];
        vshort8 bvh1 = *(const vshort8*)&B1th[(size_t)(sr + 64) * K1M + kt + skb * 8];
        __syncthreads();
        *(vshort8*)&Ah[sr][SWZ(sr, skb)]           = avh;
        *(vshort8*)&Bh[sr][SWZ(sr, skb)]           = bvh0;
        *(vshort8*)&Bh[sr + 64][SWZ(sr + 64, skb)] = bvh1;
        __syncthreads();
        vshort8 afh[2], bfh[4];
#pragma unroll
        for (int mf = 0; mf < 2; ++mf) {
            int row = wm * 32 + mf * 16 + lr;
            afh[mf] = *(const vshort8*)&Ah[row][SWZ(row, lk)];
        }
#pragma unroll
        for (int nf = 0; nf < 4; ++nf) {
            int row = wn * 64 + nf * 16 + lr;
            bfh[nf] = *(const vshort8*)&Bh[row][SWZ(row, lk)];
        }
#pragma unroll
        for (int mf = 0; mf < 2; ++mf)
#pragma unroll
            for (int nf = 0; nf < 4; ++nf)
                acc[mf][nf] = __builtin_amdgcn_mfma_f32_16x16x32_bf16(afh[mf], bfh[nf], acc[mf][nf], 0, 0, 0);
    }
    // epilogue: + root lookups + bias, relu, write A2 root block (bf16-hi)
#pragma unroll
    for (int mf = 0; mf < 2; ++mf) {
        int mb = bm0 + wm * 32 + mf * 16 + (lane >> 4) * 4;
#pragma unroll
        for (int r = 0; r < 4; ++r) {
            int gm = mb + r;
            if (gm >= NNODE) continue;
            int sid = shape_id[gm], cid = color_id[gm];
            float pv = pos[gm];
#pragma unroll
            for (int nf = 0; nf < 4; ++nf) {
                int n = wn * 64 + nf * 16 + lr;
                float v = acc[mf][nf][r] + rootTab[sid * 128 + n] + rootTab[(16 + cid) * 128 + n]
                        + pv * rootTab[32 * 128 + n] + bias[n];
                A2h[(size_t)gm * 512 + 384 + n] = (unsigned short)bf16_rne(fmaxf(v, 0.f));
            }
        }
    }
}

// ---------------- layer-2 GEMM: MFMA bf16 AhxBh, BM=64, swizzled LDS ----------------
__global__ __launch_bounds__(256) void gemm2_mfma_kernel(
    const unsigned short* __restrict__ A2h,
    const short* __restrict__ Bt_hi,
    const float* __restrict__ bias,
    unsigned short* __restrict__ x2b) {
    __shared__ short Ah[64][32];   // [row][swizzled k] bf16-hi
    __shared__ short Bh[128][32];
    const int t    = threadIdx.x;
    const int lane = t & 63;
    const int w    = t >> 6;
    const int wm   = w >> 1, wn = w & 1;     // wave tile 32(M) x 64(N)
    const int bm0  = blockIdx.x * 64;
    const int lr   = lane & 15, lk = lane >> 4;
    const int sr = t >> 2, skb = t & 3;
    int gra = bm0 + sr; if (gra >= NNODE) gra = NNODE - 1;   // clamp (C-write guarded)
    f32x4 acc[2][4] = {};
    for (int kt = 0; kt < K2; kt += 32) {
        vshort8 avh = *(const vshort8*)&A2h[(size_t)gra * K2 + kt + skb * 8];
        vshort8 bvh0 = *(const vshort8*)&Bt_hi[(size_t)sr * K2 + kt + skb * 8];
        vshort8 bvh1 = *(const vshort8*)&Bt_hi[(size_t)(sr + 64) * K2 + kt + skb * 8];
        __syncthreads();
        *(vshort8*)&Ah[sr][SWZ(sr, skb)]           = avh;
        *(vshort8*)&Bh[sr][SWZ(sr, skb)]           = bvh0;
        *(vshort8*)&Bh[sr + 64][SWZ(sr + 64, skb)] = bvh1;
        __syncthreads();
        vshort8 afh[2], bfh[4];
#pragma unroll
        for (int mf = 0; mf < 2; ++mf) {
            int row = wm * 32 + mf * 16 + lr;
            afh[mf] = *(const vshort8*)&Ah[row][SWZ(row, lk)];
        }
#pragma unroll
        for (int nf = 0; nf < 4; ++nf) {
            int row = wn * 64 + nf * 16 + lr;
            bfh[nf] = *(const vshort8*)&Bh[row][SWZ(row, lk)];
        }
#pragma unroll
        for (int mf = 0; mf < 2; ++mf)
#pragma unroll
            for (int nf = 0; nf < 4; ++nf)
                acc[mf][nf] = __builtin_amdgcn_mfma_f32_16x16x32_bf16(afh[mf], bfh[nf], acc[mf][nf], 0, 0, 0);
    }
#pragma unroll
    for (int mf = 0; mf < 2; ++mf) {
        int mb = bm0 + wm * 32 + mf * 16 + (lane >> 4) * 4;
#pragma unroll
        for (int nf = 0; nf < 4; ++nf) {
            int n = wn * 64 + nf * 16 + lr;
            float bn = bias[n];
#pragma unroll
            for (int r = 0; r < 4; ++r) {
                int gm = mb + r;
                if (gm < NNODE)
                    x2b[(size_t)gm * HIDD + n] =
                        (unsigned short)bf16_rne(fmaxf(acc[mf][nf][r] + bn, 0.f));
            }
        }
    }
}

// ---------------- pooling (batch sorted -> run-length reduce), bf16 input ----------------
__global__ void pool_kernel(const unsigned short* __restrict__ x2b, const int* __restrict__ batch,
                            float* __restrict__ pooled, float* __restrict__ cntg) {
    const int CH = 64;
    int h  = threadIdx.x; // 128
    int n0 = blockIdx.x * CH;
    if (n0 >= NNODE) return;
    int n1 = min(n0 + CH, NNODE);
    int cur = batch[n0];
    float acc = 0.f;
    int run = 0;
    for (int n = n0; n < n1; ++n) {
        int g = batch[n];
        if (g != cur) {
            atomicAdd(&pooled[cur * 128 + h], acc);
            if (h == 0) atomicAdd(&cntg[cur], (float)run);
            acc = 0.f; run = 0; cur = g;
        }
        acc += __uint_as_float((unsigned)x2b[(size_t)n * 128 + h] << 16);
        ++run;
    }
    atomicAdd(&pooled[cur * 128 + h], acc);
    if (h == 0) atomicAdd(&cntg[cur], (float)run);
}

__global__ void final_kernel(const float* __restrict__ pooled, const float* __restrict__ cntg,
                             const float* __restrict__ lin_w, const float* __restrict__ lin_b,
                             float* __restrict__ out) {
    int idx = blockIdx.x * blockDim.x + threadIdx.x;
    if (idx >= GNUM * 4) return;
    int g = idx >> 2, c = idx & 3;
    float dot = 0.f;
    for (int k = 0; k < 128; ++k) dot += pooled[g * 128 + k] * lin_w[k * 4 + c];
    out[idx] = dot / fmaxf(cntg[g], 1.f) + lin_b[c];
}

// ---------------- launch ----------------
extern "C" void kernel_launch(void* const* d_in, const int* in_sizes, int n_in,
                              void* d_out, int out_size, void* d_ws, size_t ws_size,
                              hipStream_t stream) {
    const float* pos      = (const float*)d_in[0];
    const int*   shape_id = (const int*)d_in[1];
    const int*   color_id = (const int*)d_in[2];
    const int*   ei       = (const int*)d_in[3];
    const int*   et       = (const int*)d_in[4];
    const int*   batch    = (const int*)d_in[5];
    const float* shape_w  = (const float*)d_in[6];
    const float* color_w  = (const float*)d_in[7];
    const float* W1       = (const float*)d_in[8];
    const float* root1    = (const float*)d_in[9];
    const float* b1       = (const float*)d_in[10];
    const float* W2       = (const float*)d_in[11];
    const float* root2    = (const float*)d_in[12];
    const float* b2       = (const float*)d_in[13];
    const float* lin_w    = (const float*)d_in[14];
    const float* lin_b    = (const float*)d_in[15];
    float* out = (float*)d_out;

    char* p = (char*)d_ws;
    auto alloc = [&](size_t bytes) { char* r = p; p += (bytes + 255) & ~(size_t)255; return r; };
    int*   cnt     = (int*)alloc((size_t)NNODE * 3 * 4);
    unsigned short* A1h = (unsigned short*)alloc((size_t)NNODE * K1M * 2);
    float* rcntBuf = (float*)alloc((size_t)NNODE * 4 * 4);
    unsigned short* A2h = (unsigned short*)alloc((size_t)NNODE * K2 * 2);
    unsigned short* x2b = (unsigned short*)alloc((size_t)NNODE * 128 * 2);
    float* rootTab = (float*)alloc((size_t)33 * 128 * 4);
    short* B1th    = (short*)alloc((size_t)128 * K1M * 2);
    short* Bt_hi   = (short*)alloc((size_t)128 * K2 * 2);
    float* pooled  = (float*)alloc((size_t)GNUM * 128 * 4);
    float* cntg    = (float*)alloc((size_t)GNUM * 4);
    int2*  nfTab   = (int2*)alloc((size_t)NNODE * 8);
    // CSR temporaries alias into x2b (12.8 MB; all consumed before gemm2 writes x2b)
    char* xb = (char*)x2b;
    int* sorted  = (int*)(xb);                       // E ints  = 2.56 MB
    int* offs3   = (int*)(xb + 2600960);             // 3*NNODE+1 ints = 600 KB
    int* rank    = (int*)(xb + 3201280);             // E ints  = 2.56 MB
    int* partial = (int*)(xb + 5761536);             // NB ints

    hipMemsetAsync(cnt,    0, (size_t)NNODE * 3 * 4, stream);
    hipMemsetAsync(pooled, 0, (size_t)GNUM * 128 * 4, stream);
    hipMemsetAsync(cntg,   0, (size_t)GNUM * 4, stream);

    build_tabs_kernel<<<(K1M * 128 + 33 * 128 + K2 * 128 + 255) / 256, 256, 0, stream>>>(
        shape_w, color_w, W1, root1, W2, root2, B1th, rootTab, Bt_hi);

    count_nf_kernel<<<(NEDGE + 255) / 256, 256, 0, stream>>>(
        ei, et, shape_id, color_id, pos, cnt, rank, nfTab);
    scan_partial_kernel<<<NB, 256, 0, stream>>>(cnt, partial);
    scan_final_kernel<<<NB, 256, 0, stream>>>(cnt, partial, offs3, rcntBuf);
    fill_kernel<<<(NEDGE + 255) / 256, 256, 0, stream>>>(ei, et, rank, offs3, sorted);

    hist1_kernel<<<(NNODE + 3) / 4, 256, 0, stream>>>(offs3, sorted, nfTab, rcntBuf, A1h);

    gemm1_mfma_kernel<<<(NNODE + 63) / 64, 256, 0, stream>>>(
        A1h, B1th, shape_id, color_id, pos, rootTab, b1, A2h);

    aggregate_kernel<<<(NNODE + 3) / 4, 256, 0, stream>>>(offs3, sorted, rcntBuf, A2h);

    gemm2_mfma_kernel<<<(NNODE + 63) / 64, 256, 0, stream>>>(
        A2h, Bt_hi, b2, x2b);

    pool_kernel<<<(NNODE + 63) / 64, 128, 0, stream>>>(x2b, batch, pooled, cntg);

    final_kernel<<<(GNUM * 4 + 255) / 256, 256, 0, stream>>>(
        pooled, cntg, lin_w, lin_b, out);
}

// Round 14
// 170.260 us; speedup vs baseline: 2.2221x; 1.0124x over previous
//
#include <hip/hip_runtime.h>
#include <hip/hip_bf16.h>

#define NNODE 50000
#define NEDGE 640000
#define NREL  3
#define HIDD  128
#define GNUM  512
#define K1M   128   // layer-1 GEMM K (99 used + pad to 128 for MFMA)
#define K2    512   // layer-2 GEMM K (3*128 relations + 128 root)
#define NB    196   // scan blocks = ceil(NNODE/256)

typedef float  f32x4   __attribute__((ext_vector_type(4)));
typedef short  vshort8 __attribute__((ext_vector_type(8)));

// swizzled k-block position within a 32-short row (MFMA LDS, conflict-free)
#define SWZ(row, kb) ((((kb) ^ (((row) >> 1) & 3)) << 3))

__device__ __forceinline__ short bf16_rne(float f) {
    unsigned u = __float_as_uint(f);
    return (short)((u + 0x7FFFu + ((u >> 16) & 1u)) >> 16);
}

// ---------------- single builder: B1th + rootTab + Bt_hi; also zeroes cnt/cntgi ----------------
__global__ void build_tabs_kernel(const float* __restrict__ shape_w,
                                  const float* __restrict__ color_w,
                                  const float* __restrict__ W1,
                                  const float* __restrict__ root1,
                                  const float* __restrict__ W2,
                                  const float* __restrict__ root2,
                                  short* __restrict__ B1th,
                                  float* __restrict__ rootTab,
                                  short* __restrict__ Bt_hi,
                                  int* __restrict__ cnt, int* __restrict__ cntgi) {
    int idx = blockIdx.x * blockDim.x + threadIdx.x;
    // grid-stride zeroing of cnt (3N) + cntgi (GNUM)
    const int NTH = ((K1M * 128 + 33 * 128 + K2 * 128 + 255) / 256) * 256;
    for (int z = idx; z < NNODE * 3 + GNUM; z += NTH) {
        if (z < NNODE * 3) cnt[z] = 0; else cntgi[z - NNODE * 3] = 0;
    }
    if (idx < K1M * 128) {                    // B1th[n][k]
        int k = idx >> 7, n = idx & 127;
        float v = 0.f;
        if (k < 99) {
            int r = k / 33, j = k - r * 33;
            const float* Wsrc = W1 + (size_t)r * 129 * 128;
            if (j < 16) {
                for (int e = 0; e < 64; ++e) v += shape_w[j * 64 + e] * Wsrc[e * 128 + n];
            } else if (j < 32) {
                int c = j - 16;
                for (int e = 0; e < 64; ++e) v += color_w[c * 64 + e] * Wsrc[(64 + e) * 128 + n];
            } else {
                v = Wsrc[128 * 128 + n];
            }
        }
        B1th[(size_t)n * K1M + k] = bf16_rne(v);
        return;
    }
    int idx2 = idx - K1M * 128;
    if (idx2 < 33 * 128) {                    // rootTab[j][h]
        int h = idx2 & 127, j = idx2 >> 7;
        float v;
        if (j < 16) {
            v = 0.f;
            for (int e = 0; e < 64; ++e) v += shape_w[j * 64 + e] * root1[e * 128 + h];
        } else if (j < 32) {
            int c = j - 16;
            v = 0.f;
            for (int e = 0; e < 64; ++e) v += color_w[c * 64 + e] * root1[(64 + e) * 128 + h];
        } else {
            v = root1[128 * 128 + h];
        }
        rootTab[j * 128 + h] = v;
        return;
    }
    int idx3 = idx2 - 33 * 128;               // Bt_hi[n][k] (B2 transposed)
    if (idx3 >= K2 * 128) return;
    int k = idx3 >> 7, n = idx3 & 127;
    float v = (k < 384) ? W2[idx3] : root2[idx3 - 384 * 128];
    Bt_hi[(size_t)n * K2 + k] = bf16_rne(v);
}

// ---------------- edge counting (atomic returns per-edge rank) + nf pack + graph-size hist ----------------
__global__ void count_nf_kernel(const int* __restrict__ ei, const int* __restrict__ et,
                                const int* __restrict__ shape_id, const int* __restrict__ color_id,
                                const float* __restrict__ pos, const int* __restrict__ batch,
                                int* __restrict__ cnt, int* __restrict__ rank,
                                int2* __restrict__ nf, int* __restrict__ cntgi) {
    int e = blockIdx.x * blockDim.x + threadIdx.x;
    if (e < NNODE) {
        nf[e] = make_int2(shape_id[e] | (color_id[e] << 8), __float_as_int(pos[e]));
        atomicAdd(&cntgi[batch[e]], 1);
    }
    if (e >= NEDGE) return;
    int d = ei[NEDGE + e], r = et[e];
    rank[e] = atomicAdd(&cnt[d * 3 + r], 1);   // rank within (d,r) segment
}

// ---------------- prefix scan (2-phase), relation-major CSR; also zeroes pooled ----------------
__global__ void scan_partial_kernel(const int* __restrict__ cnt, int* __restrict__ partial,
                                    float* __restrict__ pooled) {
    __shared__ int sh[256];
    int t = threadIdx.x, i = blockIdx.x * 256 + t;
    for (int z = i; z < GNUM * 128; z += NB * 256) pooled[z] = 0.f;
    int v = (i < NNODE) ? cnt[3 * i] + cnt[3 * i + 1] + cnt[3 * i + 2] : 0;
    sh[t] = v; __syncthreads();
    for (int o = 128; o > 0; o >>= 1) { if (t < o) sh[t] += sh[t + o]; __syncthreads(); }
    if (t == 0) partial[blockIdx.x] = sh[0];
}

// merged mid+final: each block redundantly scans the 196 partials in LDS
__global__ void scan_final_kernel(const int* __restrict__ cnt, const int* __restrict__ partial,
                                  int* __restrict__ offs3, float* __restrict__ rcnt) {
    __shared__ int shp[256];
    __shared__ int sh[256];
    int t = threadIdx.x, i = blockIdx.x * 256 + t;
    int pv = (t < NB) ? partial[t] : 0;
    shp[t] = pv; __syncthreads();
    for (int o = 1; o < 256; o <<= 1) {
        int x = (t >= o) ? shp[t - o] : 0; __syncthreads();
        shp[t] += x; __syncthreads();
    }
    int blockOff = (blockIdx.x > 0) ? shp[blockIdx.x - 1] : 0;
    int c0 = 0, c1 = 0, c2 = 0;
    if (i < NNODE) { c0 = cnt[3 * i]; c1 = cnt[3 * i + 1]; c2 = cnt[3 * i + 2]; }
    int v = c0 + c1 + c2;
    sh[t] = v; __syncthreads();
    for (int o = 1; o < 256; o <<= 1) {
        int x = (t >= o) ? sh[t - o] : 0; __syncthreads();
        sh[t] += x; __syncthreads();
    }
    int exc = sh[t] - v + blockOff;
    if (i < NNODE) {
        offs3[3 * i]     = exc;
        offs3[3 * i + 1] = exc + c0;
        offs3[3 * i + 2] = exc + c0 + c1;
        float4 rc = make_float4(1.f / fmaxf((float)c0, 1.f), 1.f / fmaxf((float)c1, 1.f),
                                1.f / fmaxf((float)c2, 1.f), 1.f);
        *(float4*)&rcnt[i * 4] = rc;
    }
    if (blockIdx.x == 0 && t == 0) offs3[3 * NNODE] = NEDGE;
}

// ---------------- fill: atomic-free (p = offs3 + precomputed rank) ----------------
__global__ void fill_kernel(const int* __restrict__ ei, const int* __restrict__ et,
                            const int* __restrict__ rank, const int* __restrict__ offs3,
                            int* __restrict__ sorted) {
    int e = blockIdx.x * blockDim.x + threadIdx.x;
    if (e >= NEDGE) return;
    int s = ei[e], d = ei[NEDGE + e], r = et[e];
    int p = offs3[d * 3 + r] + rank[e];
    sorted[p] = s | (r << 16);   // NNODE < 65536, r < 4
}

// ---------------- layer-1 histogram: edge-parallel LDS hist; emits scaled bf16-hi ----------------
__global__ __launch_bounds__(256) void hist1_kernel(const int* __restrict__ offs3,
                                                    const int* __restrict__ sorted,
                                                    const int2* __restrict__ nf,
                                                    const float* __restrict__ rcnt,
                                                    unsigned short* __restrict__ A1h) {
    __shared__ float hist[4][3 * 34];
    int lane = threadIdx.x & 63;
    int wv   = threadIdx.x >> 6;
    int d    = (blockIdx.x << 2) + wv;
    float* hf = hist[wv];
    if (lane < 51) { hf[lane] = 0.f; hf[lane + 51] = 0.f; }
    if (d < NNODE) {
        int beg = offs3[3 * d], end = offs3[3 * d + 3];
        for (int i = beg + lane; i < end; i += 64) {
            int w = sorted[i];
            int s = w & 0xFFFF, r = (w >> 16) & 3;
            int2 f = nf[s];
            atomicAdd(&hf[r * 34 + (f.x & 0xFF)], 1.f);
            atomicAdd(&hf[r * 34 + 16 + (f.x >> 8)], 1.f);
            atomicAdd(&hf[r * 34 + 32], __int_as_float(f.y));
        }
#pragma unroll
        for (int half = 0; half < 2; ++half) {
            int slot = lane + half * 64;                 // 0..127
            float v = 0.f;
            if (slot < 99) {
                int r = slot / 33;
                v = hf[r * 34 + (slot - r * 33)] * rcnt[d * 4 + r];
            }
            A1h[(size_t)d * K1M + slot] = (unsigned short)bf16_rne(v);
        }
    }
}

// ---------------- layer-2 aggregation: wave-per-node, segmented, 8-deep ILP, hi-only ----------------
__global__ __launch_bounds__(256) void aggregate_kernel(const int* __restrict__ offs3,
                                                        const int* __restrict__ sorted,
                                                        const float* __restrict__ rcnt,
                                                        unsigned short* __restrict__ A2h) {
    int lane = threadIdx.x & 63;
    int d = (blockIdx.x << 2) + (threadIdx.x >> 6);
    if (d >= NNODE) return;
    int b0  = __builtin_amdgcn_readfirstlane(offs3[3 * d]);
    int b1  = __builtin_amdgcn_readfirstlane(offs3[3 * d + 1]);
    int b2  = __builtin_amdgcn_readfirstlane(offs3[3 * d + 2]);
    int end = __builtin_amdgcn_readfirstlane(offs3[3 * d + 3]);
    const unsigned* xp = (const unsigned*)A2h;   // row = 256 unsigneds; root block at +192
    float a00 = 0.f, a01 = 0.f, a10 = 0.f, a11 = 0.f, a20 = 0.f, a21 = 0.f;
#define AGG_ACC(ii, x) {                                            \
        float lo_ = __uint_as_float((x) << 16);                     \
        float hi_ = __uint_as_float((x) & 0xFFFF0000u);             \
        if ((ii) >= b2)      { a20 += lo_; a21 += hi_; }            \
        else if ((ii) >= b1) { a10 += lo_; a11 += hi_; }            \
        else                 { a00 += lo_; a01 += hi_; } }
#define AGG_LD(j)  unsigned x##j = xp[((size_t)(unsigned)(sorted[i + j] & 0xFFFF) << 8) + 192 + lane]
    int i = b0;
    for (; i + 8 <= end; i += 8) {
        AGG_LD(0); AGG_LD(1); AGG_LD(2); AGG_LD(3);
        AGG_LD(4); AGG_LD(5); AGG_LD(6); AGG_LD(7);
        AGG_ACC(i, x0); AGG_ACC(i + 1, x1); AGG_ACC(i + 2, x2); AGG_ACC(i + 3, x3);
        AGG_ACC(i + 4, x4); AGG_ACC(i + 5, x5); AGG_ACC(i + 6, x6); AGG_ACC(i + 7, x7);
    }
    for (; i + 4 <= end; i += 4) {
        AGG_LD(0); AGG_LD(1); AGG_LD(2); AGG_LD(3);
        AGG_ACC(i, x0); AGG_ACC(i + 1, x1); AGG_ACC(i + 2, x2); AGG_ACC(i + 3, x3);
    }
    for (; i < end; ++i) {
        AGG_LD(0);
        AGG_ACC(i, x0);
    }
#undef AGG_LD
#undef AGG_ACC
    float rc0 = rcnt[d * 4 + 0], rc1 = rcnt[d * 4 + 1], rc2 = rcnt[d * 4 + 2];
    size_t base = (size_t)d * 512 + (lane << 1);
#define AGG_OUT(vA, vB, rel) {                                        \
        unsigned short h0_ = (unsigned short)bf16_rne(vA);            \
        unsigned short h1_ = (unsigned short)bf16_rne(vB);            \
        *(unsigned*)&A2h[base + (rel) * 128] = (unsigned)h0_ | ((unsigned)h1_ << 16); }
    AGG_OUT(a00 * rc0, a01 * rc0, 0);
    AGG_OUT(a10 * rc1, a11 * rc1, 1);
    AGG_OUT(a20 * rc2, a21 * rc2, 2);
#undef AGG_OUT
}

// ---------------- layer-1 GEMM: MFMA bf16 AhxBh, BM=64, swizzled LDS, fused root epilogue ----------------
__global__ __launch_bounds__(256) void gemm1_mfma_kernel(
    const unsigned short* __restrict__ A1h,
    const short* __restrict__ B1th,
    const int* __restrict__ shape_id, const int* __restrict__ color_id,
    const float* __restrict__ pos, const float* __restrict__ rootTab,
    const float* __restrict__ bias,
    unsigned short* __restrict__ A2h) {
    __shared__ short Ah[64][32];
    __shared__ short Bh[128][32];
    const int t    = threadIdx.x;
    const int lane = t & 63;
    const int w    = t >> 6;
    const int wm   = w >> 1, wn = w & 1;     // wave tile 32(M) x 64(N)
    const int bm0  = blockIdx.x * 64;
    const int lr   = lane & 15, lk = lane >> 4;
    const int sr = t >> 2, skb = t & 3;
    int gra = bm0 + sr; if (gra >= NNODE) gra = NNODE - 1;   // clamp (C-write guarded)
    f32x4 acc[2][4] = {};
    for (int kt = 0; kt < K1M; kt += 32) {
        vshort8 avh = *(const vshort8*)&A1h[(size_t)gra * K1M + kt + skb * 8];
        vshort8 bvh0 = *(const vshort8*)&B1th[(size_t)sr * K1M + kt + skb * 8];
        vshort8 bvh1 = *(const vshort8*)&B1th[(size_t)(sr + 64) * K1M + kt + skb * 8];
        __syncthreads();
        *(vshort8*)&Ah[sr][SWZ(sr, skb)]           = avh;
        *(vshort8*)&Bh[sr][SWZ(sr, skb)]           = bvh0;
        *(vshort8*)&Bh[sr + 64][SWZ(sr + 64, skb)] = bvh1;
        __syncthreads();
        vshort8 afh[2], bfh[4];
#pragma unroll
        for (int mf = 0; mf < 2; ++mf) {
            int row = wm * 32 + mf * 16 + lr;
            afh[mf] = *(const vshort8*)&Ah[row][SWZ(row, lk)];
        }
#pragma unroll
        for (int nf = 0; nf < 4; ++nf) {
            int row = wn * 64 + nf * 16 + lr;
            bfh[nf] = *(const vshort8*)&Bh[row][SWZ(row, lk)];
        }
#pragma unroll
        for (int mf = 0; mf < 2; ++mf)
#pragma unroll
            for (int nf = 0; nf < 4; ++nf)
                acc[mf][nf] = __builtin_amdgcn_mfma_f32_16x16x32_bf16(afh[mf], bfh[nf], acc[mf][nf], 0, 0, 0);
    }
    // epilogue: + root lookups + bias, relu, write A2 root block (bf16-hi)
#pragma unroll
    for (int mf = 0; mf < 2; ++mf) {
        int mb = bm0 + wm * 32 + mf * 16 + (lane >> 4) * 4;
#pragma unroll
        for (int r = 0; r < 4; ++r) {
            int gm = mb + r;
            if (gm >= NNODE) continue;
            int sid = shape_id[gm], cid = color_id[gm];
            float pv = pos[gm];
#pragma unroll
            for (int nf = 0; nf < 4; ++nf) {
                int n = wn * 64 + nf * 16 + lr;
                float v = acc[mf][nf][r] + rootTab[sid * 128 + n] + rootTab[(16 + cid) * 128 + n]
                        + pv * rootTab[32 * 128 + n] + bias[n];
                A2h[(size_t)gm * 512 + 384 + n] = (unsigned short)bf16_rne(fmaxf(v, 0.f));
            }
        }
    }
}

// ---------------- layer-2 GEMM: MFMA bf16 AhxBh, BM=64, swizzled LDS, FUSED POOL epilogue ----------------
__global__ __launch_bounds__(256) void gemm2_mfma_kernel(
    const unsigned short* __restrict__ A2h,
    const short* __restrict__ Bt_hi,
    const float* __restrict__ bias,
    const int* __restrict__ batch,
    float* __restrict__ pooled) {
    __shared__ char smem[64 * 132 * 4 + 256];          // Cst[64][132] f32, union w/ Ah,Bh
    short (*Ah)[32]   = (short(*)[32])smem;            // 4 KB
    short (*Bh)[32]   = (short(*)[32])(smem + 4096);   // 8 KB
    float (*Cst)[132] = (float(*)[132])smem;           // 33.8 KB (after compute)
    int*  batchLDS    = (int*)(smem + 64 * 132 * 4);
    const int t    = threadIdx.x;
    const int lane = t & 63;
    const int w    = t >> 6;
    const int wm   = w >> 1, wn = w & 1;     // wave tile 32(M) x 64(N)
    const int bm0  = blockIdx.x * 64;
    const int lr   = lane & 15, lk = lane >> 4;
    const int sr = t >> 2, skb = t & 3;
    int gra = bm0 + sr; if (gra >= NNODE) gra = NNODE - 1;   // clamp (epilogue guarded)
    f32x4 acc[2][4] = {};
    for (int kt = 0; kt < K2; kt += 32) {
        vshort8 avh = *(const vshort8*)&A2h[(size_t)gra * K2 + kt + skb * 8];
        vshort8 bvh0 = *(const vshort8*)&Bt_hi[(size_t)sr * K2 + kt + skb * 8];
        vshort8 bvh1 = *(const vshort8*)&Bt_hi[(size_t)(sr + 64) * K2 + kt + skb * 8];
        __syncthreads();
        *(vshort8*)&Ah[sr][SWZ(sr, skb)]           = avh;
        *(vshort8*)&Bh[sr][SWZ(sr, skb)]           = bvh0;
        *(vshort8*)&Bh[sr + 64][SWZ(sr + 64, skb)] = bvh1;
        __syncthreads();
        vshort8 afh[2], bfh[4];
#pragma unroll
        for (int mf = 0; mf < 2; ++mf) {
            int row = wm * 32 + mf * 16 + lr;
            afh[mf] = *(const vshort8*)&Ah[row][SWZ(row, lk)];
        }
#pragma unroll
        for (int nf = 0; nf < 4; ++nf) {
            int row = wn * 64 + nf * 16 + lr;
            bfh[nf] = *(const vshort8*)&Bh[row][SWZ(row, lk)];
        }
#pragma unroll
        for (int mf = 0; mf < 2; ++mf)
#pragma unroll
            for (int nf = 0; nf < 4; ++nf)
                acc[mf][nf] = __builtin_amdgcn_mfma_f32_16x16x32_bf16(afh[mf], bfh[nf], acc[mf][nf], 0, 0, 0);
    }
    __syncthreads();   // all LDS reads done; reuse smem as Cst
    // stage relu(C) to LDS
#pragma unroll
    for (int mf = 0; mf < 2; ++mf) {
        int rb = wm * 32 + mf * 16 + (lane >> 4) * 4;
#pragma unroll
        for (int nf = 0; nf < 4; ++nf) {
            int n = wn * 64 + nf * 16 + lr;
            float bn = bias[n];
#pragma unroll
            for (int r = 0; r < 4; ++r)
                Cst[rb + r][n] = fmaxf(acc[mf][nf][r] + bn, 0.f);
        }
    }
    if (t < 64) batchLDS[t] = (bm0 + t < NNODE) ? batch[bm0 + t] : -1;
    __syncthreads();
    // run-length reduce 32 rows per thread -> atomicAdd per (graph, col)
    {
        int col  = t & 127;
        int rbeg = (t >> 7) * 32;
        float accp = 0.f;
        int cur = batchLDS[rbeg];
        for (int rr = 0; rr < 32; ++rr) {
            int row = rbeg + rr;
            int g = batchLDS[row];
            if (g != cur) {
                if (cur >= 0) atomicAdd(&pooled[cur * 128 + col], accp);
                accp = 0.f; cur = g;
            }
            if (g >= 0) accp += Cst[row][col];
        }
        if (cur >= 0) atomicAdd(&pooled[cur * 128 + col], accp);
    }
}

__global__ void final_kernel(const float* __restrict__ pooled, const int* __restrict__ cntgi,
                             const float* __restrict__ lin_w, const float* __restrict__ lin_b,
                             float* __restrict__ out) {
    int idx = blockIdx.x * blockDim.x + threadIdx.x;
    if (idx >= GNUM * 4) return;
    int g = idx >> 2, c = idx & 3;
    float dot = 0.f;
    for (int k = 0; k < 128; ++k) dot += pooled[g * 128 + k] * lin_w[k * 4 + c];
    out[idx] = dot / (float)max(cntgi[g], 1) + lin_b[c];
}

// ---------------- launch ----------------
extern "C" void kernel_launch(void* const* d_in, const int* in_sizes, int n_in,
                              void* d_out, int out_size, void* d_ws, size_t ws_size,
                              hipStream_t stream) {
    const float* pos      = (const float*)d_in[0];
    const int*   shape_id = (const int*)d_in[1];
    const int*   color_id = (const int*)d_in[2];
    const int*   ei       = (const int*)d_in[3];
    const int*   et       = (const int*)d_in[4];
    const int*   batch    = (const int*)d_in[5];
    const float* shape_w  = (const float*)d_in[6];
    const float* color_w  = (const float*)d_in[7];
    const float* W1       = (const float*)d_in[8];
    const float* root1    = (const float*)d_in[9];
    const float* b1       = (const float*)d_in[10];
    const float* W2       = (const float*)d_in[11];
    const float* root2    = (const float*)d_in[12];
    const float* b2       = (const float*)d_in[13];
    const float* lin_w    = (const float*)d_in[14];
    const float* lin_b    = (const float*)d_in[15];
    float* out = (float*)d_out;

    char* p = (char*)d_ws;
    auto alloc = [&](size_t bytes) { char* r = p; p += (bytes + 255) & ~(size_t)255; return r; };
    int*   cnt     = (int*)alloc((size_t)NNODE * 3 * 4);
    unsigned short* A1h = (unsigned short*)alloc((size_t)NNODE * K1M * 2);
    float* rcntBuf = (float*)alloc((size_t)NNODE * 4 * 4);
    unsigned short* A2h = (unsigned short*)alloc((size_t)NNODE * K2 * 2);
    float* rootTab = (float*)alloc((size_t)33 * 128 * 4);
    short* B1th    = (short*)alloc((size_t)128 * K1M * 2);
    short* Bt_hi   = (short*)alloc((size_t)128 * K2 * 2);
    float* pooled  = (float*)alloc((size_t)GNUM * 128 * 4);
    int*   cntgi   = (int*)alloc((size_t)GNUM * 4);
    int2*  nfTab   = (int2*)alloc((size_t)NNODE * 8);
    int*   sorted  = (int*)alloc((size_t)NEDGE * 4);
    int*   offs3   = (int*)alloc((size_t)(3 * NNODE + 1) * 4);
    int*   rank    = (int*)alloc((size_t)NEDGE * 4);
    int*   partial = (int*)alloc((size_t)NB * 4);

    build_tabs_kernel<<<(K1M * 128 + 33 * 128 + K2 * 128 + 255) / 256, 256, 0, stream>>>(
        shape_w, color_w, W1, root1, W2, root2, B1th, rootTab, Bt_hi, cnt, cntgi);

    count_nf_kernel<<<(NEDGE + 255) / 256, 256, 0, stream>>>(
        ei, et, shape_id, color_id, pos, batch, cnt, rank, nfTab, cntgi);
    scan_partial_kernel<<<NB, 256, 0, stream>>>(cnt, partial, pooled);
    scan_final_kernel<<<NB, 256, 0, stream>>>(cnt, partial, offs3, rcntBuf);
    fill_kernel<<<(NEDGE + 255) / 256, 256, 0, stream>>>(ei, et, rank, offs3, sorted);

    hist1_kernel<<<(NNODE + 3) / 4, 256, 0, stream>>>(offs3, sorted, nfTab, rcntBuf, A1h);

    gemm1_mfma_kernel<<<(NNODE + 63) / 64, 256, 0, stream>>>(
        A1h, B1th, shape_id, color_id, pos, rootTab, b1, A2h);

    aggregate_kernel<<<(NNODE + 3) / 4, 256, 0, stream>>>(offs3, sorted, rcntBuf, A2h);

    gemm2_mfma_kernel<<<(NNODE + 63) / 64, 256, 0, stream>>>(
        A2h, Bt_hi, b2, batch, pooled);

    final_kernel<<<(GNUM * 4 + 255) / 256, 256, 0, stream>>>(
        pooled, cntgi, lin_w, lin_b, out);
}

// Round 15
// 148.237 us; speedup vs baseline: 2.5522x; 1.1486x over previous
//
#include <hip/hip_runtime.h>
#include <hip/hip_bf16.h>

#define NNODE 50000
#define NEDGE 640000
#define NREL  3
#define HIDD  128
#define GNUM  512
#define K1M   128   // layer-1 GEMM K (99 used + pad to 128 for MFMA)
#define K2    512   // layer-2 GEMM K (3*128 relations + 128 root)
#define NB    196   // scan blocks = ceil(NNODE/256)

typedef float  f32x4   __attribute__((ext_vector_type(4)));
typedef short  vshort8 __attribute__((ext_vector_type(8)));

// swizzled k-block position within a 32-short row (MFMA LDS, conflict-free)
#define SWZ(row, kb) ((((kb) ^ (((row) >> 1) & 3)) << 3))

__device__ __forceinline__ short bf16_rne(float f) {
    unsigned u = __float_as_uint(f);
    return (short)((u + 0x7FFFu + ((u >> 16) & 1u)) >> 16);
}

// ---------------- single builder: B1th + rootTab + Bt_hi; also zeroes cnt ----------------
__global__ void build_tabs_kernel(const float* __restrict__ shape_w,
                                  const float* __restrict__ color_w,
                                  const float* __restrict__ W1,
                                  const float* __restrict__ root1,
                                  const float* __restrict__ W2,
                                  const float* __restrict__ root2,
                                  short* __restrict__ B1th,
                                  float* __restrict__ rootTab,
                                  short* __restrict__ Bt_hi,
                                  int* __restrict__ cnt) {
    int idx = blockIdx.x * blockDim.x + threadIdx.x;
    // grid-stride zeroing of cnt (3N)
    const int NTH = ((K1M * 128 + 33 * 128 + K2 * 128 + 255) / 256) * 256;
    for (int z = idx; z < NNODE * 3; z += NTH) cnt[z] = 0;
    if (idx < K1M * 128) {                    // B1th[n][k]
        int k = idx >> 7, n = idx & 127;
        float v = 0.f;
        if (k < 99) {
            int r = k / 33, j = k - r * 33;
            const float* Wsrc = W1 + (size_t)r * 129 * 128;
            if (j < 16) {
                for (int e = 0; e < 64; ++e) v += shape_w[j * 64 + e] * Wsrc[e * 128 + n];
            } else if (j < 32) {
                int c = j - 16;
                for (int e = 0; e < 64; ++e) v += color_w[c * 64 + e] * Wsrc[(64 + e) * 128 + n];
            } else {
                v = Wsrc[128 * 128 + n];
            }
        }
        B1th[(size_t)n * K1M + k] = bf16_rne(v);
        return;
    }
    int idx2 = idx - K1M * 128;
    if (idx2 < 33 * 128) {                    // rootTab[j][h]
        int h = idx2 & 127, j = idx2 >> 7;
        float v;
        if (j < 16) {
            v = 0.f;
            for (int e = 0; e < 64; ++e) v += shape_w[j * 64 + e] * root1[e * 128 + h];
        } else if (j < 32) {
            int c = j - 16;
            v = 0.f;
            for (int e = 0; e < 64; ++e) v += color_w[c * 64 + e] * root1[(64 + e) * 128 + h];
        } else {
            v = root1[128 * 128 + h];
        }
        rootTab[j * 128 + h] = v;
        return;
    }
    int idx3 = idx2 - 33 * 128;               // Bt_hi[n][k] (B2 transposed)
    if (idx3 >= K2 * 128) return;
    int k = idx3 >> 7, n = idx3 & 127;
    float v = (k < 384) ? W2[idx3] : root2[idx3 - 384 * 128];
    Bt_hi[(size_t)n * K2 + k] = bf16_rne(v);
}

// ---------------- edge counting (atomic returns per-edge rank) + node-feature pack ----------------
__global__ void count_nf_kernel(const int* __restrict__ ei, const int* __restrict__ et,
                                const int* __restrict__ shape_id, const int* __restrict__ color_id,
                                const float* __restrict__ pos,
                                int* __restrict__ cnt, int* __restrict__ rank,
                                int2* __restrict__ nf) {
    int e = blockIdx.x * blockDim.x + threadIdx.x;
    if (e < NNODE) nf[e] = make_int2(shape_id[e] | (color_id[e] << 8), __float_as_int(pos[e]));
    if (e >= NEDGE) return;
    int d = ei[NEDGE + e], r = et[e];
    rank[e] = atomicAdd(&cnt[d * 3 + r], 1);   // rank within (d,r) segment
}

// ---------------- prefix scan (2-phase), relation-major CSR; also zeroes pooled ----------------
__global__ void scan_partial_kernel(const int* __restrict__ cnt, int* __restrict__ partial,
                                    float* __restrict__ pooled) {
    __shared__ int sh[256];
    int t = threadIdx.x, i = blockIdx.x * 256 + t;
    for (int z = i; z < GNUM * 128; z += NB * 256) pooled[z] = 0.f;
    int v = (i < NNODE) ? cnt[3 * i] + cnt[3 * i + 1] + cnt[3 * i + 2] : 0;
    sh[t] = v; __syncthreads();
    for (int o = 128; o > 0; o >>= 1) { if (t < o) sh[t] += sh[t + o]; __syncthreads(); }
    if (t == 0) partial[blockIdx.x] = sh[0];
}

// merged mid+final: each block redundantly scans the 196 partials in LDS
__global__ void scan_final_kernel(const int* __restrict__ cnt, const int* __restrict__ partial,
                                  int* __restrict__ offs3, float* __restrict__ rcnt) {
    __shared__ int shp[256];
    __shared__ int sh[256];
    int t = threadIdx.x, i = blockIdx.x * 256 + t;
    int pv = (t < NB) ? partial[t] : 0;
    shp[t] = pv; __syncthreads();
    for (int o = 1; o < 256; o <<= 1) {
        int x = (t >= o) ? shp[t - o] : 0; __syncthreads();
        shp[t] += x; __syncthreads();
    }
    int blockOff = (blockIdx.x > 0) ? shp[blockIdx.x - 1] : 0;
    int c0 = 0, c1 = 0, c2 = 0;
    if (i < NNODE) { c0 = cnt[3 * i]; c1 = cnt[3 * i + 1]; c2 = cnt[3 * i + 2]; }
    int v = c0 + c1 + c2;
    sh[t] = v; __syncthreads();
    for (int o = 1; o < 256; o <<= 1) {
        int x = (t >= o) ? sh[t - o] : 0; __syncthreads();
        sh[t] += x; __syncthreads();
    }
    int exc = sh[t] - v + blockOff;
    if (i < NNODE) {
        offs3[3 * i]     = exc;
        offs3[3 * i + 1] = exc + c0;
        offs3[3 * i + 2] = exc + c0 + c1;
        float4 rc = make_float4(1.f / fmaxf((float)c0, 1.f), 1.f / fmaxf((float)c1, 1.f),
                                1.f / fmaxf((float)c2, 1.f), 1.f);
        *(float4*)&rcnt[i * 4] = rc;
    }
    if (blockIdx.x == 0 && t == 0) offs3[3 * NNODE] = NEDGE;
}

// ---------------- fill: atomic-free (p = offs3 + precomputed rank) ----------------
__global__ void fill_kernel(const int* __restrict__ ei, const int* __restrict__ et,
                            const int* __restrict__ rank, const int* __restrict__ offs3,
                            int* __restrict__ sorted) {
    int e = blockIdx.x * blockDim.x + threadIdx.x;
    if (e >= NEDGE) return;
    int s = ei[e], d = ei[NEDGE + e], r = et[e];
    int p = offs3[d * 3 + r] + rank[e];
    sorted[p] = s | (r << 16);   // NNODE < 65536, r < 4
}

// ---------------- layer-1 histogram: edge-parallel LDS hist; emits scaled bf16-hi ----------------
__global__ __launch_bounds__(256) void hist1_kernel(const int* __restrict__ offs3,
                                                    const int* __restrict__ sorted,
                                                    const int2* __restrict__ nf,
                                                    const float* __restrict__ rcnt,
                                                    unsigned short* __restrict__ A1h) {
    __shared__ float hist[4][3 * 34];
    int lane = threadIdx.x & 63;
    int wv   = threadIdx.x >> 6;
    int d    = (blockIdx.x << 2) + wv;
    float* hf = hist[wv];
    if (lane < 51) { hf[lane] = 0.f; hf[lane + 51] = 0.f; }
    if (d < NNODE) {
        int beg = offs3[3 * d], end = offs3[3 * d + 3];
        for (int i = beg + lane; i < end; i += 64) {
            int w = sorted[i];
            int s = w & 0xFFFF, r = (w >> 16) & 3;
            int2 f = nf[s];
            atomicAdd(&hf[r * 34 + (f.x & 0xFF)], 1.f);
            atomicAdd(&hf[r * 34 + 16 + (f.x >> 8)], 1.f);
            atomicAdd(&hf[r * 34 + 32], __int_as_float(f.y));
        }
#pragma unroll
        for (int half = 0; half < 2; ++half) {
            int slot = lane + half * 64;                 // 0..127
            float v = 0.f;
            if (slot < 99) {
                int r = slot / 33;
                v = hf[r * 34 + (slot - r * 33)] * rcnt[d * 4 + r];
            }
            A1h[(size_t)d * K1M + slot] = (unsigned short)bf16_rne(v);
        }
    }
}

// ---------------- layer-2 aggregation: wave-per-node, segmented, 8-deep ILP, hi-only ----------------
__global__ __launch_bounds__(256) void aggregate_kernel(const int* __restrict__ offs3,
                                                        const int* __restrict__ sorted,
                                                        const float* __restrict__ rcnt,
                                                        unsigned short* __restrict__ A2h) {
    int lane = threadIdx.x & 63;
    int d = (blockIdx.x << 2) + (threadIdx.x >> 6);
    if (d >= NNODE) return;
    int b0  = __builtin_amdgcn_readfirstlane(offs3[3 * d]);
    int b1  = __builtin_amdgcn_readfirstlane(offs3[3 * d + 1]);
    int b2  = __builtin_amdgcn_readfirstlane(offs3[3 * d + 2]);
    int end = __builtin_amdgcn_readfirstlane(offs3[3 * d + 3]);
    const unsigned* xp = (const unsigned*)A2h;   // row = 256 unsigneds; root block at +192
    float a00 = 0.f, a01 = 0.f, a10 = 0.f, a11 = 0.f, a20 = 0.f, a21 = 0.f;
#define AGG_ACC(ii, x) {                                            \
        float lo_ = __uint_as_float((x) << 16);                     \
        float hi_ = __uint_as_float((x) & 0xFFFF0000u);             \
        if ((ii) >= b2)      { a20 += lo_; a21 += hi_; }            \
        else if ((ii) >= b1) { a10 += lo_; a11 += hi_; }            \
        else                 { a00 += lo_; a01 += hi_; } }
#define AGG_LD(j)  unsigned x##j = xp[((size_t)(unsigned)(sorted[i + j] & 0xFFFF) << 8) + 192 + lane]
    int i = b0;
    for (; i + 8 <= end; i += 8) {
        AGG_LD(0); AGG_LD(1); AGG_LD(2); AGG_LD(3);
        AGG_LD(4); AGG_LD(5); AGG_LD(6); AGG_LD(7);
        AGG_ACC(i, x0); AGG_ACC(i + 1, x1); AGG_ACC(i + 2, x2); AGG_ACC(i + 3, x3);
        AGG_ACC(i + 4, x4); AGG_ACC(i + 5, x5); AGG_ACC(i + 6, x6); AGG_ACC(i + 7, x7);
    }
    for (; i + 4 <= end; i += 4) {
        AGG_LD(0); AGG_LD(1); AGG_LD(2); AGG_LD(3);
        AGG_ACC(i, x0); AGG_ACC(i + 1, x1); AGG_ACC(i + 2, x2); AGG_ACC(i + 3, x3);
    }
    for (; i < end; ++i) {
        AGG_LD(0);
        AGG_ACC(i, x0);
    }
#undef AGG_LD
#undef AGG_ACC
    float rc0 = rcnt[d * 4 + 0], rc1 = rcnt[d * 4 + 1], rc2 = rcnt[d * 4 + 2];
    size_t base = (size_t)d * 512 + (lane << 1);
#define AGG_OUT(vA, vB, rel) {                                        \
        unsigned short h0_ = (unsigned short)bf16_rne(vA);            \
        unsigned short h1_ = (unsigned short)bf16_rne(vB);            \
        *(unsigned*)&A2h[base + (rel) * 128] = (unsigned)h0_ | ((unsigned)h1_ << 16); }
    AGG_OUT(a00 * rc0, a01 * rc0, 0);
    AGG_OUT(a10 * rc1, a11 * rc1, 1);
    AGG_OUT(a20 * rc2, a21 * rc2, 2);
#undef AGG_OUT
}

// ---------------- layer-1 GEMM: MFMA bf16 AhxBh, BM=64, swizzled LDS, fused root epilogue ----------------
__global__ __launch_bounds__(256) void gemm1_mfma_kernel(
    const unsigned short* __restrict__ A1h,
    const short* __restrict__ B1th,
    const int* __restrict__ shape_id, const int* __restrict__ color_id,
    const float* __restrict__ pos, const float* __restrict__ rootTab,
    const float* __restrict__ bias,
    unsigned short* __restrict__ A2h) {
    __shared__ short Ah[64][32];
    __shared__ short Bh[128][32];
    const int t    = threadIdx.x;
    const int lane = t & 63;
    const int w    = t >> 6;
    const int wm   = w >> 1, wn = w & 1;     // wave tile 32(M) x 64(N)
    const int bm0  = blockIdx.x * 64;
    const int lr   = lane & 15, lk = lane >> 4;
    const int sr = t >> 2, skb = t & 3;
    int gra = bm0 + sr; if (gra >= NNODE) gra = NNODE - 1;   // clamp (C-write guarded)
    f32x4 acc[2][4] = {};
    for (int kt = 0; kt < K1M; kt += 32) {
        vshort8 avh = *(const vshort8*)&A1h[(size_t)gra * K1M + kt + skb * 8];
        vshort8 bvh0 = *(const vshort8*)&B1th[(size_t)sr * K1M + kt + skb * 8];
        vshort8 bvh1 = *(const vshort8*)&B1th[(size_t)(sr + 64) * K1M + kt + skb * 8];
        __syncthreads();
        *(vshort8*)&Ah[sr][SWZ(sr, skb)]           = avh;
        *(vshort8*)&Bh[sr][SWZ(sr, skb)]           = bvh0;
        *(vshort8*)&Bh[sr + 64][SWZ(sr + 64, skb)] = bvh1;
        __syncthreads();
        vshort8 afh[2], bfh[4];
#pragma unroll
        for (int mf = 0; mf < 2; ++mf) {
            int row = wm * 32 + mf * 16 + lr;
            afh[mf] = *(const vshort8*)&Ah[row][SWZ(row, lk)];
        }
#pragma unroll
        for (int nf = 0; nf < 4; ++nf) {
            int row = wn * 64 + nf * 16 + lr;
            bfh[nf] = *(const vshort8*)&Bh[row][SWZ(row, lk)];
        }
#pragma unroll
        for (int mf = 0; mf < 2; ++mf)
#pragma unroll
            for (int nf = 0; nf < 4; ++nf)
                acc[mf][nf] = __builtin_amdgcn_mfma_f32_16x16x32_bf16(afh[mf], bfh[nf], acc[mf][nf], 0, 0, 0);
    }
    // epilogue: + root lookups + bias, relu, write A2 root block (bf16-hi)
#pragma unroll
    for (int mf = 0; mf < 2; ++mf) {
        int mb = bm0 + wm * 32 + mf * 16 + (lane >> 4) * 4;
#pragma unroll
        for (int r = 0; r < 4; ++r) {
            int gm = mb + r;
            if (gm >= NNODE) continue;
            int sid = shape_id[gm], cid = color_id[gm];
            float pv = pos[gm];
#pragma unroll
            for (int nf = 0; nf < 4; ++nf) {
                int n = wn * 64 + nf * 16 + lr;
                float v = acc[mf][nf][r] + rootTab[sid * 128 + n] + rootTab[(16 + cid) * 128 + n]
                        + pv * rootTab[32 * 128 + n] + bias[n];
                A2h[(size_t)gm * 512 + 384 + n] = (unsigned short)bf16_rne(fmaxf(v, 0.f));
            }
        }
    }
}

// ---------------- layer-2 GEMM: MFMA bf16 AhxBh, BM=64, swizzled LDS, FUSED POOL epilogue ----------------
__global__ __launch_bounds__(256) void gemm2_mfma_kernel(
    const unsigned short* __restrict__ A2h,
    const short* __restrict__ Bt_hi,
    const float* __restrict__ bias,
    const int* __restrict__ batch,
    float* __restrict__ pooled) {
    __shared__ char smem[64 * 132 * 4 + 256];          // Cst[64][132] f32, union w/ Ah,Bh
    short (*Ah)[32]   = (short(*)[32])smem;            // 4 KB
    short (*Bh)[32]   = (short(*)[32])(smem + 4096);   // 8 KB
    float (*Cst)[132] = (float(*)[132])smem;           // 33.8 KB (after compute)
    int*  batchLDS    = (int*)(smem + 64 * 132 * 4);
    const int t    = threadIdx.x;
    const int lane = t & 63;
    const int w    = t >> 6;
    const int wm   = w >> 1, wn = w & 1;     // wave tile 32(M) x 64(N)
    const int bm0  = blockIdx.x * 64;
    const int lr   = lane & 15, lk = lane >> 4;
    const int sr = t >> 2, skb = t & 3;
    int gra = bm0 + sr; if (gra >= NNODE) gra = NNODE - 1;   // clamp (epilogue guarded)
    f32x4 acc[2][4] = {};
    for (int kt = 0; kt < K2; kt += 32) {
        vshort8 avh = *(const vshort8*)&A2h[(size_t)gra * K2 + kt + skb * 8];
        vshort8 bvh0 = *(const vshort8*)&Bt_hi[(size_t)sr * K2 + kt + skb * 8];
        vshort8 bvh1 = *(const vshort8*)&Bt_hi[(size_t)(sr + 64) * K2 + kt + skb * 8];
        __syncthreads();
        *(vshort8*)&Ah[sr][SWZ(sr, skb)]           = avh;
        *(vshort8*)&Bh[sr][SWZ(sr, skb)]           = bvh0;
        *(vshort8*)&Bh[sr + 64][SWZ(sr + 64, skb)] = bvh1;
        __syncthreads();
        vshort8 afh[2], bfh[4];
#pragma unroll
        for (int mf = 0; mf < 2; ++mf) {
            int row = wm * 32 + mf * 16 + lr;
            afh[mf] = *(const vshort8*)&Ah[row][SWZ(row, lk)];
        }
#pragma unroll
        for (int nf = 0; nf < 4; ++nf) {
            int row = wn * 64 + nf * 16 + lr;
            bfh[nf] = *(const vshort8*)&Bh[row][SWZ(row, lk)];
        }
#pragma unroll
        for (int mf = 0; mf < 2; ++mf)
#pragma unroll
            for (int nf = 0; nf < 4; ++nf)
                acc[mf][nf] = __builtin_amdgcn_mfma_f32_16x16x32_bf16(afh[mf], bfh[nf], acc[mf][nf], 0, 0, 0);
    }
    __syncthreads();   // all LDS reads done; reuse smem as Cst
    // stage relu(C) to LDS
#pragma unroll
    for (int mf = 0; mf < 2; ++mf) {
        int rb = wm * 32 + mf * 16 + (lane >> 4) * 4;
#pragma unroll
        for (int nf = 0; nf < 4; ++nf) {
            int n = wn * 64 + nf * 16 + lr;
            float bn = bias[n];
#pragma unroll
            for (int r = 0; r < 4; ++r)
                Cst[rb + r][n] = fmaxf(acc[mf][nf][r] + bn, 0.f);
        }
    }
    if (t < 64) batchLDS[t] = (bm0 + t < NNODE) ? batch[bm0 + t] : -1;
    __syncthreads();
    // run-length reduce 32 rows per thread -> atomicAdd per (graph, col)
    {
        int col  = t & 127;
        int rbeg = (t >> 7) * 32;
        float accp = 0.f;
        int cur = batchLDS[rbeg];
        for (int rr = 0; rr < 32; ++rr) {
            int row = rbeg + rr;
            int g = batchLDS[row];
            if (g != cur) {
                if (cur >= 0) atomicAdd(&pooled[cur * 128 + col], accp);
                accp = 0.f; cur = g;
            }
            if (g >= 0) accp += Cst[row][col];
        }
        if (cur >= 0) atomicAdd(&pooled[cur * 128 + col], accp);
    }
}

// ---------------- final: per-graph count via binary search on sorted batch ----------------
__global__ void final_kernel(const float* __restrict__ pooled, const int* __restrict__ batch,
                             const float* __restrict__ lin_w, const float* __restrict__ lin_b,
                             float* __restrict__ out) {
    int idx = blockIdx.x * blockDim.x + threadIdx.x;
    if (idx >= GNUM * 4) return;
    int g = idx >> 2, c = idx & 3;
    // count of nodes with batch==g: lower_bound(g+1) - lower_bound(g)
    int lo = 0, hi = NNODE;
    while (lo < hi) { int m = (lo + hi) >> 1; if (batch[m] < g) lo = m + 1; else hi = m; }
    int lo2 = lo, hi2 = NNODE;
    while (lo2 < hi2) { int m = (lo2 + hi2) >> 1; if (batch[m] < g + 1) lo2 = m + 1; else hi2 = m; }
    float cntf = (float)max(lo2 - lo, 1);
    float dot = 0.f;
    for (int k = 0; k < 128; ++k) dot += pooled[g * 128 + k] * lin_w[k * 4 + c];
    out[idx] = dot / cntf + lin_b[c];
}

// ---------------- launch ----------------
extern "C" void kernel_launch(void* const* d_in, const int* in_sizes, int n_in,
                              void* d_out, int out_size, void* d_ws, size_t ws_size,
                              hipStream_t stream) {
    const float* pos      = (const float*)d_in[0];
    const int*   shape_id = (const int*)d_in[1];
    const int*   color_id = (const int*)d_in[2];
    const int*   ei       = (const int*)d_in[3];
    const int*   et       = (const int*)d_in[4];
    const int*   batch    = (const int*)d_in[5];
    const float* shape_w  = (const float*)d_in[6];
    const float* color_w  = (const float*)d_in[7];
    const float* W1       = (const float*)d_in[8];
    const float* root1    = (const float*)d_in[9];
    const float* b1       = (const float*)d_in[10];
    const float* W2       = (const float*)d_in[11];
    const float* root2    = (const float*)d_in[12];
    const float* b2       = (const float*)d_in[13];
    const float* lin_w    = (const float*)d_in[14];
    const float* lin_b    = (const float*)d_in[15];
    float* out = (float*)d_out;

    char* p = (char*)d_ws;
    auto alloc = [&](size_t bytes) { char* r = p; p += (bytes + 255) & ~(size_t)255; return r; };
    int*   cnt     = (int*)alloc((size_t)NNODE * 3 * 4);
    unsigned short* A1h = (unsigned short*)alloc((size_t)NNODE * K1M * 2);
    float* rcntBuf = (float*)alloc((size_t)NNODE * 4 * 4);
    unsigned short* A2h = (unsigned short*)alloc((size_t)NNODE * K2 * 2);
    float* rootTab = (float*)alloc((size_t)33 * 128 * 4);
    short* B1th    = (short*)alloc((size_t)128 * K1M * 2);
    short* Bt_hi   = (short*)alloc((size_t)128 * K2 * 2);
    float* pooled  = (float*)alloc((size_t)GNUM * 128 * 4);
    int2*  nfTab   = (int2*)alloc((size_t)NNODE * 8);
    int*   sorted  = (int*)alloc((size_t)NEDGE * 4);
    int*   offs3   = (int*)alloc((size_t)(3 * NNODE + 1) * 4);
    int*   rank    = (int*)alloc((size_t)NEDGE * 4);
    int*   partial = (int*)alloc((size_t)NB * 4);

    build_tabs_kernel<<<(K1M * 128 + 33 * 128 + K2 * 128 + 255) / 256, 256, 0, stream>>>(
        shape_w, color_w, W1, root1, W2, root2, B1th, rootTab, Bt_hi, cnt);

    count_nf_kernel<<<(NEDGE + 255) / 256, 256, 0, stream>>>(
        ei, et, shape_id, color_id, pos, cnt, rank, nfTab);
    scan_partial_kernel<<<NB, 256, 0, stream>>>(cnt, partial, pooled);
    scan_final_kernel<<<NB, 256, 0, stream>>>(cnt, partial, offs3, rcntBuf);
    fill_kernel<<<(NEDGE + 255) / 256, 256, 0, stream>>>(ei, et, rank, offs3, sorted);

    hist1_kernel<<<(NNODE + 3) / 4, 256, 0, stream>>>(offs3, sorted, nfTab, rcntBuf, A1h);

    gemm1_mfma_kernel<<<(NNODE + 63) / 64, 256, 0, stream>>>(
        A1h, B1th, shape_id, color_id, pos, rootTab, b1, A2h);

    aggregate_kernel<<<(NNODE + 3) / 4, 256, 0, stream>>>(offs3, sorted, rcntBuf, A2h);

    gemm2_mfma_kernel<<<(NNODE + 63) / 64, 256, 0, stream>>>(
        A2h, Bt_hi, b2, batch, pooled);

    final_kernel<<<(GNUM * 4 + 255) / 256, 256, 0, stream>>>(
        pooled, batch, lin_w, lin_b, out);
}